// Round 6
// baseline (833.395 us; speedup 1.0000x reference)
//
#include <hip/hip_runtime.h>
#include <hip/hip_bf16.h>

#define LN_EPS 1e-5f

typedef __attribute__((ext_vector_type(8))) short bf16x8;
typedef __attribute__((ext_vector_type(4))) float f32x4;

__device__ __forceinline__ float sigmoidf_(float x) { return 1.0f / (1.0f + __expf(-x)); }
__device__ __forceinline__ ushort f2bf(float x) {
    __hip_bfloat16 h = __float2bfloat16(x);   // RNE
    return __builtin_bit_cast(ushort, h);
}
// m204 bijective XCD-chunked swizzle (8 XCDs)
__device__ __forceinline__ int xcd_swz(int bid, int nwg) {
    const int q = nwg >> 3, r = nwg & 7;
    const int xcd = bid & 7, idx = bid >> 3;
    return (xcd < r ? xcd * (q + 1) : r * (q + 1) + (xcd - r) * q) + idx;
}
// block-local edge permutation: swap bits[3:2] <-> bits[5:4] (involution).
// sA row r holds sorted edge s0+g(r); thread (lhi,m,j) then owns 16 CONSECUTIVE edges.
__device__ __forceinline__ int gperm(int l) {
    return (l & ~63) | (((l >> 2) & 3) << 4) | (((l >> 4) & 3) << 2) | (l & 3);
}
__device__ __forceinline__ void gload_lds16(const void* g, void* l) {
    __builtin_amdgcn_global_load_lds((const __attribute__((address_space(1))) void*)g,
                                     (__attribute__((address_space(3))) void*)l, 16, 0, 0);
}

// ws layout (N read on device):
//   float aggL[N*128]; float aggR[N*128]; float rd[N];
//   int ideg[N]; int ioff[N+1]; int icur[N]; int elist[E]; int epos[E];
//   ushort WgF[16*4*64*8]; ushort W1F[8*8*64*8]
//   ... tail of ws (host-computed): ushort ynb[(E+128)*128]  (LN'd y, bf16, permuted-sorted order)
struct WsPtrs {
    float *aggL, *aggR, *rd;
    int *ideg, *ioff, *icur, *elist, *epos;
    ushort *WgF, *W1F;
    int N;
};
__device__ __forceinline__ WsPtrs ws_ptrs(float* ws, const int* n_nodes_p, int E) {
    WsPtrs p;
    p.N    = *n_nodes_p;
    p.aggL = ws;
    p.aggR = ws + (size_t)p.N * 128;
    p.rd   = ws + (size_t)p.N * 256;
    p.ideg = (int*)(ws + (size_t)p.N * 257);
    p.ioff = p.ideg + p.N;
    p.icur = p.ioff + p.N + 1;
    p.elist = p.icur + p.N;
    p.epos  = p.elist + E;
    p.WgF = (ushort*)(((uintptr_t)(p.epos + E) + 15) & ~(uintptr_t)15);
    p.W1F = p.WgF + 32768;
    return p;
}

// ---------------- zero agg + deg ----------------
__global__ void init_kernel(float* __restrict__ ws, const int* __restrict__ n_nodes_p, int E) {
    WsPtrs p = ws_ptrs(ws, n_nodes_p, E);
    const long long stride = (long long)gridDim.x * blockDim.x;
    const long long tid = (long long)blockIdx.x * blockDim.x + threadIdx.x;
    const long long nf = (long long)p.N * 256;
    for (long long i = tid; i < nf; i += stride) ws[i] = 0.0f;
    for (long long i = tid; i < p.N; i += stride) p.ideg[i] = 0;
}

// ---------------- histogram of dst ----------------
__global__ void hist_kernel(const int* __restrict__ dst, float* __restrict__ ws,
                            const int* __restrict__ n_nodes_p, int E) {
    WsPtrs p = ws_ptrs(ws, n_nodes_p, E);
    const int i = blockIdx.x * blockDim.x + threadIdx.x;
    if (i < E) atomicAdd(&p.ideg[dst[i]], 1);
}

// ---------------- exclusive scan (single block) + rd = 1/max(deg,1) ----------------
__global__ __launch_bounds__(256) void scan_kernel(float* __restrict__ ws,
                                                   const int* __restrict__ n_nodes_p, int E) {
    WsPtrs p = ws_ptrs(ws, n_nodes_p, E);
    __shared__ int wsum[4];
    __shared__ int carry_s;
    const int t = threadIdx.x;
    const int lane = t & 63, wid = t >> 6;
    if (t == 0) carry_s = 0;
    __syncthreads();
    for (int base = 0; base < p.N; base += 1024) {
        const int i0 = base + t * 4;
        const int v0 = (i0 + 0 < p.N) ? p.ideg[i0 + 0] : 0;
        const int v1 = (i0 + 1 < p.N) ? p.ideg[i0 + 1] : 0;
        const int v2 = (i0 + 2 < p.N) ? p.ideg[i0 + 2] : 0;
        const int v3 = (i0 + 3 < p.N) ? p.ideg[i0 + 3] : 0;
        const int s = v0 + v1 + v2 + v3;
        int sc = s;
        #pragma unroll
        for (int off = 1; off < 64; off <<= 1) {
            const int n = __shfl_up(sc, off);
            if (lane >= off) sc += n;
        }
        if (lane == 63) wsum[wid] = sc;
        __syncthreads();
        int woff = 0;
        #pragma unroll
        for (int w = 0; w < 4; ++w) if (w < wid) woff += wsum[w];
        const int carry = carry_s;
        __syncthreads();
        const int excl = carry + woff + (sc - s);
        if (i0 + 0 < p.N) { p.ioff[i0+0] = excl;          p.icur[i0+0] = excl;          p.rd[i0+0] = 1.0f / fmaxf((float)v0, 1.0f); }
        if (i0 + 1 < p.N) { p.ioff[i0+1] = excl+v0;       p.icur[i0+1] = excl+v0;       p.rd[i0+1] = 1.0f / fmaxf((float)v1, 1.0f); }
        if (i0 + 2 < p.N) { p.ioff[i0+2] = excl+v0+v1;    p.icur[i0+2] = excl+v0+v1;    p.rd[i0+2] = 1.0f / fmaxf((float)v2, 1.0f); }
        if (i0 + 3 < p.N) { p.ioff[i0+3] = excl+v0+v1+v2; p.icur[i0+3] = excl+v0+v1+v2; p.rd[i0+3] = 1.0f / fmaxf((float)v3, 1.0f); }
        if (t == 255) carry_s = carry + woff + sc;
        __syncthreads();
    }
    if (t == 0) p.ioff[p.N] = carry_s;
}

// ---------------- scatter edge ids into buckets ----------------
__global__ void scatter_kernel(const int* __restrict__ dst, float* __restrict__ ws,
                               const int* __restrict__ n_nodes_p, int E) {
    WsPtrs p = ws_ptrs(ws, n_nodes_p, E);
    const int i = blockIdx.x * blockDim.x + threadIdx.x;
    if (i < E) {
        const int pos = atomicAdd(&p.icur[dst[i]], 1);
        p.elist[pos] = i;
    }
}

// ---------------- per-bucket insertion sort + inverse (permuted) position map ----------------
__global__ void bsort_kernel(float* __restrict__ ws, const int* __restrict__ n_nodes_p, int E) {
    WsPtrs p = ws_ptrs(ws, n_nodes_p, E);
    const int stride = gridDim.x * blockDim.x;
    for (int i = blockIdx.x * blockDim.x + threadIdx.x; i < p.N; i += stride) {
        const int beg = p.ioff[i], end = p.ioff[i + 1];
        for (int a = beg + 1; a < end; ++a) {
            const int key = p.elist[a];
            int b = a - 1;
            while (b >= beg && p.elist[b] > key) { p.elist[b + 1] = p.elist[b]; --b; }
            p.elist[b + 1] = key;
        }
        for (int a = beg; a < end; ++a)
            p.epos[p.elist[a]] = (a & ~63) | gperm(a & 63);
    }
}

// ---------------- build fragment-major bf16 B tables ----------------
__global__ void prep_w_kernel(const float* __restrict__ Wl, const float* __restrict__ Wr,
                              const float* __restrict__ W1,
                              float* __restrict__ ws, const int* __restrict__ n_nodes_p, int E) {
    WsPtrs p = ws_ptrs(ws, n_nodes_p, E);
    const int i = blockIdx.x * blockDim.x + threadIdx.x;
    if (i < 32768) {
        const int i8 = i & 7, lane = (i >> 3) & 63, kf = (i >> 9) & 3, nblk = i >> 11;
        const int k = kf * 32 + (lane >> 4) * 8 + i8;
        const int n = nblk * 16 + (lane & 15);
        const float val = (n < 128) ? Wl[k * 128 + n] : Wr[k * 128 + (n - 128)];
        p.WgF[i] = f2bf(val);
    } else if (i < 65536) {
        const int j = i - 32768;
        const int i8 = j & 7, lane = (j >> 3) & 63, kf = (j >> 9) & 7, nblk = j >> 12;
        const int k = kf * 32 + (lane >> 4) * 8 + i8;
        const int n = nblk * 16 + (lane & 15);
        p.W1F[j] = f2bf(W1[k * 128 + n]);
    }
}

// ---------------- streaming LN(y) -> bf16, scatter-write to permuted-sorted order ----------------
// 4 threads/row, 64 rows/block. Reads coalesced; writes 256B rows scattered (posted).
__global__ __launch_bounds__(256) void ln_y_kernel(
    const float* __restrict__ y,
    const float* __restrict__ ln_g, const float* __restrict__ ln_b,
    float* __restrict__ ws, const int* __restrict__ n_nodes_p, int E,
    ushort* __restrict__ ynb)
{
    WsPtrs p = ws_ptrs(ws, n_nodes_p, E);
    const int t = threadIdx.x;
    const int e = blockIdx.x * 64 + (t >> 2);
    const int sub = t & 3;
    if (e >= E) return;

    const float* yr = y + (size_t)e * 128;
    float v[32];
    float s = 0.f, sq = 0.f;
    #pragma unroll
    for (int i = 0; i < 8; ++i) {
        const float4 q = *reinterpret_cast<const float4*>(yr + sub * 32 + i * 4);
        v[i*4+0] = q.x; v[i*4+1] = q.y; v[i*4+2] = q.z; v[i*4+3] = q.w;
        s  += q.x + q.y + q.z + q.w;
        sq += q.x*q.x + q.y*q.y + q.z*q.z + q.w*q.w;
    }
    s  += __shfl_xor(s, 1);  s  += __shfl_xor(s, 2);
    sq += __shfl_xor(sq, 1); sq += __shfl_xor(sq, 2);
    const float mu = s * (1.f / 128.f);
    const float rstd = rsqrtf(sq * (1.f / 128.f) - mu * mu + LN_EPS);

    ushort* dstrow = ynb + (size_t)p.epos[e] * 128 + sub * 32;
    #pragma unroll
    for (int i = 0; i < 4; ++i) {
        uint w32[4];
        #pragma unroll
        for (int h2 = 0; h2 < 4; ++h2) {
            const int c = sub * 32 + i * 8 + h2 * 2;
            const float x0 = (v[i*8 + h2*2 + 0] - mu) * rstd * ln_g[c + 0] + ln_b[c + 0];
            const float x1 = (v[i*8 + h2*2 + 1] - mu) * rstd * ln_g[c + 1] + ln_b[c + 1];
            w32[h2] = (uint)f2bf(x0) | ((uint)f2bf(x1) << 16);
        }
        *reinterpret_cast<uint4*>(dstrow + i * 8) = make_uint4(w32[0], w32[1], w32[2], w32[3]);
    }
}

// ---------------- gates: MFMA dual-gate GEMM + sigmoid + compressed scatter ----------------
// 512 threads (8 waves), 128 dst-sorted edges/block.
// sA row r holds sorted edge s0+g(r) -> each thread run-compresses 16 CONSECUTIVE edges.
// sA: [128 rows][128 cols] bf16, byte = row*256 + col*2, XOR-swizzle ((byte>>8)&7)<<4.
// If ynb != null: sA staged via global_load_lds from contiguous ynb (swizzle on source addr).
__global__ __launch_bounds__(512) void gates_kernel(
    const float* __restrict__ y, const int* __restrict__ dst,
    const float* __restrict__ ln_g, const float* __restrict__ ln_b,
    const float* __restrict__ bl, const float* __restrict__ br,
    float* __restrict__ ws, const int* __restrict__ n_nodes_p, int E,
    const ushort* __restrict__ ynb)
{
    __shared__ ushort sA[128 * 128];   // 32 KB
    __shared__ int sNode[128];

    WsPtrs p = ws_ptrs(ws, n_nodes_p, E);
    char* sAb = reinterpret_cast<char*>(sA);
    const int t = threadIdx.x;
    const int bid = xcd_swz(blockIdx.x, gridDim.x);
    const int s0 = bid * 128;
    const int lane = t & 63;
    const int w8 = t >> 6;

    if (t < 128) {
        const int j = s0 + t;
        const int eid = (j < E) ? p.elist[j] : -1;
        sNode[t] = (eid >= 0) ? dst[eid] : -1;
    }

    if (ynb) {
        // pure DMA staging: LDS linear, swizzle folded into source offset
        const char* ybase = (const char*)ynb + (size_t)s0 * 256;
        #pragma unroll
        for (int i = 0; i < 4; ++i) {
            const int chunk = w8 + i * 8;
            const int L = chunk * 1024 + lane * 16;
            const int b = L ^ (((L >> 8) & 7) << 4);
            gload_lds16(ybase + b, sAb + chunk * 1024);
        }
    } else {
        // fallback: in-kernel LN; thread r fills sA row r with edge elist[s0+g(r)]
        const int r = t >> 2, sub = t & 3;
        const int je = s0 + gperm(r);
        const int eid = (je < E) ? p.elist[je] : 0;
        const float* yr = y + (size_t)eid * 128;
        float v[32];
        float s = 0.f, sq = 0.f;
        #pragma unroll
        for (int i = 0; i < 8; ++i) {
            const float4 q = *reinterpret_cast<const float4*>(yr + sub * 32 + i * 4);
            v[i*4+0] = q.x; v[i*4+1] = q.y; v[i*4+2] = q.z; v[i*4+3] = q.w;
            s  += q.x + q.y + q.z + q.w;
            sq += q.x*q.x + q.y*q.y + q.z*q.z + q.w*q.w;
        }
        s  += __shfl_xor(s, 1);  s  += __shfl_xor(s, 2);
        sq += __shfl_xor(sq, 1); sq += __shfl_xor(sq, 2);
        const float mu = s * (1.f / 128.f);
        const float rstd = rsqrtf(sq * (1.f / 128.f) - mu * mu + LN_EPS);
        #pragma unroll
        for (int i = 0; i < 4; ++i) {
            uint w32[4];
            #pragma unroll
            for (int h2 = 0; h2 < 4; ++h2) {
                const int c = sub * 32 + i * 8 + h2 * 2;
                const float x0 = (v[i*8 + h2*2 + 0] - mu) * rstd * ln_g[c + 0] + ln_b[c + 0];
                const float x1 = (v[i*8 + h2*2 + 1] - mu) * rstd * ln_g[c + 1] + ln_b[c + 1];
                w32[h2] = (uint)f2bf(x0) | ((uint)f2bf(x1) << 16);
            }
            int byte = r * 256 + sub * 64 + i * 16;
            byte ^= ((byte >> 8) & 7) << 4;
            *reinterpret_cast<uint4*>(sAb + byte) = make_uint4(w32[0], w32[1], w32[2], w32[3]);
        }
    }
    __syncthreads();

    const int rowh = w8 >> 2, colw = w8 & 3;
    const int lhi = lane >> 4, llo = lane & 15;

    f32x4 acc[4][4];
    #pragma unroll
    for (int m = 0; m < 4; ++m)
        #pragma unroll
        for (int n = 0; n < 4; ++n) acc[m][n] = (f32x4){0.f, 0.f, 0.f, 0.f};

    #pragma unroll
    for (int kf = 0; kf < 4; ++kf) {
        bf16x8 a[4], b[4];
        #pragma unroll
        for (int m = 0; m < 4; ++m) {
            const int row = rowh * 64 + m * 16 + llo;
            int byte = row * 256 + kf * 64 + lhi * 16;
            byte ^= ((byte >> 8) & 7) << 4;
            a[m] = *reinterpret_cast<const bf16x8*>(sAb + byte);
        }
        #pragma unroll
        for (int nf = 0; nf < 4; ++nf) {
            const int nblk = colw * 4 + nf;
            b[nf] = *reinterpret_cast<const bf16x8*>(p.WgF + ((size_t)(nblk * 4 + kf) * 64 + lane) * 8);
        }
        #pragma unroll
        for (int m = 0; m < 4; ++m)
            #pragma unroll
            for (int nf = 0; nf < 4; ++nf)
                acc[m][nf] = __builtin_amdgcn_mfma_f32_16x16x32_bf16(a[m], b[nf], acc[m][nf], 0, 0, 0);
    }

    // epilogue: sigmoid + run-compressed atomics over 16 CONSECUTIVE edges per thread.
    // D row (m,lhi,j) holds edge s0 + rowh*64 + lhi*16 + m*4 + j (increasing in m,j).
    const int g = colw >> 1;
    float* ag = g ? p.aggR : p.aggL;
    const float* bp = g ? br : bl;
    #pragma unroll
    for (int nf = 0; nf < 4; ++nf) {
        const int col = colw * 64 + nf * 16 + llo;
        const int lcol = col & 127;
        const float bias = bp[lcol];
        float runv = 0.f;
        int rnode = -1;
        #pragma unroll
        for (int m = 0; m < 4; ++m) {
            #pragma unroll
            for (int j = 0; j < 4; ++j) {
                const int el = rowh * 64 + lhi * 16 + m * 4 + j;
                const int node = sNode[el];
                const float val = sigmoidf_(acc[m][nf][j] + bias);
                if (node != rnode) {
                    if (rnode >= 0) atomicAdd(ag + (size_t)rnode * 128 + lcol, runv);
                    rnode = node;
                    runv = val;
                } else {
                    runv += val;
                }
            }
        }
        if (rnode >= 0) atomicAdd(ag + (size_t)rnode * 128 + lcol, runv);
    }
}

// ---------------- mlp: gather + LN(256) + MFMA GEMM + ELU + W2 dot ----------------
// 512 threads (8 waves), 128 dst-sorted edges/block.
// sA: [128 rows][256 cols] bf16, byte = row*512 + col*2, XOR-swizzle ((byte>>9)&7)<<4.
__global__ __launch_bounds__(512) void mlp_kernel(
    const int* __restrict__ src, const int* __restrict__ dst,
    const float* __restrict__ ln2_g, const float* __restrict__ ln2_b,
    const float* __restrict__ b1, const float* __restrict__ W2,
    const float* __restrict__ b2,
    float* __restrict__ ws, const int* __restrict__ n_nodes_p,
    float* __restrict__ out, int E)
{
    __shared__ ushort sA[128 * 256];   // 64 KB
    __shared__ float sPart[4][128];
    __shared__ int sEid[128];

    WsPtrs p = ws_ptrs(ws, n_nodes_p, E);
    char* sAb = reinterpret_cast<char*>(sA);
    const int t = threadIdx.x;
    const int bid = xcd_swz(blockIdx.x, gridDim.x);
    const int s0 = bid * 128;

    if (t < 128) {
        const int j = s0 + t;
        sEid[t] = (j < E) ? p.elist[j] : -1;
    }

    // gather + LN(256) -> sA. 4 threads/row, sub owns cols [64*sub, 64*sub+64).
    {
        const int r = t >> 2, sub = t & 3;
        const int je = s0 + r;
        const int eid = (je < E) ? p.elist[je] : -1;
        const bool vld = eid >= 0;
        const int node = vld ? ((sub < 2) ? src[eid] : dst[eid]) : 0;
        const float* base = ((sub < 2) ? p.aggL : p.aggR) + (size_t)node * 128 + (sub & 1) * 64;
        const float scale = vld ? p.rd[node] : 0.f;
        float s = 0.f, sq = 0.f;
        #pragma unroll
        for (int i = 0; i < 16; ++i) {
            const float4 q = *reinterpret_cast<const float4*>(base + i * 4);
            const float x0 = q.x * scale, x1 = q.y * scale, x2 = q.z * scale, x3 = q.w * scale;
            s  += x0 + x1 + x2 + x3;
            sq += x0*x0 + x1*x1 + x2*x2 + x3*x3;
        }
        s  += __shfl_xor(s, 1);  s  += __shfl_xor(s, 2);
        sq += __shfl_xor(sq, 1); sq += __shfl_xor(sq, 2);
        const float mu = s * (1.f / 256.f);
        const float rstd = rsqrtf(sq * (1.f / 256.f) - mu * mu + LN_EPS);
        #pragma unroll
        for (int ii = 0; ii < 8; ++ii) {
            const float4 qa = *reinterpret_cast<const float4*>(base + ii * 8);
            const float4 qb = *reinterpret_cast<const float4*>(base + ii * 8 + 4);
            const float xs[8] = { qa.x*scale, qa.y*scale, qa.z*scale, qa.w*scale,
                                  qb.x*scale, qb.y*scale, qb.z*scale, qb.w*scale };
            uint w32[4];
            #pragma unroll
            for (int h2 = 0; h2 < 4; ++h2) {
                const int c = sub * 64 + ii * 8 + h2 * 2;
                const float x0 = (xs[h2*2 + 0] - mu) * rstd * ln2_g[c + 0] + ln2_b[c + 0];
                const float x1 = (xs[h2*2 + 1] - mu) * rstd * ln2_g[c + 1] + ln2_b[c + 1];
                w32[h2] = (uint)f2bf(x0) | ((uint)f2bf(x1) << 16);
            }
            int byte = r * 512 + sub * 128 + ii * 16;
            byte ^= ((byte >> 9) & 7) << 4;
            *reinterpret_cast<uint4*>(sAb + byte) = make_uint4(w32[0], w32[1], w32[2], w32[3]);
        }
    }
    __syncthreads();

    const int lane = t & 63;
    const int w8 = t >> 6;
    const int rowh = w8 >> 2, colw = w8 & 3;
    const int lhi = lane >> 4, llo = lane & 15;

    f32x4 acc[4][2];
    #pragma unroll
    for (int m = 0; m < 4; ++m)
        #pragma unroll
        for (int n = 0; n < 2; ++n) acc[m][n] = (f32x4){0.f, 0.f, 0.f, 0.f};

    #pragma unroll
    for (int kf = 0; kf < 8; ++kf) {
        bf16x8 a[4], b[2];
        #pragma unroll
        for (int m = 0; m < 4; ++m) {
            const int row = rowh * 64 + m * 16 + llo;
            int byte = row * 512 + kf * 64 + lhi * 16;
            byte ^= ((byte >> 9) & 7) << 4;
            a[m] = *reinterpret_cast<const bf16x8*>(sAb + byte);
        }
        #pragma unroll
        for (int nf = 0; nf < 2; ++nf) {
            const int nblk = colw * 2 + nf;
            b[nf] = *reinterpret_cast<const bf16x8*>(p.W1F + ((size_t)(nblk * 8 + kf) * 64 + lane) * 8);
        }
        #pragma unroll
        for (int m = 0; m < 4; ++m)
            #pragma unroll
            for (int nf = 0; nf < 2; ++nf)
                acc[m][nf] = __builtin_amdgcn_mfma_f32_16x16x32_bf16(a[m], b[nf], acc[m][nf], 0, 0, 0);
    }

    // epilogue: bias + ELU + dot(W2) + 16-lane reduce + cross-wave reduce
    float b1v[2], w2v[2];
    #pragma unroll
    for (int nf = 0; nf < 2; ++nf) {
        const int col = colw * 32 + nf * 16 + llo;
        b1v[nf] = b1[col];
        w2v[nf] = W2[col];
    }
    #pragma unroll
    for (int m = 0; m < 4; ++m) {
        #pragma unroll
        for (int j = 0; j < 4; ++j) {
            float pr = 0.f;
            #pragma unroll
            for (int nf = 0; nf < 2; ++nf) {
                float x = acc[m][nf][j] + b1v[nf];
                x = x > 0.f ? x : (__expf(x) - 1.f);
                pr += x * w2v[nf];
            }
            pr += __shfl_xor(pr, 1); pr += __shfl_xor(pr, 2);
            pr += __shfl_xor(pr, 4); pr += __shfl_xor(pr, 8);
            if (llo == 0) sPart[colw][rowh * 64 + m * 16 + lhi * 4 + j] = pr;
        }
    }
    __syncthreads();
    if (t < 128) {
        const int eid = sEid[t];
        if (eid >= 0) out[eid] = sPart[0][t] + sPart[1][t] + sPart[2][t] + sPart[3][t] + b2[0];
    }
}

extern "C" void kernel_launch(void* const* d_in, const int* in_sizes, int n_in,
                              void* d_out, int out_size, void* d_ws, size_t ws_size,
                              hipStream_t stream) {
    const float* y       = (const float*)d_in[0];
    const int*   src     = (const int*)d_in[1];
    const int*   dst     = (const int*)d_in[2];
    const int*   n_nodes = (const int*)d_in[3];
    const float* ln_g    = (const float*)d_in[4];
    const float* ln_b    = (const float*)d_in[5];
    const float* Wl      = (const float*)d_in[6];
    const float* bl      = (const float*)d_in[7];
    const float* Wr      = (const float*)d_in[8];
    const float* br      = (const float*)d_in[9];
    const float* ln2_g   = (const float*)d_in[10];
    const float* ln2_b   = (const float*)d_in[11];
    const float* W1      = (const float*)d_in[12];
    const float* b1      = (const float*)d_in[13];
    const float* W2      = (const float*)d_in[14];
    const float* b2      = (const float*)d_in[15];
    float* out = (float*)d_out;
    float* ws  = (float*)d_ws;

    const int E = in_sizes[0] / 128;
    const int eb = (E + 127) / 128;

    // ynb at tail of ws (bf16 LN'd y, permuted-sorted order), if ws is large enough.
    const size_t need = (size_t)(E + 128) * 256;
    const bool use_pre = ws_size >= need + (96ull << 20);
    ushort* ynb = use_pre
        ? (ushort*)(((uintptr_t)ws + ws_size - need) & ~(uintptr_t)255)
        : nullptr;

    init_kernel<<<2048, 256, 0, stream>>>(ws, n_nodes, E);
    hist_kernel<<<(E + 255) / 256, 256, 0, stream>>>(dst, ws, n_nodes, E);
    scan_kernel<<<1, 256, 0, stream>>>(ws, n_nodes, E);
    scatter_kernel<<<(E + 255) / 256, 256, 0, stream>>>(dst, ws, n_nodes, E);
    bsort_kernel<<<512, 256, 0, stream>>>(ws, n_nodes, E);
    prep_w_kernel<<<256, 256, 0, stream>>>(Wl, Wr, W1, ws, n_nodes, E);
    if (use_pre)
        ln_y_kernel<<<(E + 63) / 64, 256, 0, stream>>>(y, ln_g, ln_b, ws, n_nodes, E, ynb);
    gates_kernel<<<eb, 512, 0, stream>>>(y, dst, ln_g, ln_b, bl, br, ws, n_nodes, E, ynb);
    mlp_kernel<<<eb, 512, 0, stream>>>(src, dst, ln2_g, ln2_b, b1, W2, b2, ws, n_nodes, out, E);
}

// Round 8
// 681.082 us; speedup vs baseline: 1.2236x; 1.2236x over previous
//
#include <hip/hip_runtime.h>
#include <hip/hip_bf16.h>

#define LN_EPS 1e-5f

typedef __attribute__((ext_vector_type(8))) short bf16x8;
typedef __attribute__((ext_vector_type(4))) float f32x4;

__device__ __forceinline__ float sigmoidf_(float x) { return 1.0f / (1.0f + __expf(-x)); }
__device__ __forceinline__ ushort f2bf(float x) {
    __hip_bfloat16 h = __float2bfloat16(x);   // RNE
    return __builtin_bit_cast(ushort, h);
}
// m204 bijective XCD-chunked swizzle (8 XCDs)
__device__ __forceinline__ int xcd_swz(int bid, int nwg) {
    const int q = nwg >> 3, r = nwg & 7;
    const int xcd = bid & 7, idx = bid >> 3;
    return (xcd < r ? xcd * (q + 1) : r * (q + 1) + (xcd - r) * q) + idx;
}
// block-local edge permutation: swap bits[3:2] <-> bits[5:4] (involution).
__device__ __forceinline__ int gperm(int l) {
    return (l & ~63) | (((l >> 2) & 3) << 4) | (((l >> 4) & 3) << 2) | (l & 3);
}
__device__ __forceinline__ void gload_lds16(const void* g, void* l) {
    __builtin_amdgcn_global_load_lds((const __attribute__((address_space(1))) void*)g,
                                     (__attribute__((address_space(3))) void*)l, 16, 0, 0);
}

// ws layout (N read on device):
//   float aggL[N*128]; float aggR[N*128]; float rd[N];
//   int ideg[N]; int ioff[N+1]; int icur[N]; int elist[E]; int epos[E];
//   ushort WgF[16*4*64*8]; ushort W1F[8*8*64*8];
//   float gwb[384] (gL@W1top[128], gR@W1bot[128], b@W1+b1[128]);
//   float nstL[2N]; float nstR[2N]
//   ... tail of ws: ushort ynb[(E+128)*128]  (LN'd y, bf16, permuted-sorted order)
// NOTE: after gates completes, aggL/aggR are transformed IN PLACE into uL/uR by node_mlp.
struct WsPtrs {
    float *aggL, *aggR, *rd;
    int *ideg, *ioff, *icur, *elist, *epos;
    ushort *WgF, *W1F;
    float *gwb, *nstL, *nstR;
    int N;
};
__device__ __forceinline__ WsPtrs ws_ptrs(float* ws, const int* n_nodes_p, int E) {
    WsPtrs p;
    p.N    = *n_nodes_p;
    p.aggL = ws;
    p.aggR = ws + (size_t)p.N * 128;
    p.rd   = ws + (size_t)p.N * 256;
    p.ideg = (int*)(ws + (size_t)p.N * 257);
    p.ioff = p.ideg + p.N;
    p.icur = p.ioff + p.N + 1;
    p.elist = p.icur + p.N;
    p.epos  = p.elist + E;
    p.WgF = (ushort*)(((uintptr_t)(p.epos + E) + 15) & ~(uintptr_t)15);
    p.W1F = p.WgF + 32768;
    p.gwb = (float*)(p.W1F + 32768);
    p.nstL = p.gwb + 384;
    p.nstR = p.nstL + 2 * p.N;
    return p;
}

// ---------------- zero agg + deg ----------------
__global__ void init_kernel(float* __restrict__ ws, const int* __restrict__ n_nodes_p, int E) {
    WsPtrs p = ws_ptrs(ws, n_nodes_p, E);
    const long long stride = (long long)gridDim.x * blockDim.x;
    const long long tid = (long long)blockIdx.x * blockDim.x + threadIdx.x;
    const long long nf = (long long)p.N * 256;
    for (long long i = tid; i < nf; i += stride) ws[i] = 0.0f;
    for (long long i = tid; i < p.N; i += stride) p.ideg[i] = 0;
}

// ---------------- histogram of dst ----------------
__global__ void hist_kernel(const int* __restrict__ dst, float* __restrict__ ws,
                            const int* __restrict__ n_nodes_p, int E) {
    WsPtrs p = ws_ptrs(ws, n_nodes_p, E);
    const int i = blockIdx.x * blockDim.x + threadIdx.x;
    if (i < E) atomicAdd(&p.ideg[dst[i]], 1);
}

// ---------------- exclusive scan (single block) + rd = 1/max(deg,1) ----------------
__global__ __launch_bounds__(256) void scan_kernel(float* __restrict__ ws,
                                                   const int* __restrict__ n_nodes_p, int E) {
    WsPtrs p = ws_ptrs(ws, n_nodes_p, E);
    __shared__ int wsum[4];
    __shared__ int carry_s;
    const int t = threadIdx.x;
    const int lane = t & 63, wid = t >> 6;
    if (t == 0) carry_s = 0;
    __syncthreads();
    for (int base = 0; base < p.N; base += 1024) {
        const int i0 = base + t * 4;
        const int v0 = (i0 + 0 < p.N) ? p.ideg[i0 + 0] : 0;
        const int v1 = (i0 + 1 < p.N) ? p.ideg[i0 + 1] : 0;
        const int v2 = (i0 + 2 < p.N) ? p.ideg[i0 + 2] : 0;
        const int v3 = (i0 + 3 < p.N) ? p.ideg[i0 + 3] : 0;
        const int s = v0 + v1 + v2 + v3;
        int sc = s;
        #pragma unroll
        for (int off = 1; off < 64; off <<= 1) {
            const int n = __shfl_up(sc, off);
            if (lane >= off) sc += n;
        }
        if (lane == 63) wsum[wid] = sc;
        __syncthreads();
        int woff = 0;
        #pragma unroll
        for (int w = 0; w < 4; ++w) if (w < wid) woff += wsum[w];
        const int carry = carry_s;
        __syncthreads();
        const int excl = carry + woff + (sc - s);
        if (i0 + 0 < p.N) { p.ioff[i0+0] = excl;          p.icur[i0+0] = excl;          p.rd[i0+0] = 1.0f / fmaxf((float)v0, 1.0f); }
        if (i0 + 1 < p.N) { p.ioff[i0+1] = excl+v0;       p.icur[i0+1] = excl+v0;       p.rd[i0+1] = 1.0f / fmaxf((float)v1, 1.0f); }
        if (i0 + 2 < p.N) { p.ioff[i0+2] = excl+v0+v1;    p.icur[i0+2] = excl+v0+v1;    p.rd[i0+2] = 1.0f / fmaxf((float)v2, 1.0f); }
        if (i0 + 3 < p.N) { p.ioff[i0+3] = excl+v0+v1+v2; p.icur[i0+3] = excl+v0+v1+v2; p.rd[i0+3] = 1.0f / fmaxf((float)v3, 1.0f); }
        if (t == 255) carry_s = carry + woff + sc;
        __syncthreads();
    }
    if (t == 0) p.ioff[p.N] = carry_s;
}

// ---------------- scatter edge ids into buckets ----------------
__global__ void scatter_kernel(const int* __restrict__ dst, float* __restrict__ ws,
                               const int* __restrict__ n_nodes_p, int E) {
    WsPtrs p = ws_ptrs(ws, n_nodes_p, E);
    const int i = blockIdx.x * blockDim.x + threadIdx.x;
    if (i < E) {
        const int pos = atomicAdd(&p.icur[dst[i]], 1);
        p.elist[pos] = i;
    }
}

// ---------------- per-bucket insertion sort + inverse (permuted) position map ----------------
__global__ void bsort_kernel(float* __restrict__ ws, const int* __restrict__ n_nodes_p, int E) {
    WsPtrs p = ws_ptrs(ws, n_nodes_p, E);
    const int stride = gridDim.x * blockDim.x;
    for (int i = blockIdx.x * blockDim.x + threadIdx.x; i < p.N; i += stride) {
        const int beg = p.ioff[i], end = p.ioff[i + 1];
        for (int a = beg + 1; a < end; ++a) {
            const int key = p.elist[a];
            int b = a - 1;
            while (b >= beg && p.elist[b] > key) { p.elist[b + 1] = p.elist[b]; --b; }
            p.elist[b + 1] = key;
        }
        for (int a = beg; a < end; ++a)
            p.epos[p.elist[a]] = (a & ~63) | gperm(a & 63);
    }
}

// ---------------- build fragment-major bf16 B tables + split gW1 halves + bW1 ----------------
__global__ void prep_w_kernel(const float* __restrict__ Wl, const float* __restrict__ Wr,
                              const float* __restrict__ W1,
                              const float* __restrict__ ln2_g, const float* __restrict__ ln2_b,
                              const float* __restrict__ b1,
                              float* __restrict__ ws, const int* __restrict__ n_nodes_p, int E) {
    WsPtrs p = ws_ptrs(ws, n_nodes_p, E);
    const int i = blockIdx.x * blockDim.x + threadIdx.x;
    if (i < 32768) {
        const int i8 = i & 7, lane = (i >> 3) & 63, kf = (i >> 9) & 3, nblk = i >> 11;
        const int k = kf * 32 + (lane >> 4) * 8 + i8;
        const int n = nblk * 16 + (lane & 15);
        const float val = (n < 128) ? Wl[k * 128 + n] : Wr[k * 128 + (n - 128)];
        p.WgF[i] = f2bf(val);
    } else if (i < 65536) {
        const int j = i - 32768;
        const int i8 = j & 7, lane = (j >> 3) & 63, kf = (j >> 9) & 7, nblk = j >> 12;
        const int k = kf * 32 + (lane >> 4) * 8 + i8;
        const int n = nblk * 16 + (lane & 15);
        p.W1F[j] = f2bf(W1[k * 128 + n]);
    } else if (i < 65664) {
        const int j = i - 65536;   // 0..127
        float gsL = 0.f, gsR = 0.f, bs = 0.f;
        for (int k = 0; k < 128; ++k) {
            const float wt = W1[k * 128 + j];
            const float wb = W1[(k + 128) * 128 + j];
            gsL += ln2_g[k] * wt;
            gsR += ln2_g[k + 128] * wb;
            bs  += ln2_b[k] * wt + ln2_b[k + 128] * wb;
        }
        p.gwb[j]       = gsL;
        p.gwb[128 + j] = gsR;
        p.gwb[256 + j] = bs + b1[j];
    }
}

// ---------------- streaming LN(y) -> bf16, scatter-write to permuted-sorted order ----------------
__global__ __launch_bounds__(256) void ln_y_kernel(
    const float* __restrict__ y,
    const float* __restrict__ ln_g, const float* __restrict__ ln_b,
    float* __restrict__ ws, const int* __restrict__ n_nodes_p, int E,
    ushort* __restrict__ ynb)
{
    WsPtrs p = ws_ptrs(ws, n_nodes_p, E);
    const int t = threadIdx.x;
    const int e = blockIdx.x * 64 + (t >> 2);
    const int sub = t & 3;
    if (e >= E) return;

    const float* yr = y + (size_t)e * 128;
    float v[32];
    float s = 0.f, sq = 0.f;
    #pragma unroll
    for (int i = 0; i < 8; ++i) {
        const float4 q = *reinterpret_cast<const float4*>(yr + sub * 32 + i * 4);
        v[i*4+0] = q.x; v[i*4+1] = q.y; v[i*4+2] = q.z; v[i*4+3] = q.w;
        s  += q.x + q.y + q.z + q.w;
        sq += q.x*q.x + q.y*q.y + q.z*q.z + q.w*q.w;
    }
    s  += __shfl_xor(s, 1);  s  += __shfl_xor(s, 2);
    sq += __shfl_xor(sq, 1); sq += __shfl_xor(sq, 2);
    const float mu = s * (1.f / 128.f);
    const float rstd = rsqrtf(sq * (1.f / 128.f) - mu * mu + LN_EPS);

    ushort* dstrow = ynb + (size_t)p.epos[e] * 128 + sub * 32;
    #pragma unroll
    for (int i = 0; i < 4; ++i) {
        uint w32[4];
        #pragma unroll
        for (int h2 = 0; h2 < 4; ++h2) {
            const int c = sub * 32 + i * 8 + h2 * 2;
            const float x0 = (v[i*8 + h2*2 + 0] - mu) * rstd * ln_g[c + 0] + ln_b[c + 0];
            const float x1 = (v[i*8 + h2*2 + 1] - mu) * rstd * ln_g[c + 1] + ln_b[c + 1];
            w32[h2] = (uint)f2bf(x0) | ((uint)f2bf(x1) << 16);
        }
        *reinterpret_cast<uint4*>(dstrow + i * 8) = make_uint4(w32[0], w32[1], w32[2], w32[3]);
    }
}

// ---------------- gates: MFMA dual-gate GEMM + sigmoid + compressed scatter ----------------
__global__ __launch_bounds__(512) void gates_kernel(
    const float* __restrict__ y, const int* __restrict__ dst,
    const float* __restrict__ ln_g, const float* __restrict__ ln_b,
    const float* __restrict__ bl, const float* __restrict__ br,
    float* __restrict__ ws, const int* __restrict__ n_nodes_p, int E,
    const ushort* __restrict__ ynb)
{
    __shared__ ushort sA[128 * 128];   // 32 KB
    __shared__ int sNode[128];

    WsPtrs p = ws_ptrs(ws, n_nodes_p, E);
    char* sAb = reinterpret_cast<char*>(sA);
    const int t = threadIdx.x;
    const int bid = xcd_swz(blockIdx.x, gridDim.x);
    const int s0 = bid * 128;
    const int lane = t & 63;
    const int w8 = t >> 6;

    if (t < 128) {
        const int j = s0 + t;
        const int eid = (j < E) ? p.elist[j] : -1;
        sNode[t] = (eid >= 0) ? dst[eid] : -1;
    }

    if (ynb) {
        const char* ybase = (const char*)ynb + (size_t)s0 * 256;
        #pragma unroll
        for (int i = 0; i < 4; ++i) {
            const int chunk = w8 + i * 8;
            const int L = chunk * 1024 + lane * 16;
            const int b = L ^ (((L >> 8) & 7) << 4);
            gload_lds16(ybase + b, sAb + chunk * 1024);
        }
    } else {
        const int r = t >> 2, sub = t & 3;
        const int je = s0 + gperm(r);
        const int eid = (je < E) ? p.elist[je] : 0;
        const float* yr = y + (size_t)eid * 128;
        float v[32];
        float s = 0.f, sq = 0.f;
        #pragma unroll
        for (int i = 0; i < 8; ++i) {
            const float4 q = *reinterpret_cast<const float4*>(yr + sub * 32 + i * 4);
            v[i*4+0] = q.x; v[i*4+1] = q.y; v[i*4+2] = q.z; v[i*4+3] = q.w;
            s  += q.x + q.y + q.z + q.w;
            sq += q.x*q.x + q.y*q.y + q.z*q.z + q.w*q.w;
        }
        s  += __shfl_xor(s, 1);  s  += __shfl_xor(s, 2);
        sq += __shfl_xor(sq, 1); sq += __shfl_xor(sq, 2);
        const float mu = s * (1.f / 128.f);
        const float rstd = rsqrtf(sq * (1.f / 128.f) - mu * mu + LN_EPS);
        #pragma unroll
        for (int i = 0; i < 4; ++i) {
            uint w32[4];
            #pragma unroll
            for (int h2 = 0; h2 < 4; ++h2) {
                const int c = sub * 32 + i * 8 + h2 * 2;
                const float x0 = (v[i*8 + h2*2 + 0] - mu) * rstd * ln_g[c + 0] + ln_b[c + 0];
                const float x1 = (v[i*8 + h2*2 + 1] - mu) * rstd * ln_g[c + 1] + ln_b[c + 1];
                w32[h2] = (uint)f2bf(x0) | ((uint)f2bf(x1) << 16);
            }
            int byte = r * 256 + sub * 64 + i * 16;
            byte ^= ((byte >> 8) & 7) << 4;
            *reinterpret_cast<uint4*>(sAb + byte) = make_uint4(w32[0], w32[1], w32[2], w32[3]);
        }
    }
    __syncthreads();

    const int rowh = w8 >> 2, colw = w8 & 3;
    const int lhi = lane >> 4, llo = lane & 15;

    f32x4 acc[4][4];
    #pragma unroll
    for (int m = 0; m < 4; ++m)
        #pragma unroll
        for (int n = 0; n < 4; ++n) acc[m][n] = (f32x4){0.f, 0.f, 0.f, 0.f};

    #pragma unroll
    for (int kf = 0; kf < 4; ++kf) {
        bf16x8 a[4], b[4];
        #pragma unroll
        for (int m = 0; m < 4; ++m) {
            const int row = rowh * 64 + m * 16 + llo;
            int byte = row * 256 + kf * 64 + lhi * 16;
            byte ^= ((byte >> 8) & 7) << 4;
            a[m] = *reinterpret_cast<const bf16x8*>(sAb + byte);
        }
        #pragma unroll
        for (int nf = 0; nf < 4; ++nf) {
            const int nblk = colw * 4 + nf;
            b[nf] = *reinterpret_cast<const bf16x8*>(p.WgF + ((size_t)(nblk * 4 + kf) * 64 + lane) * 8);
        }
        #pragma unroll
        for (int m = 0; m < 4; ++m)
            #pragma unroll
            for (int nf = 0; nf < 4; ++nf)
                acc[m][nf] = __builtin_amdgcn_mfma_f32_16x16x32_bf16(a[m], b[nf], acc[m][nf], 0, 0, 0);
    }

    const int g = colw >> 1;
    float* ag = g ? p.aggR : p.aggL;
    const float* bp = g ? br : bl;
    #pragma unroll
    for (int nf = 0; nf < 4; ++nf) {
        const int col = colw * 64 + nf * 16 + llo;
        const int lcol = col & 127;
        const float bias = bp[lcol];
        float runv = 0.f;
        int rnode = -1;
        #pragma unroll
        for (int m = 0; m < 4; ++m) {
            #pragma unroll
            for (int j = 0; j < 4; ++j) {
                const int el = rowh * 64 + lhi * 16 + m * 4 + j;
                const int node = sNode[el];
                const float val = sigmoidf_(acc[m][nf][j] + bias);
                if (node != rnode) {
                    if (rnode >= 0) atomicAdd(ag + (size_t)rnode * 128 + lcol, runv);
                    rnode = node;
                    runv = val;
                } else {
                    runv += val;
                }
            }
        }
        if (rnode >= 0) atomicAdd(ag + (size_t)rnode * 128 + lcol, runv);
    }
}

// ---------------- node_mlp: uL/uR = ((z - mu_node) ⊙ g2) @ W1half, IN PLACE; stats ----------------
// 512 threads (8 waves), 128 node rows/block (contiguous — zero gathers).
// z = agg*rd. Centering by the per-node half-mean keeps rstd amplification off the
// bf16 quantization (round-7 failure mode). Stats (sum, sumsq of z) feed edge-level LN.
// sA: [128 rows][256 cols] bf16, XOR-swizzle ((byte>>9)&7)<<4.
__global__ __launch_bounds__(512) void node_mlp_kernel(
    const float* __restrict__ ln2_g,
    float* __restrict__ ws, const int* __restrict__ n_nodes_p, int E)
{
    __shared__ ushort sA[128 * 256];   // 64 KB

    WsPtrs p = ws_ptrs(ws, n_nodes_p, E);
    char* sAb = reinterpret_cast<char*>(sA);
    const int t = threadIdx.x;
    const int n0 = blockIdx.x * 128;

    // staging + stats: r = t>>2 (row), sub = t&3. sub<2 -> L half, sub>=2 -> R half; 64 cols each.
    {
        const int r = t >> 2, sub = t & 3;
        const int n = n0 + r;
        const bool vld = n < p.N;
        const int nn = vld ? n : (p.N - 1);
        const float* base = ((sub < 2) ? p.aggL : p.aggR) + (size_t)nn * 128 + (sub & 1) * 64;
        const float scale = vld ? p.rd[nn] : 0.f;
        const int cb = ((sub >> 1) << 7) + ((sub & 1) << 6);   // concat col base

        // pass 1: stats of z = agg*scale over this half
        float s = 0.f, sq = 0.f;
        #pragma unroll
        for (int ii = 0; ii < 8; ++ii) {
            const float4 qa = *reinterpret_cast<const float4*>(base + ii * 8);
            const float4 qb = *reinterpret_cast<const float4*>(base + ii * 8 + 4);
            s  += qa.x + qa.y + qa.z + qa.w + qb.x + qb.y + qb.z + qb.w;
            sq += qa.x*qa.x + qa.y*qa.y + qa.z*qa.z + qa.w*qa.w
                + qb.x*qb.x + qb.y*qb.y + qb.z*qb.z + qb.w*qb.w;
        }
        s *= scale; sq *= scale * scale;
        s  += __shfl_xor(s, 1);
        sq += __shfl_xor(sq, 1);
        if (vld && sub == 0) { p.nstL[2*n] = s; p.nstL[2*n+1] = sq; }
        if (vld && sub == 2) { p.nstR[2*n] = s; p.nstR[2*n+1] = sq; }
        const float mu_n = s * (1.f / 128.f);

        // pass 2 (L1-hot re-read): center, scale by g2, quantize
        #pragma unroll
        for (int ii = 0; ii < 8; ++ii) {
            const float4 qa = *reinterpret_cast<const float4*>(base + ii * 8);
            const float4 qb = *reinterpret_cast<const float4*>(base + ii * 8 + 4);
            const float xs[8] = { qa.x*scale - mu_n, qa.y*scale - mu_n, qa.z*scale - mu_n, qa.w*scale - mu_n,
                                  qb.x*scale - mu_n, qb.y*scale - mu_n, qb.z*scale - mu_n, qb.w*scale - mu_n };
            uint w32[4];
            #pragma unroll
            for (int h2 = 0; h2 < 4; ++h2) {
                const int c = cb + ii * 8 + h2 * 2;
                w32[h2] = (uint)f2bf(xs[h2*2+0] * ln2_g[c+0]) |
                          ((uint)f2bf(xs[h2*2+1] * ln2_g[c+1]) << 16);
            }
            int byte = r * 512 + cb * 2 + ii * 16;
            byte ^= ((byte >> 9) & 7) << 4;
            *reinterpret_cast<uint4*>(sAb + byte) = make_uint4(w32[0], w32[1], w32[2], w32[3]);
        }
    }
    __syncthreads();

    const int lane = t & 63;
    const int w8 = t >> 6;
    const int rowh = w8 >> 2, colw = w8 & 3;
    const int half = colw >> 1;                  // 0 -> uL, 1 -> uR
    const int lhi = lane >> 4, llo = lane & 15;

    f32x4 acc[4][4];
    #pragma unroll
    for (int m = 0; m < 4; ++m)
        #pragma unroll
        for (int n = 0; n < 4; ++n) acc[m][n] = (f32x4){0.f, 0.f, 0.f, 0.f};

    #pragma unroll
    for (int kfl = 0; kfl < 4; ++kfl) {
        bf16x8 a[4], b[4];
        #pragma unroll
        for (int m = 0; m < 4; ++m) {
            const int row = rowh * 64 + m * 16 + llo;
            int byte = row * 512 + half * 256 + kfl * 64 + lhi * 16;
            byte ^= ((byte >> 9) & 7) << 4;
            a[m] = *reinterpret_cast<const bf16x8*>(sAb + byte);
        }
        #pragma unroll
        for (int nf = 0; nf < 4; ++nf) {
            const int nblk = (colw & 1) * 4 + nf;
            const int kf = half * 4 + kfl;
            b[nf] = *reinterpret_cast<const bf16x8*>(p.W1F + ((size_t)(nblk * 8 + kf) * 64 + lane) * 8);
        }
        #pragma unroll
        for (int m = 0; m < 4; ++m)
            #pragma unroll
            for (int nf = 0; nf < 4; ++nf)
                acc[m][nf] = __builtin_amdgcn_mfma_f32_16x16x32_bf16(a[m], b[nf], acc[m][nf], 0, 0, 0);
    }

    // write uL/uR in place over aggL/aggR. D: col=llo, row=lhi*4+j (within 16x16 frag).
    float* u = half ? p.aggR : p.aggL;
    #pragma unroll
    for (int m = 0; m < 4; ++m) {
        #pragma unroll
        for (int j = 0; j < 4; ++j) {
            const int n = n0 + rowh * 64 + m * 16 + lhi * 4 + j;
            if (n < p.N) {
                const int col = (colw & 1) * 64 + llo;
                #pragma unroll
                for (int nf = 0; nf < 4; ++nf)
                    u[(size_t)n * 128 + col + nf * 16] = acc[m][nf][j];
            }
        }
    }
}

// ---------------- edge_out: h1 = rstd*(uL[s]+uR[d] + dL*gwL + dR*gwR) + bW1; ELU; dot W2 ----------------
__global__ __launch_bounds__(256) void edge_out_kernel(
    const int* __restrict__ src, const int* __restrict__ dst,
    const float* __restrict__ W2, const float* __restrict__ b2,
    float* __restrict__ ws, const int* __restrict__ n_nodes_p,
    float* __restrict__ out, int E)
{
    WsPtrs p = ws_ptrs(ws, n_nodes_p, E);
    const float* uL = p.aggL;
    const float* uR = p.aggR;
    const int t = threadIdx.x;
    const int lane = t & 63;
    const int wv = blockIdx.x * 4 + (t >> 6);
    const int nw = gridDim.x * 4;
    const int span = (E + nw - 1) / nw;
    const int j0 = wv * span;
    const int j1 = min(E, j0 + span);

    const float2 gwl = *reinterpret_cast<const float2*>(p.gwb + lane * 2);
    const float2 gwr = *reinterpret_cast<const float2*>(p.gwb + 128 + lane * 2);
    const float2 bw  = *reinterpret_cast<const float2*>(p.gwb + 256 + lane * 2);
    const float2 w2  = *reinterpret_cast<const float2*>(W2 + lane * 2);
    const float b2v = b2[0];

    for (int j = j0; j < j1; ++j) {
        const int eid = p.elist[j];
        const int s = src[eid], d = dst[eid];
        const float2 ul = *reinterpret_cast<const float2*>(uL + (size_t)s * 128 + lane * 2);
        const float2 ur = *reinterpret_cast<const float2*>(uR + (size_t)d * 128 + lane * 2);
        const float2 nsl = *reinterpret_cast<const float2*>(p.nstL + 2 * s);
        const float2 nsr = *reinterpret_cast<const float2*>(p.nstR + 2 * d);
        const float mu = (nsl.x + nsr.x) * (1.f / 256.f);
        const float var = (nsl.y + nsr.y) * (1.f / 256.f) - mu * mu;
        const float rstd = rsqrtf(var + LN_EPS);
        const float dL = nsl.x * (1.f / 128.f) - mu;
        const float dR = nsr.x * (1.f / 128.f) - mu;
        float x0 = rstd * (ul.x + ur.x + dL * gwl.x + dR * gwr.x) + bw.x;
        float x1 = rstd * (ul.y + ur.y + dL * gwl.y + dR * gwr.y) + bw.y;
        x0 = x0 > 0.f ? x0 : __expf(x0) - 1.f;
        x1 = x1 > 0.f ? x1 : __expf(x1) - 1.f;
        float acc = x0 * w2.x + x1 * w2.y;
        #pragma unroll
        for (int m = 32; m >= 1; m >>= 1) acc += __shfl_xor(acc, m);
        if (lane == 0) out[eid] = acc + b2v;
    }
}

extern "C" void kernel_launch(void* const* d_in, const int* in_sizes, int n_in,
                              void* d_out, int out_size, void* d_ws, size_t ws_size,
                              hipStream_t stream) {
    const float* y       = (const float*)d_in[0];
    const int*   src     = (const int*)d_in[1];
    const int*   dst     = (const int*)d_in[2];
    const int*   n_nodes = (const int*)d_in[3];
    const float* ln_g    = (const float*)d_in[4];
    const float* ln_b    = (const float*)d_in[5];
    const float* Wl      = (const float*)d_in[6];
    const float* bl      = (const float*)d_in[7];
    const float* Wr      = (const float*)d_in[8];
    const float* br      = (const float*)d_in[9];
    const float* ln2_g   = (const float*)d_in[10];
    const float* ln2_b   = (const float*)d_in[11];
    const float* W1      = (const float*)d_in[12];
    const float* b1      = (const float*)d_in[13];
    const float* W2      = (const float*)d_in[14];
    const float* b2      = (const float*)d_in[15];
    float* out = (float*)d_out;
    float* ws  = (float*)d_ws;

    const int E = in_sizes[0] / 128;
    const int eb = (E + 127) / 128;
    const int N_MAX = 40000;   // grid sizing only; device code reads *n_nodes

    const size_t need = (size_t)(E + 128) * 256;
    const bool use_pre = ws_size >= need + (96ull << 20);
    ushort* ynb = use_pre
        ? (ushort*)(((uintptr_t)ws + ws_size - need) & ~(uintptr_t)255)
        : nullptr;

    init_kernel<<<2048, 256, 0, stream>>>(ws, n_nodes, E);
    hist_kernel<<<(E + 255) / 256, 256, 0, stream>>>(dst, ws, n_nodes, E);
    scan_kernel<<<1, 256, 0, stream>>>(ws, n_nodes, E);
    scatter_kernel<<<(E + 255) / 256, 256, 0, stream>>>(dst, ws, n_nodes, E);
    bsort_kernel<<<512, 256, 0, stream>>>(ws, n_nodes, E);
    prep_w_kernel<<<257, 256, 0, stream>>>(Wl, Wr, W1, ln2_g, ln2_b, b1, ws, n_nodes, E);
    if (use_pre)
        ln_y_kernel<<<(E + 63) / 64, 256, 0, stream>>>(y, ln_g, ln_b, ws, n_nodes, E, ynb);
    gates_kernel<<<eb, 512, 0, stream>>>(y, dst, ln_g, ln_b, bl, br, ws, n_nodes, E, ynb);
    node_mlp_kernel<<<(N_MAX + 127) / 128, 512, 0, stream>>>(ln2_g, ws, n_nodes, E);
    edge_out_kernel<<<2048, 256, 0, stream>>>(src, dst, W2, b2, ws, n_nodes, out, E);
}

// Round 9
// 637.021 us; speedup vs baseline: 1.3083x; 1.0692x over previous
//
#include <hip/hip_runtime.h>
#include <hip/hip_bf16.h>

#define LN_EPS 1e-5f

typedef __attribute__((ext_vector_type(8))) short bf16x8;
typedef __attribute__((ext_vector_type(4))) float f32x4;

__device__ __forceinline__ float sigmoidf_(float x) { return 1.0f / (1.0f + __expf(-x)); }
__device__ __forceinline__ ushort f2bf(float x) {
    __hip_bfloat16 h = __float2bfloat16(x);   // RNE
    return __builtin_bit_cast(ushort, h);
}
// m204 bijective XCD-chunked swizzle (8 XCDs)
__device__ __forceinline__ int xcd_swz(int bid, int nwg) {
    const int q = nwg >> 3, r = nwg & 7;
    const int xcd = bid & 7, idx = bid >> 3;
    return (xcd < r ? xcd * (q + 1) : r * (q + 1) + (xcd - r) * q) + idx;
}
// block-local edge permutation: swap bits[3:2] <-> bits[5:4] (involution).
__device__ __forceinline__ int gperm(int l) {
    return (l & ~63) | (((l >> 2) & 3) << 4) | (((l >> 4) & 3) << 2) | (l & 3);
}
__device__ __forceinline__ void gload_lds16(const void* g, void* l) {
    __builtin_amdgcn_global_load_lds((const __attribute__((address_space(1))) void*)g,
                                     (__attribute__((address_space(3))) void*)l, 16, 0, 0);
}

// ws layout (N read on device):
//   float aggL[N*128]; float aggR[N*128]; float rd[N];
//   int ideg[N]; int ioff[N+1]; int icur[N]; int elist[E]; int epos[E];
//   ushort WgF[16*4*64*8]; ushort W1F[8*8*64*8];
//   float gwb[384] (gL@W1top[128], gR@W1bot[128], b@W1+b1[128]);
//   float nstL[2N]; float nstR[2N]
//   ... tail of ws: ushort ynb[(E+128)*128]  (LN'd y, bf16, permuted-sorted order)
// NOTE: node_mlp overwrites the FIRST 256B of each 512B agg row with the bf16 u row
// (per-block self-overwrite only, after all of that block's reads).
struct WsPtrs {
    float *aggL, *aggR, *rd;
    int *ideg, *ioff, *icur, *elist, *epos;
    ushort *WgF, *W1F;
    float *gwb, *nstL, *nstR;
    int N;
};
__device__ __forceinline__ WsPtrs ws_ptrs(float* ws, const int* n_nodes_p, int E) {
    WsPtrs p;
    p.N    = *n_nodes_p;
    p.aggL = ws;
    p.aggR = ws + (size_t)p.N * 128;
    p.rd   = ws + (size_t)p.N * 256;
    p.ideg = (int*)(ws + (size_t)p.N * 257);
    p.ioff = p.ideg + p.N;
    p.icur = p.ioff + p.N + 1;
    p.elist = p.icur + p.N;
    p.epos  = p.elist + E;
    p.WgF = (ushort*)(((uintptr_t)(p.epos + E) + 15) & ~(uintptr_t)15);
    p.W1F = p.WgF + 32768;
    p.gwb = (float*)(p.W1F + 32768);
    p.nstL = p.gwb + 384;
    p.nstR = p.nstL + 2 * p.N;
    return p;
}

// ---------------- zero agg + deg ----------------
__global__ void init_kernel(float* __restrict__ ws, const int* __restrict__ n_nodes_p, int E) {
    WsPtrs p = ws_ptrs(ws, n_nodes_p, E);
    const long long stride = (long long)gridDim.x * blockDim.x;
    const long long tid = (long long)blockIdx.x * blockDim.x + threadIdx.x;
    const long long nf = (long long)p.N * 256;
    for (long long i = tid; i < nf; i += stride) ws[i] = 0.0f;
    for (long long i = tid; i < p.N; i += stride) p.ideg[i] = 0;
}

// ---------------- histogram of dst ----------------
__global__ void hist_kernel(const int* __restrict__ dst, float* __restrict__ ws,
                            const int* __restrict__ n_nodes_p, int E) {
    WsPtrs p = ws_ptrs(ws, n_nodes_p, E);
    const int i = blockIdx.x * blockDim.x + threadIdx.x;
    if (i < E) atomicAdd(&p.ideg[dst[i]], 1);
}

// ---------------- exclusive scan (single block) + rd = 1/max(deg,1) ----------------
__global__ __launch_bounds__(256) void scan_kernel(float* __restrict__ ws,
                                                   const int* __restrict__ n_nodes_p, int E) {
    WsPtrs p = ws_ptrs(ws, n_nodes_p, E);
    __shared__ int wsum[4];
    __shared__ int carry_s;
    const int t = threadIdx.x;
    const int lane = t & 63, wid = t >> 6;
    if (t == 0) carry_s = 0;
    __syncthreads();
    for (int base = 0; base < p.N; base += 1024) {
        const int i0 = base + t * 4;
        const int v0 = (i0 + 0 < p.N) ? p.ideg[i0 + 0] : 0;
        const int v1 = (i0 + 1 < p.N) ? p.ideg[i0 + 1] : 0;
        const int v2 = (i0 + 2 < p.N) ? p.ideg[i0 + 2] : 0;
        const int v3 = (i0 + 3 < p.N) ? p.ideg[i0 + 3] : 0;
        const int s = v0 + v1 + v2 + v3;
        int sc = s;
        #pragma unroll
        for (int off = 1; off < 64; off <<= 1) {
            const int n = __shfl_up(sc, off);
            if (lane >= off) sc += n;
        }
        if (lane == 63) wsum[wid] = sc;
        __syncthreads();
        int woff = 0;
        #pragma unroll
        for (int w = 0; w < 4; ++w) if (w < wid) woff += wsum[w];
        const int carry = carry_s;
        __syncthreads();
        const int excl = carry + woff + (sc - s);
        if (i0 + 0 < p.N) { p.ioff[i0+0] = excl;          p.icur[i0+0] = excl;          p.rd[i0+0] = 1.0f / fmaxf((float)v0, 1.0f); }
        if (i0 + 1 < p.N) { p.ioff[i0+1] = excl+v0;       p.icur[i0+1] = excl+v0;       p.rd[i0+1] = 1.0f / fmaxf((float)v1, 1.0f); }
        if (i0 + 2 < p.N) { p.ioff[i0+2] = excl+v0+v1;    p.icur[i0+2] = excl+v0+v1;    p.rd[i0+2] = 1.0f / fmaxf((float)v2, 1.0f); }
        if (i0 + 3 < p.N) { p.ioff[i0+3] = excl+v0+v1+v2; p.icur[i0+3] = excl+v0+v1+v2; p.rd[i0+3] = 1.0f / fmaxf((float)v3, 1.0f); }
        if (t == 255) carry_s = carry + woff + sc;
        __syncthreads();
    }
    if (t == 0) p.ioff[p.N] = carry_s;
}

// ---------------- scatter edge ids into buckets + position map ----------------
// Intra-bucket order is atomic-arrival order: all entries in a bucket share the same
// dst, so run-compression in gates behaves identically to a sorted list. (The former
// per-bucket insertion sort only reordered fp-add sequences within the tolerance.)
__global__ void scatter_kernel(const int* __restrict__ dst, float* __restrict__ ws,
                               const int* __restrict__ n_nodes_p, int E) {
    WsPtrs p = ws_ptrs(ws, n_nodes_p, E);
    const int i = blockIdx.x * blockDim.x + threadIdx.x;
    if (i < E) {
        const int pos = atomicAdd(&p.icur[dst[i]], 1);
        p.elist[pos] = i;
        p.epos[i] = (pos & ~63) | gperm(pos & 63);
    }
}

// ---------------- build fragment-major bf16 B tables + split gW1 halves + bW1 ----------------
__global__ void prep_w_kernel(const float* __restrict__ Wl, const float* __restrict__ Wr,
                              const float* __restrict__ W1,
                              const float* __restrict__ ln2_g, const float* __restrict__ ln2_b,
                              const float* __restrict__ b1,
                              float* __restrict__ ws, const int* __restrict__ n_nodes_p, int E) {
    WsPtrs p = ws_ptrs(ws, n_nodes_p, E);
    const int i = blockIdx.x * blockDim.x + threadIdx.x;
    if (i < 32768) {
        const int i8 = i & 7, lane = (i >> 3) & 63, kf = (i >> 9) & 3, nblk = i >> 11;
        const int k = kf * 32 + (lane >> 4) * 8 + i8;
        const int n = nblk * 16 + (lane & 15);
        const float val = (n < 128) ? Wl[k * 128 + n] : Wr[k * 128 + (n - 128)];
        p.WgF[i] = f2bf(val);
    } else if (i < 65536) {
        const int j = i - 32768;
        const int i8 = j & 7, lane = (j >> 3) & 63, kf = (j >> 9) & 7, nblk = j >> 12;
        const int k = kf * 32 + (lane >> 4) * 8 + i8;
        const int n = nblk * 16 + (lane & 15);
        p.W1F[j] = f2bf(W1[k * 128 + n]);
    } else if (i < 65664) {
        const int j = i - 65536;   // 0..127
        float gsL = 0.f, gsR = 0.f, bs = 0.f;
        for (int k = 0; k < 128; ++k) {
            const float wt = W1[k * 128 + j];
            const float wb = W1[(k + 128) * 128 + j];
            gsL += ln2_g[k] * wt;
            gsR += ln2_g[k + 128] * wb;
            bs  += ln2_b[k] * wt + ln2_b[k + 128] * wb;
        }
        p.gwb[j]       = gsL;
        p.gwb[128 + j] = gsR;
        p.gwb[256 + j] = bs + b1[j];
    }
}

// ---------------- streaming LN(y) -> bf16, scatter-write to permuted-sorted order ----------------
__global__ __launch_bounds__(256) void ln_y_kernel(
    const float* __restrict__ y,
    const float* __restrict__ ln_g, const float* __restrict__ ln_b,
    float* __restrict__ ws, const int* __restrict__ n_nodes_p, int E,
    ushort* __restrict__ ynb)
{
    WsPtrs p = ws_ptrs(ws, n_nodes_p, E);
    const int t = threadIdx.x;
    const int e = blockIdx.x * 64 + (t >> 2);
    const int sub = t & 3;
    if (e >= E) return;

    const float* yr = y + (size_t)e * 128;
    float v[32];
    float s = 0.f, sq = 0.f;
    #pragma unroll
    for (int i = 0; i < 8; ++i) {
        const float4 q = *reinterpret_cast<const float4*>(yr + sub * 32 + i * 4);
        v[i*4+0] = q.x; v[i*4+1] = q.y; v[i*4+2] = q.z; v[i*4+3] = q.w;
        s  += q.x + q.y + q.z + q.w;
        sq += q.x*q.x + q.y*q.y + q.z*q.z + q.w*q.w;
    }
    s  += __shfl_xor(s, 1);  s  += __shfl_xor(s, 2);
    sq += __shfl_xor(sq, 1); sq += __shfl_xor(sq, 2);
    const float mu = s * (1.f / 128.f);
    const float rstd = rsqrtf(sq * (1.f / 128.f) - mu * mu + LN_EPS);

    ushort* dstrow = ynb + (size_t)p.epos[e] * 128 + sub * 32;
    #pragma unroll
    for (int i = 0; i < 4; ++i) {
        uint w32[4];
        #pragma unroll
        for (int h2 = 0; h2 < 4; ++h2) {
            const int c = sub * 32 + i * 8 + h2 * 2;
            const float x0 = (v[i*8 + h2*2 + 0] - mu) * rstd * ln_g[c + 0] + ln_b[c + 0];
            const float x1 = (v[i*8 + h2*2 + 1] - mu) * rstd * ln_g[c + 1] + ln_b[c + 1];
            w32[h2] = (uint)f2bf(x0) | ((uint)f2bf(x1) << 16);
        }
        *reinterpret_cast<uint4*>(dstrow + i * 8) = make_uint4(w32[0], w32[1], w32[2], w32[3]);
    }
}

// ---------------- gates: MFMA dual-gate GEMM + sigmoid + compressed scatter ----------------
__global__ __launch_bounds__(512) void gates_kernel(
    const float* __restrict__ y, const int* __restrict__ dst,
    const float* __restrict__ ln_g, const float* __restrict__ ln_b,
    const float* __restrict__ bl, const float* __restrict__ br,
    float* __restrict__ ws, const int* __restrict__ n_nodes_p, int E,
    const ushort* __restrict__ ynb)
{
    __shared__ ushort sA[128 * 128];   // 32 KB
    __shared__ int sNode[128];

    WsPtrs p = ws_ptrs(ws, n_nodes_p, E);
    char* sAb = reinterpret_cast<char*>(sA);
    const int t = threadIdx.x;
    const int bid = xcd_swz(blockIdx.x, gridDim.x);
    const int s0 = bid * 128;
    const int lane = t & 63;
    const int w8 = t >> 6;

    if (t < 128) {
        const int j = s0 + t;
        const int eid = (j < E) ? p.elist[j] : -1;
        sNode[t] = (eid >= 0) ? dst[eid] : -1;
    }

    if (ynb) {
        const char* ybase = (const char*)ynb + (size_t)s0 * 256;
        #pragma unroll
        for (int i = 0; i < 4; ++i) {
            const int chunk = w8 + i * 8;
            const int L = chunk * 1024 + lane * 16;
            const int b = L ^ (((L >> 8) & 7) << 4);
            gload_lds16(ybase + b, sAb + chunk * 1024);
        }
    } else {
        const int r = t >> 2, sub = t & 3;
        const int je = s0 + gperm(r);
        const int eid = (je < E) ? p.elist[je] : 0;
        const float* yr = y + (size_t)eid * 128;
        float v[32];
        float s = 0.f, sq = 0.f;
        #pragma unroll
        for (int i = 0; i < 8; ++i) {
            const float4 q = *reinterpret_cast<const float4*>(yr + sub * 32 + i * 4);
            v[i*4+0] = q.x; v[i*4+1] = q.y; v[i*4+2] = q.z; v[i*4+3] = q.w;
            s  += q.x + q.y + q.z + q.w;
            sq += q.x*q.x + q.y*q.y + q.z*q.z + q.w*q.w;
        }
        s  += __shfl_xor(s, 1);  s  += __shfl_xor(s, 2);
        sq += __shfl_xor(sq, 1); sq += __shfl_xor(sq, 2);
        const float mu = s * (1.f / 128.f);
        const float rstd = rsqrtf(sq * (1.f / 128.f) - mu * mu + LN_EPS);
        #pragma unroll
        for (int i = 0; i < 4; ++i) {
            uint w32[4];
            #pragma unroll
            for (int h2 = 0; h2 < 4; ++h2) {
                const int c = sub * 32 + i * 8 + h2 * 2;
                const float x0 = (v[i*8 + h2*2 + 0] - mu) * rstd * ln_g[c + 0] + ln_b[c + 0];
                const float x1 = (v[i*8 + h2*2 + 1] - mu) * rstd * ln_g[c + 1] + ln_b[c + 1];
                w32[h2] = (uint)f2bf(x0) | ((uint)f2bf(x1) << 16);
            }
            int byte = r * 256 + sub * 64 + i * 16;
            byte ^= ((byte >> 8) & 7) << 4;
            *reinterpret_cast<uint4*>(sAb + byte) = make_uint4(w32[0], w32[1], w32[2], w32[3]);
        }
    }
    __syncthreads();

    const int rowh = w8 >> 2, colw = w8 & 3;
    const int lhi = lane >> 4, llo = lane & 15;

    f32x4 acc[4][4];
    #pragma unroll
    for (int m = 0; m < 4; ++m)
        #pragma unroll
        for (int n = 0; n < 4; ++n) acc[m][n] = (f32x4){0.f, 0.f, 0.f, 0.f};

    #pragma unroll
    for (int kf = 0; kf < 4; ++kf) {
        bf16x8 a[4], b[4];
        #pragma unroll
        for (int m = 0; m < 4; ++m) {
            const int row = rowh * 64 + m * 16 + llo;
            int byte = row * 256 + kf * 64 + lhi * 16;
            byte ^= ((byte >> 8) & 7) << 4;
            a[m] = *reinterpret_cast<const bf16x8*>(sAb + byte);
        }
        #pragma unroll
        for (int nf = 0; nf < 4; ++nf) {
            const int nblk = colw * 4 + nf;
            b[nf] = *reinterpret_cast<const bf16x8*>(p.WgF + ((size_t)(nblk * 4 + kf) * 64 + lane) * 8);
        }
        #pragma unroll
        for (int m = 0; m < 4; ++m)
            #pragma unroll
            for (int nf = 0; nf < 4; ++nf)
                acc[m][nf] = __builtin_amdgcn_mfma_f32_16x16x32_bf16(a[m], b[nf], acc[m][nf], 0, 0, 0);
    }

    const int g = colw >> 1;
    float* ag = g ? p.aggR : p.aggL;
    const float* bp = g ? br : bl;
    #pragma unroll
    for (int nf = 0; nf < 4; ++nf) {
        const int col = colw * 64 + nf * 16 + llo;
        const int lcol = col & 127;
        const float bias = bp[lcol];
        float runv = 0.f;
        int rnode = -1;
        #pragma unroll
        for (int m = 0; m < 4; ++m) {
            #pragma unroll
            for (int j = 0; j < 4; ++j) {
                const int el = rowh * 64 + lhi * 16 + m * 4 + j;
                const int node = sNode[el];
                const float val = sigmoidf_(acc[m][nf][j] + bias);
                if (node != rnode) {
                    if (rnode >= 0) atomicAdd(ag + (size_t)rnode * 128 + lcol, runv);
                    rnode = node;
                    runv = val;
                } else {
                    runv += val;
                }
            }
        }
        if (rnode >= 0) atomicAdd(ag + (size_t)rnode * 128 + lcol, runv);
    }
}

// ---------------- node_mlp: u = ((z - mu_node) ⊙ g2) @ W1half -> bf16 IN PLACE; stats ----------------
// 512 threads (8 waves), 128 node rows/block (contiguous — zero gathers).
// u written as bf16 into the FIRST 256B of each node's own 512B agg row (row stride 256
// ushorts): only rows this block already fully read pre-barrier are overwritten -> no race.
__global__ __launch_bounds__(512) void node_mlp_kernel(
    const float* __restrict__ ln2_g,
    float* __restrict__ ws, const int* __restrict__ n_nodes_p, int E)
{
    __shared__ ushort sA[128 * 256];   // 64 KB

    WsPtrs p = ws_ptrs(ws, n_nodes_p, E);
    char* sAb = reinterpret_cast<char*>(sA);
    const int t = threadIdx.x;
    const int n0 = blockIdx.x * 128;

    {
        const int r = t >> 2, sub = t & 3;
        const int n = n0 + r;
        const bool vld = n < p.N;
        const int nn = vld ? n : (p.N - 1);
        const float* base = ((sub < 2) ? p.aggL : p.aggR) + (size_t)nn * 128 + (sub & 1) * 64;
        const float scale = vld ? p.rd[nn] : 0.f;
        const int cb = ((sub >> 1) << 7) + ((sub & 1) << 6);   // concat col base

        float s = 0.f, sq = 0.f;
        #pragma unroll
        for (int ii = 0; ii < 8; ++ii) {
            const float4 qa = *reinterpret_cast<const float4*>(base + ii * 8);
            const float4 qb = *reinterpret_cast<const float4*>(base + ii * 8 + 4);
            s  += qa.x + qa.y + qa.z + qa.w + qb.x + qb.y + qb.z + qb.w;
            sq += qa.x*qa.x + qa.y*qa.y + qa.z*qa.z + qa.w*qa.w
                + qb.x*qb.x + qb.y*qb.y + qb.z*qb.z + qb.w*qb.w;
        }
        s *= scale; sq *= scale * scale;
        s  += __shfl_xor(s, 1);
        sq += __shfl_xor(sq, 1);
        if (vld && sub == 0) { p.nstL[2*n] = s; p.nstL[2*n+1] = sq; }
        if (vld && sub == 2) { p.nstR[2*n] = s; p.nstR[2*n+1] = sq; }
        const float mu_n = s * (1.f / 128.f);

        #pragma unroll
        for (int ii = 0; ii < 8; ++ii) {
            const float4 qa = *reinterpret_cast<const float4*>(base + ii * 8);
            const float4 qb = *reinterpret_cast<const float4*>(base + ii * 8 + 4);
            const float xs[8] = { qa.x*scale - mu_n, qa.y*scale - mu_n, qa.z*scale - mu_n, qa.w*scale - mu_n,
                                  qb.x*scale - mu_n, qb.y*scale - mu_n, qb.z*scale - mu_n, qb.w*scale - mu_n };
            uint w32[4];
            #pragma unroll
            for (int h2 = 0; h2 < 4; ++h2) {
                const int c = cb + ii * 8 + h2 * 2;
                w32[h2] = (uint)f2bf(xs[h2*2+0] * ln2_g[c+0]) |
                          ((uint)f2bf(xs[h2*2+1] * ln2_g[c+1]) << 16);
            }
            int byte = r * 512 + cb * 2 + ii * 16;
            byte ^= ((byte >> 9) & 7) << 4;
            *reinterpret_cast<uint4*>(sAb + byte) = make_uint4(w32[0], w32[1], w32[2], w32[3]);
        }
    }
    __syncthreads();

    const int lane = t & 63;
    const int w8 = t >> 6;
    const int rowh = w8 >> 2, colw = w8 & 3;
    const int half = colw >> 1;                  // 0 -> uL, 1 -> uR
    const int lhi = lane >> 4, llo = lane & 15;

    f32x4 acc[4][4];
    #pragma unroll
    for (int m = 0; m < 4; ++m)
        #pragma unroll
        for (int n = 0; n < 4; ++n) acc[m][n] = (f32x4){0.f, 0.f, 0.f, 0.f};

    #pragma unroll
    for (int kfl = 0; kfl < 4; ++kfl) {
        bf16x8 a[4], b[4];
        #pragma unroll
        for (int m = 0; m < 4; ++m) {
            const int row = rowh * 64 + m * 16 + llo;
            int byte = row * 512 + half * 256 + kfl * 64 + lhi * 16;
            byte ^= ((byte >> 9) & 7) << 4;
            a[m] = *reinterpret_cast<const bf16x8*>(sAb + byte);
        }
        #pragma unroll
        for (int nf = 0; nf < 4; ++nf) {
            const int nblk = (colw & 1) * 4 + nf;
            const int kf = half * 4 + kfl;
            b[nf] = *reinterpret_cast<const bf16x8*>(p.W1F + ((size_t)(nblk * 8 + kf) * 64 + lane) * 8);
        }
        #pragma unroll
        for (int m = 0; m < 4; ++m)
            #pragma unroll
            for (int nf = 0; nf < 4; ++nf)
                acc[m][nf] = __builtin_amdgcn_mfma_f32_16x16x32_bf16(a[m], b[nf], acc[m][nf], 0, 0, 0);
    }

    // write u as bf16 into first half of each node's 512B row (row stride = 256 ushorts)
    ushort* u16 = (ushort*)(half ? p.aggR : p.aggL);
    #pragma unroll
    for (int m = 0; m < 4; ++m) {
        #pragma unroll
        for (int j = 0; j < 4; ++j) {
            const int n = n0 + rowh * 64 + m * 16 + lhi * 4 + j;
            if (n < p.N) {
                const int col = (colw & 1) * 64 + llo;
                #pragma unroll
                for (int nf = 0; nf < 4; ++nf)
                    u16[(size_t)n * 256 + col + nf * 16] = f2bf(acc[m][nf][j]);
            }
        }
    }
}

// ---------------- edge_out: h1 = rstd*(uL[s]+uR[d] + dL*gwL + dR*gwR) + bW1; ELU; dot W2 ----------------
__global__ __launch_bounds__(256) void edge_out_kernel(
    const int* __restrict__ src, const int* __restrict__ dst,
    const float* __restrict__ W2, const float* __restrict__ b2,
    float* __restrict__ ws, const int* __restrict__ n_nodes_p,
    float* __restrict__ out, int E)
{
    WsPtrs p = ws_ptrs(ws, n_nodes_p, E);
    const ushort* uLb = (const ushort*)p.aggL;   // bf16 rows, stride 256 ushorts
    const ushort* uRb = (const ushort*)p.aggR;
    const int t = threadIdx.x;
    const int lane = t & 63;
    const int wv = blockIdx.x * 4 + (t >> 6);
    const int nw = gridDim.x * 4;
    const int span = (E + nw - 1) / nw;
    const int j0 = wv * span;
    const int j1 = min(E, j0 + span);

    const float2 gwl = *reinterpret_cast<const float2*>(p.gwb + lane * 2);
    const float2 gwr = *reinterpret_cast<const float2*>(p.gwb + 128 + lane * 2);
    const float2 bw  = *reinterpret_cast<const float2*>(p.gwb + 256 + lane * 2);
    const float2 w2  = *reinterpret_cast<const float2*>(W2 + lane * 2);
    const float b2v = b2[0];

    for (int j = j0; j < j1; ++j) {
        const int eid = p.elist[j];
        const int s = src[eid], d = dst[eid];
        const uint ulp = *reinterpret_cast<const uint*>(uLb + (size_t)s * 256 + lane * 2);
        const uint urp = *reinterpret_cast<const uint*>(uRb + (size_t)d * 256 + lane * 2);
        const float ulx = __builtin_bit_cast(float, ulp << 16);
        const float uly = __builtin_bit_cast(float, ulp & 0xffff0000u);
        const float urx = __builtin_bit_cast(float, urp << 16);
        const float ury = __builtin_bit_cast(float, urp & 0xffff0000u);
        const float2 nsl = *reinterpret_cast<const float2*>(p.nstL + 2 * s);
        const float2 nsr = *reinterpret_cast<const float2*>(p.nstR + 2 * d);
        const float mu = (nsl.x + nsr.x) * (1.f / 256.f);
        const float var = (nsl.y + nsr.y) * (1.f / 256.f) - mu * mu;
        const float rstd = rsqrtf(var + LN_EPS);
        const float dL = nsl.x * (1.f / 128.f) - mu;
        const float dR = nsr.x * (1.f / 128.f) - mu;
        float x0 = rstd * (ulx + urx + dL * gwl.x + dR * gwr.x) + bw.x;
        float x1 = rstd * (uly + ury + dL * gwl.y + dR * gwr.y) + bw.y;
        x0 = x0 > 0.f ? x0 : __expf(x0) - 1.f;
        x1 = x1 > 0.f ? x1 : __expf(x1) - 1.f;
        float acc = x0 * w2.x + x1 * w2.y;
        #pragma unroll
        for (int m = 32; m >= 1; m >>= 1) acc += __shfl_xor(acc, m);
        if (lane == 0) out[eid] = acc + b2v;
    }
}

extern "C" void kernel_launch(void* const* d_in, const int* in_sizes, int n_in,
                              void* d_out, int out_size, void* d_ws, size_t ws_size,
                              hipStream_t stream) {
    const float* y       = (const float*)d_in[0];
    const int*   src     = (const int*)d_in[1];
    const int*   dst     = (const int*)d_in[2];
    const int*   n_nodes = (const int*)d_in[3];
    const float* ln_g    = (const float*)d_in[4];
    const float* ln_b    = (const float*)d_in[5];
    const float* Wl      = (const float*)d_in[6];
    const float* bl      = (const float*)d_in[7];
    const float* Wr      = (const float*)d_in[8];
    const float* br      = (const float*)d_in[9];
    const float* ln2_g   = (const float*)d_in[10];
    const float* ln2_b   = (const float*)d_in[11];
    const float* W1      = (const float*)d_in[12];
    const float* b1      = (const float*)d_in[13];
    const float* W2      = (const float*)d_in[14];
    const float* b2      = (const float*)d_in[15];
    float* out = (float*)d_out;
    float* ws  = (float*)d_ws;

    const int E = in_sizes[0] / 128;
    const int eb = (E + 127) / 128;
    const int N_MAX = 40000;   // grid sizing only; device code reads *n_nodes

    const size_t need = (size_t)(E + 128) * 256;
    const bool use_pre = ws_size >= need + (96ull << 20);
    ushort* ynb = use_pre
        ? (ushort*)(((uintptr_t)ws + ws_size - need) & ~(uintptr_t)255)
        : nullptr;

    init_kernel<<<2048, 256, 0, stream>>>(ws, n_nodes, E);
    hist_kernel<<<(E + 255) / 256, 256, 0, stream>>>(dst, ws, n_nodes, E);
    scan_kernel<<<1, 256, 0, stream>>>(ws, n_nodes, E);
    scatter_kernel<<<(E + 255) / 256, 256, 0, stream>>>(dst, ws, n_nodes, E);
    prep_w_kernel<<<257, 256, 0, stream>>>(Wl, Wr, W1, ln2_g, ln2_b, b1, ws, n_nodes, E);
    if (use_pre)
        ln_y_kernel<<<(E + 63) / 64, 256, 0, stream>>>(y, ln_g, ln_b, ws, n_nodes, E, ynb);
    gates_kernel<<<eb, 512, 0, stream>>>(y, dst, ln_g, ln_b, bl, br, ws, n_nodes, E, ynb);
    node_mlp_kernel<<<(N_MAX + 127) / 128, 512, 0, stream>>>(ln2_g, ws, n_nodes, E);
    edge_out_kernel<<<2048, 256, 0, stream>>>(src, dst, W2, b2, ws, n_nodes, out, E);
}

// Round 10
// 559.977 us; speedup vs baseline: 1.4883x; 1.1376x over previous
//
#include <hip/hip_runtime.h>
#include <hip/hip_bf16.h>

#define LN_EPS 1e-5f

typedef __attribute__((ext_vector_type(8))) short bf16x8;
typedef __attribute__((ext_vector_type(4))) float f32x4;

__device__ __forceinline__ float sigmoid_fast(float x) {
    // rcp(1 + e^-x): v_exp path via __expf, v_rcp_f32 instead of IEEE divide.
    return __builtin_amdgcn_rcpf(1.0f + __expf(-x));
}
__device__ __forceinline__ ushort f2bf(float x) {
    __hip_bfloat16 h = __float2bfloat16(x);   // RNE
    return __builtin_bit_cast(ushort, h);
}
// m204 bijective XCD-chunked swizzle (8 XCDs)
__device__ __forceinline__ int xcd_swz(int bid, int nwg) {
    const int q = nwg >> 3, r = nwg & 7;
    const int xcd = bid & 7, idx = bid >> 3;
    return (xcd < r ? xcd * (q + 1) : r * (q + 1) + (xcd - r) * q) + idx;
}
// block-local edge permutation: swap bits[3:2] <-> bits[5:4] (involution).
__device__ __forceinline__ int gperm(int l) {
    return (l & ~63) | (((l >> 2) & 3) << 4) | (((l >> 4) & 3) << 2) | (l & 3);
}
__device__ __forceinline__ void gload_lds16(const void* g, void* l) {
    __builtin_amdgcn_global_load_lds((const __attribute__((address_space(1))) void*)g,
                                     (__attribute__((address_space(3))) void*)l, 16, 0, 0);
}

// ws layout (N read on device):
//   float aggL[N*128]; float aggR[N*128]; float rd[N];
//   int ideg[N]; int ioff[N+1]; int icur[N]; int elist[E]; int epos[E];
//   ushort WgF[16*4*64*8]; ushort W1F[8*8*64*8];
//   float gwb[384] (gL@W1top[128], gR@W1bot[128], b@W1+b1[128]);
//   float nstL[2N]; float nstR[2N]
//   ... tail of ws: ushort ynb[(E+128)*128]  (LN'd y, bf16, permuted-sorted order)
// NOTE: node_mlp overwrites the FIRST 256B of each 512B agg row with the bf16 u row
// (per-block self-overwrite only, after all of that block's reads).
struct WsPtrs {
    float *aggL, *aggR, *rd;
    int *ideg, *ioff, *icur, *elist, *epos;
    ushort *WgF, *W1F;
    float *gwb, *nstL, *nstR;
    int N;
};
__device__ __forceinline__ WsPtrs ws_ptrs(float* ws, const int* n_nodes_p, int E) {
    WsPtrs p;
    p.N    = *n_nodes_p;
    p.aggL = ws;
    p.aggR = ws + (size_t)p.N * 128;
    p.rd   = ws + (size_t)p.N * 256;
    p.ideg = (int*)(ws + (size_t)p.N * 257);
    p.ioff = p.ideg + p.N;
    p.icur = p.ioff + p.N + 1;
    p.elist = p.icur + p.N;
    p.epos  = p.elist + E;
    p.WgF = (ushort*)(((uintptr_t)(p.epos + E) + 15) & ~(uintptr_t)15);
    p.W1F = p.WgF + 32768;
    p.gwb = (float*)(p.W1F + 32768);
    p.nstL = p.gwb + 384;
    p.nstR = p.nstL + 2 * p.N;
    return p;
}

// ---------------- zero agg + deg ----------------
__global__ void init_kernel(float* __restrict__ ws, const int* __restrict__ n_nodes_p, int E) {
    WsPtrs p = ws_ptrs(ws, n_nodes_p, E);
    const long long stride = (long long)gridDim.x * blockDim.x;
    const long long tid = (long long)blockIdx.x * blockDim.x + threadIdx.x;
    const long long nf = (long long)p.N * 256;
    for (long long i = tid; i < nf; i += stride) ws[i] = 0.0f;
    for (long long i = tid; i < p.N; i += stride) p.ideg[i] = 0;
}

// ---------------- histogram of dst ----------------
__global__ void hist_kernel(const int* __restrict__ dst, float* __restrict__ ws,
                            const int* __restrict__ n_nodes_p, int E) {
    WsPtrs p = ws_ptrs(ws, n_nodes_p, E);
    const int i = blockIdx.x * blockDim.x + threadIdx.x;
    if (i < E) atomicAdd(&p.ideg[dst[i]], 1);
}

// ---------------- exclusive scan (single block) + rd = 1/max(deg,1) ----------------
__global__ __launch_bounds__(256) void scan_kernel(float* __restrict__ ws,
                                                   const int* __restrict__ n_nodes_p, int E) {
    WsPtrs p = ws_ptrs(ws, n_nodes_p, E);
    __shared__ int wsum[4];
    __shared__ int carry_s;
    const int t = threadIdx.x;
    const int lane = t & 63, wid = t >> 6;
    if (t == 0) carry_s = 0;
    __syncthreads();
    for (int base = 0; base < p.N; base += 1024) {
        const int i0 = base + t * 4;
        const int v0 = (i0 + 0 < p.N) ? p.ideg[i0 + 0] : 0;
        const int v1 = (i0 + 1 < p.N) ? p.ideg[i0 + 1] : 0;
        const int v2 = (i0 + 2 < p.N) ? p.ideg[i0 + 2] : 0;
        const int v3 = (i0 + 3 < p.N) ? p.ideg[i0 + 3] : 0;
        const int s = v0 + v1 + v2 + v3;
        int sc = s;
        #pragma unroll
        for (int off = 1; off < 64; off <<= 1) {
            const int n = __shfl_up(sc, off);
            if (lane >= off) sc += n;
        }
        if (lane == 63) wsum[wid] = sc;
        __syncthreads();
        int woff = 0;
        #pragma unroll
        for (int w = 0; w < 4; ++w) if (w < wid) woff += wsum[w];
        const int carry = carry_s;
        __syncthreads();
        const int excl = carry + woff + (sc - s);
        if (i0 + 0 < p.N) { p.ioff[i0+0] = excl;          p.icur[i0+0] = excl;          p.rd[i0+0] = 1.0f / fmaxf((float)v0, 1.0f); }
        if (i0 + 1 < p.N) { p.ioff[i0+1] = excl+v0;       p.icur[i0+1] = excl+v0;       p.rd[i0+1] = 1.0f / fmaxf((float)v1, 1.0f); }
        if (i0 + 2 < p.N) { p.ioff[i0+2] = excl+v0+v1;    p.icur[i0+2] = excl+v0+v1;    p.rd[i0+2] = 1.0f / fmaxf((float)v2, 1.0f); }
        if (i0 + 3 < p.N) { p.ioff[i0+3] = excl+v0+v1+v2; p.icur[i0+3] = excl+v0+v1+v2; p.rd[i0+3] = 1.0f / fmaxf((float)v3, 1.0f); }
        if (t == 255) carry_s = carry + woff + sc;
        __syncthreads();
    }
    if (t == 0) p.ioff[p.N] = carry_s;
}

// ---------------- scatter edge ids into buckets + position map ----------------
__global__ void scatter_kernel(const int* __restrict__ dst, float* __restrict__ ws,
                               const int* __restrict__ n_nodes_p, int E) {
    WsPtrs p = ws_ptrs(ws, n_nodes_p, E);
    const int i = blockIdx.x * blockDim.x + threadIdx.x;
    if (i < E) {
        const int pos = atomicAdd(&p.icur[dst[i]], 1);
        p.elist[pos] = i;
        p.epos[i] = (pos & ~63) | gperm(pos & 63);
    }
}

// ---------------- build fragment-major bf16 B tables + split gW1 halves + bW1 ----------------
__global__ void prep_w_kernel(const float* __restrict__ Wl, const float* __restrict__ Wr,
                              const float* __restrict__ W1,
                              const float* __restrict__ ln2_g, const float* __restrict__ ln2_b,
                              const float* __restrict__ b1,
                              float* __restrict__ ws, const int* __restrict__ n_nodes_p, int E) {
    WsPtrs p = ws_ptrs(ws, n_nodes_p, E);
    const int i = blockIdx.x * blockDim.x + threadIdx.x;
    if (i < 32768) {
        const int i8 = i & 7, lane = (i >> 3) & 63, kf = (i >> 9) & 3, nblk = i >> 11;
        const int k = kf * 32 + (lane >> 4) * 8 + i8;
        const int n = nblk * 16 + (lane & 15);
        const float val = (n < 128) ? Wl[k * 128 + n] : Wr[k * 128 + (n - 128)];
        p.WgF[i] = f2bf(val);
    } else if (i < 65536) {
        const int j = i - 32768;
        const int i8 = j & 7, lane = (j >> 3) & 63, kf = (j >> 9) & 7, nblk = j >> 12;
        const int k = kf * 32 + (lane >> 4) * 8 + i8;
        const int n = nblk * 16 + (lane & 15);
        p.W1F[j] = f2bf(W1[k * 128 + n]);
    } else if (i < 65664) {
        const int j = i - 65536;   // 0..127
        float gsL = 0.f, gsR = 0.f, bs = 0.f;
        for (int k = 0; k < 128; ++k) {
            const float wt = W1[k * 128 + j];
            const float wb = W1[(k + 128) * 128 + j];
            gsL += ln2_g[k] * wt;
            gsR += ln2_g[k + 128] * wb;
            bs  += ln2_b[k] * wt + ln2_b[k + 128] * wb;
        }
        p.gwb[j]       = gsL;
        p.gwb[128 + j] = gsR;
        p.gwb[256 + j] = bs + b1[j];
    }
}

// ---------------- streaming LN(y) -> bf16, scatter-write to permuted-sorted order ----------------
__global__ __launch_bounds__(256) void ln_y_kernel(
    const float* __restrict__ y,
    const float* __restrict__ ln_g, const float* __restrict__ ln_b,
    float* __restrict__ ws, const int* __restrict__ n_nodes_p, int E,
    ushort* __restrict__ ynb)
{
    WsPtrs p = ws_ptrs(ws, n_nodes_p, E);
    const int t = threadIdx.x;
    const int e = blockIdx.x * 64 + (t >> 2);
    const int sub = t & 3;
    if (e >= E) return;

    const float* yr = y + (size_t)e * 128;
    float v[32];
    float s = 0.f, sq = 0.f;
    #pragma unroll
    for (int i = 0; i < 8; ++i) {
        const float4 q = *reinterpret_cast<const float4*>(yr + sub * 32 + i * 4);
        v[i*4+0] = q.x; v[i*4+1] = q.y; v[i*4+2] = q.z; v[i*4+3] = q.w;
        s  += q.x + q.y + q.z + q.w;
        sq += q.x*q.x + q.y*q.y + q.z*q.z + q.w*q.w;
    }
    s  += __shfl_xor(s, 1);  s  += __shfl_xor(s, 2);
    sq += __shfl_xor(sq, 1); sq += __shfl_xor(sq, 2);
    const float mu = s * (1.f / 128.f);
    const float rstd = rsqrtf(sq * (1.f / 128.f) - mu * mu + LN_EPS);

    ushort* dstrow = ynb + (size_t)p.epos[e] * 128 + sub * 32;
    #pragma unroll
    for (int i = 0; i < 4; ++i) {
        uint w32[4];
        #pragma unroll
        for (int h2 = 0; h2 < 4; ++h2) {
            const int c = sub * 32 + i * 8 + h2 * 2;
            const float x0 = (v[i*8 + h2*2 + 0] - mu) * rstd * ln_g[c + 0] + ln_b[c + 0];
            const float x1 = (v[i*8 + h2*2 + 1] - mu) * rstd * ln_g[c + 1] + ln_b[c + 1];
            w32[h2] = (uint)f2bf(x0) | ((uint)f2bf(x1) << 16);
        }
        *reinterpret_cast<uint4*>(dstrow + i * 8) = make_uint4(w32[0], w32[1], w32[2], w32[3]);
    }
}

// ---------------- gates: MFMA dual-gate GEMM + sigmoid + compressed scatter ----------------
__global__ __launch_bounds__(512) void gates_kernel(
    const float* __restrict__ y, const int* __restrict__ dst,
    const float* __restrict__ ln_g, const float* __restrict__ ln_b,
    const float* __restrict__ bl, const float* __restrict__ br,
    float* __restrict__ ws, const int* __restrict__ n_nodes_p, int E,
    const ushort* __restrict__ ynb)
{
    __shared__ ushort sA[128 * 128];   // 32 KB
    __shared__ int sNode[128];

    WsPtrs p = ws_ptrs(ws, n_nodes_p, E);
    char* sAb = reinterpret_cast<char*>(sA);
    const int t = threadIdx.x;
    const int bid = xcd_swz(blockIdx.x, gridDim.x);
    const int s0 = bid * 128;
    const int lane = t & 63;
    const int w8 = t >> 6;

    if (t < 128) {
        const int j = s0 + t;
        const int eid = (j < E) ? p.elist[j] : -1;
        sNode[t] = (eid >= 0) ? dst[eid] : -1;
    }

    if (ynb) {
        const char* ybase = (const char*)ynb + (size_t)s0 * 256;
        #pragma unroll
        for (int i = 0; i < 4; ++i) {
            const int chunk = w8 + i * 8;
            const int L = chunk * 1024 + lane * 16;
            const int b = L ^ (((L >> 8) & 7) << 4);
            gload_lds16(ybase + b, sAb + chunk * 1024);
        }
    } else {
        const int r = t >> 2, sub = t & 3;
        const int je = s0 + gperm(r);
        const int eid = (je < E) ? p.elist[je] : 0;
        const float* yr = y + (size_t)eid * 128;
        float v[32];
        float s = 0.f, sq = 0.f;
        #pragma unroll
        for (int i = 0; i < 8; ++i) {
            const float4 q = *reinterpret_cast<const float4*>(yr + sub * 32 + i * 4);
            v[i*4+0] = q.x; v[i*4+1] = q.y; v[i*4+2] = q.z; v[i*4+3] = q.w;
            s  += q.x + q.y + q.z + q.w;
            sq += q.x*q.x + q.y*q.y + q.z*q.z + q.w*q.w;
        }
        s  += __shfl_xor(s, 1);  s  += __shfl_xor(s, 2);
        sq += __shfl_xor(sq, 1); sq += __shfl_xor(sq, 2);
        const float mu = s * (1.f / 128.f);
        const float rstd = rsqrtf(sq * (1.f / 128.f) - mu * mu + LN_EPS);
        #pragma unroll
        for (int i = 0; i < 4; ++i) {
            uint w32[4];
            #pragma unroll
            for (int h2 = 0; h2 < 4; ++h2) {
                const int c = sub * 32 + i * 8 + h2 * 2;
                const float x0 = (v[i*8 + h2*2 + 0] - mu) * rstd * ln_g[c + 0] + ln_b[c + 0];
                const float x1 = (v[i*8 + h2*2 + 1] - mu) * rstd * ln_g[c + 1] + ln_b[c + 1];
                w32[h2] = (uint)f2bf(x0) | ((uint)f2bf(x1) << 16);
            }
            int byte = r * 256 + sub * 64 + i * 16;
            byte ^= ((byte >> 8) & 7) << 4;
            *reinterpret_cast<uint4*>(sAb + byte) = make_uint4(w32[0], w32[1], w32[2], w32[3]);
        }
    }
    __syncthreads();

    const int rowh = w8 >> 2, colw = w8 & 3;
    const int lhi = lane >> 4, llo = lane & 15;

    f32x4 acc[4][4];
    #pragma unroll
    for (int m = 0; m < 4; ++m)
        #pragma unroll
        for (int n = 0; n < 4; ++n) acc[m][n] = (f32x4){0.f, 0.f, 0.f, 0.f};

    #pragma unroll
    for (int kf = 0; kf < 4; ++kf) {
        bf16x8 a[4], b[4];
        #pragma unroll
        for (int m = 0; m < 4; ++m) {
            const int row = rowh * 64 + m * 16 + llo;
            int byte = row * 256 + kf * 64 + lhi * 16;
            byte ^= ((byte >> 8) & 7) << 4;
            a[m] = *reinterpret_cast<const bf16x8*>(sAb + byte);
        }
        #pragma unroll
        for (int nf = 0; nf < 4; ++nf) {
            const int nblk = colw * 4 + nf;
            b[nf] = *reinterpret_cast<const bf16x8*>(p.WgF + ((size_t)(nblk * 4 + kf) * 64 + lane) * 8);
        }
        #pragma unroll
        for (int m = 0; m < 4; ++m)
            #pragma unroll
            for (int nf = 0; nf < 4; ++nf)
                acc[m][nf] = __builtin_amdgcn_mfma_f32_16x16x32_bf16(a[m], b[nf], acc[m][nf], 0, 0, 0);
    }

    // epilogue: shared run detection across the 4 nf columns; fast-rcp sigmoid.
    // This thread owns 16 CONSECUTIVE sorted edges: el = rowh*64 + lhi*16 + m*4 + j.
    const int g = colw >> 1;
    float* ag = g ? p.aggR : p.aggL;
    const float* bp = g ? br : bl;
    const int lcol0 = (colw & 1) * 64 + llo;   // col for nf=0 (mod 128)
    float bias[4];
    #pragma unroll
    for (int nf = 0; nf < 4; ++nf) bias[nf] = bp[lcol0 + nf * 16];

    float run0 = 0.f, run1 = 0.f, run2 = 0.f, run3 = 0.f;
    int rnode = -1;
    #pragma unroll
    for (int m = 0; m < 4; ++m) {
        #pragma unroll
        for (int j = 0; j < 4; ++j) {
            const int el = rowh * 64 + lhi * 16 + m * 4 + j;
            const int node = sNode[el];
            const float v0 = sigmoid_fast(acc[m][0][j] + bias[0]);
            const float v1 = sigmoid_fast(acc[m][1][j] + bias[1]);
            const float v2 = sigmoid_fast(acc[m][2][j] + bias[2]);
            const float v3 = sigmoid_fast(acc[m][3][j] + bias[3]);
            if (node != rnode) {
                if (rnode >= 0) {
                    float* dest = ag + (size_t)rnode * 128 + lcol0;
                    atomicAdd(dest +  0, run0);
                    atomicAdd(dest + 16, run1);
                    atomicAdd(dest + 32, run2);
                    atomicAdd(dest + 48, run3);
                }
                rnode = node;
                run0 = v0; run1 = v1; run2 = v2; run3 = v3;
            } else {
                run0 += v0; run1 += v1; run2 += v2; run3 += v3;
            }
        }
    }
    if (rnode >= 0) {
        float* dest = ag + (size_t)rnode * 128 + lcol0;
        atomicAdd(dest +  0, run0);
        atomicAdd(dest + 16, run1);
        atomicAdd(dest + 32, run2);
        atomicAdd(dest + 48, run3);
    }
}

// ---------------- node_mlp: u = ((z - mu_node) ⊙ g2) @ W1half -> bf16 IN PLACE; stats ----------------
__global__ __launch_bounds__(512) void node_mlp_kernel(
    const float* __restrict__ ln2_g,
    float* __restrict__ ws, const int* __restrict__ n_nodes_p, int E)
{
    __shared__ ushort sA[128 * 256];   // 64 KB

    WsPtrs p = ws_ptrs(ws, n_nodes_p, E);
    char* sAb = reinterpret_cast<char*>(sA);
    const int t = threadIdx.x;
    const int n0 = blockIdx.x * 128;

    {
        const int r = t >> 2, sub = t & 3;
        const int n = n0 + r;
        const bool vld = n < p.N;
        const int nn = vld ? n : (p.N - 1);
        const float* base = ((sub < 2) ? p.aggL : p.aggR) + (size_t)nn * 128 + (sub & 1) * 64;
        const float scale = vld ? p.rd[nn] : 0.f;
        const int cb = ((sub >> 1) << 7) + ((sub & 1) << 6);   // concat col base

        float s = 0.f, sq = 0.f;
        #pragma unroll
        for (int ii = 0; ii < 8; ++ii) {
            const float4 qa = *reinterpret_cast<const float4*>(base + ii * 8);
            const float4 qb = *reinterpret_cast<const float4*>(base + ii * 8 + 4);
            s  += qa.x + qa.y + qa.z + qa.w + qb.x + qb.y + qb.z + qb.w;
            sq += qa.x*qa.x + qa.y*qa.y + qa.z*qa.z + qa.w*qa.w
                + qb.x*qb.x + qb.y*qb.y + qb.z*qb.z + qb.w*qb.w;
        }
        s *= scale; sq *= scale * scale;
        s  += __shfl_xor(s, 1);
        sq += __shfl_xor(sq, 1);
        if (vld && sub == 0) { p.nstL[2*n] = s; p.nstL[2*n+1] = sq; }
        if (vld && sub == 2) { p.nstR[2*n] = s; p.nstR[2*n+1] = sq; }
        const float mu_n = s * (1.f / 128.f);

        #pragma unroll
        for (int ii = 0; ii < 8; ++ii) {
            const float4 qa = *reinterpret_cast<const float4*>(base + ii * 8);
            const float4 qb = *reinterpret_cast<const float4*>(base + ii * 8 + 4);
            const float xs[8] = { qa.x*scale - mu_n, qa.y*scale - mu_n, qa.z*scale - mu_n, qa.w*scale - mu_n,
                                  qb.x*scale - mu_n, qb.y*scale - mu_n, qb.z*scale - mu_n, qb.w*scale - mu_n };
            uint w32[4];
            #pragma unroll
            for (int h2 = 0; h2 < 4; ++h2) {
                const int c = cb + ii * 8 + h2 * 2;
                w32[h2] = (uint)f2bf(xs[h2*2+0] * ln2_g[c+0]) |
                          ((uint)f2bf(xs[h2*2+1] * ln2_g[c+1]) << 16);
            }
            int byte = r * 512 + cb * 2 + ii * 16;
            byte ^= ((byte >> 9) & 7) << 4;
            *reinterpret_cast<uint4*>(sAb + byte) = make_uint4(w32[0], w32[1], w32[2], w32[3]);
        }
    }
    __syncthreads();

    const int lane = t & 63;
    const int w8 = t >> 6;
    const int rowh = w8 >> 2, colw = w8 & 3;
    const int half = colw >> 1;                  // 0 -> uL, 1 -> uR
    const int lhi = lane >> 4, llo = lane & 15;

    f32x4 acc[4][4];
    #pragma unroll
    for (int m = 0; m < 4; ++m)
        #pragma unroll
        for (int n = 0; n < 4; ++n) acc[m][n] = (f32x4){0.f, 0.f, 0.f, 0.f};

    #pragma unroll
    for (int kfl = 0; kfl < 4; ++kfl) {
        bf16x8 a[4], b[4];
        #pragma unroll
        for (int m = 0; m < 4; ++m) {
            const int row = rowh * 64 + m * 16 + llo;
            int byte = row * 512 + half * 256 + kfl * 64 + lhi * 16;
            byte ^= ((byte >> 9) & 7) << 4;
            a[m] = *reinterpret_cast<const bf16x8*>(sAb + byte);
        }
        #pragma unroll
        for (int nf = 0; nf < 4; ++nf) {
            const int nblk = (colw & 1) * 4 + nf;
            const int kf = half * 4 + kfl;
            b[nf] = *reinterpret_cast<const bf16x8*>(p.W1F + ((size_t)(nblk * 8 + kf) * 64 + lane) * 8);
        }
        #pragma unroll
        for (int m = 0; m < 4; ++m)
            #pragma unroll
            for (int nf = 0; nf < 4; ++nf)
                acc[m][nf] = __builtin_amdgcn_mfma_f32_16x16x32_bf16(a[m], b[nf], acc[m][nf], 0, 0, 0);
    }

    // write u as bf16 into first half of each node's 512B row (row stride = 256 ushorts)
    ushort* u16 = (ushort*)(half ? p.aggR : p.aggL);
    #pragma unroll
    for (int m = 0; m < 4; ++m) {
        #pragma unroll
        for (int j = 0; j < 4; ++j) {
            const int n = n0 + rowh * 64 + m * 16 + lhi * 4 + j;
            if (n < p.N) {
                const int col = (colw & 1) * 64 + llo;
                #pragma unroll
                for (int nf = 0; nf < 4; ++nf)
                    u16[(size_t)n * 256 + col + nf * 16] = f2bf(acc[m][nf][j]);
            }
        }
    }
}

// ---------------- edge_out: h1 = rstd*(uL[s]+uR[d] + dL*gwL + dR*gwR) + bW1; ELU; dot W2 ----------------
// 2-way unrolled: two independent gather+reduce chains in flight per wave.
__global__ __launch_bounds__(256) void edge_out_kernel(
    const int* __restrict__ src, const int* __restrict__ dst,
    const float* __restrict__ W2, const float* __restrict__ b2,
    float* __restrict__ ws, const int* __restrict__ n_nodes_p,
    float* __restrict__ out, int E)
{
    WsPtrs p = ws_ptrs(ws, n_nodes_p, E);
    const ushort* uLb = (const ushort*)p.aggL;   // bf16 rows, stride 256 ushorts
    const ushort* uRb = (const ushort*)p.aggR;
    const int t = threadIdx.x;
    const int lane = t & 63;
    const int wv = blockIdx.x * 4 + (t >> 6);
    const int nw = gridDim.x * 4;
    const int span = (E + nw - 1) / nw;
    const int j0 = wv * span;
    const int j1 = min(E, j0 + span);

    const float2 gwl = *reinterpret_cast<const float2*>(p.gwb + lane * 2);
    const float2 gwr = *reinterpret_cast<const float2*>(p.gwb + 128 + lane * 2);
    const float2 bw  = *reinterpret_cast<const float2*>(p.gwb + 256 + lane * 2);
    const float2 w2  = *reinterpret_cast<const float2*>(W2 + lane * 2);
    const float b2v = b2[0];

    auto body = [&](int j, float& accv, int& eidv) {
        const int eid = p.elist[j];
        const int s = src[eid], d = dst[eid];
        const uint ulp = *reinterpret_cast<const uint*>(uLb + (size_t)s * 256 + lane * 2);
        const uint urp = *reinterpret_cast<const uint*>(uRb + (size_t)d * 256 + lane * 2);
        const float ulx = __builtin_bit_cast(float, ulp << 16);
        const float uly = __builtin_bit_cast(float, ulp & 0xffff0000u);
        const float urx = __builtin_bit_cast(float, urp << 16);
        const float ury = __builtin_bit_cast(float, urp & 0xffff0000u);
        const float2 nsl = *reinterpret_cast<const float2*>(p.nstL + 2 * s);
        const float2 nsr = *reinterpret_cast<const float2*>(p.nstR + 2 * d);
        const float mu = (nsl.x + nsr.x) * (1.f / 256.f);
        const float var = (nsl.y + nsr.y) * (1.f / 256.f) - mu * mu;
        const float rstd = rsqrtf(var + LN_EPS);
        const float dL = nsl.x * (1.f / 128.f) - mu;
        const float dR = nsr.x * (1.f / 128.f) - mu;
        float x0 = rstd * (ulx + urx + dL * gwl.x + dR * gwr.x) + bw.x;
        float x1 = rstd * (uly + ury + dL * gwl.y + dR * gwr.y) + bw.y;
        x0 = x0 > 0.f ? x0 : __expf(x0) - 1.f;
        x1 = x1 > 0.f ? x1 : __expf(x1) - 1.f;
        accv = x0 * w2.x + x1 * w2.y;
        eidv = eid;
    };

    int j = j0;
    for (; j + 1 < j1; j += 2) {
        float a0, a1; int e0, e1;
        body(j, a0, e0);
        body(j + 1, a1, e1);
        #pragma unroll
        for (int m = 32; m >= 1; m >>= 1) {
            a0 += __shfl_xor(a0, m);
            a1 += __shfl_xor(a1, m);
        }
        if (lane == 0) { out[e0] = a0 + b2v; out[e1] = a1 + b2v; }
    }
    if (j < j1) {
        float a0; int e0;
        body(j, a0, e0);
        #pragma unroll
        for (int m = 32; m >= 1; m >>= 1) a0 += __shfl_xor(a0, m);
        if (lane == 0) out[e0] = a0 + b2v;
    }
}

extern "C" void kernel_launch(void* const* d_in, const int* in_sizes, int n_in,
                              void* d_out, int out_size, void* d_ws, size_t ws_size,
                              hipStream_t stream) {
    const float* y       = (const float*)d_in[0];
    const int*   src     = (const int*)d_in[1];
    const int*   dst     = (const int*)d_in[2];
    const int*   n_nodes = (const int*)d_in[3];
    const float* ln_g    = (const float*)d_in[4];
    const float* ln_b    = (const float*)d_in[5];
    const float* Wl      = (const float*)d_in[6];
    const float* bl      = (const float*)d_in[7];
    const float* Wr      = (const float*)d_in[8];
    const float* br      = (const float*)d_in[9];
    const float* ln2_g   = (const float*)d_in[10];
    const float* ln2_b   = (const float*)d_in[11];
    const float* W1      = (const float*)d_in[12];
    const float* b1      = (const float*)d_in[13];
    const float* W2      = (const float*)d_in[14];
    const float* b2      = (const float*)d_in[15];
    float* out = (float*)d_out;
    float* ws  = (float*)d_ws;

    const int E = in_sizes[0] / 128;
    const int eb = (E + 127) / 128;
    const int N_MAX = 40000;   // grid sizing only; device code reads *n_nodes

    const size_t need = (size_t)(E + 128) * 256;
    const bool use_pre = ws_size >= need + (96ull << 20);
    ushort* ynb = use_pre
        ? (ushort*)(((uintptr_t)ws + ws_size - need) & ~(uintptr_t)255)
        : nullptr;

    init_kernel<<<2048, 256, 0, stream>>>(ws, n_nodes, E);
    hist_kernel<<<(E + 255) / 256, 256, 0, stream>>>(dst, ws, n_nodes, E);
    scan_kernel<<<1, 256, 0, stream>>>(ws, n_nodes, E);
    scatter_kernel<<<(E + 255) / 256, 256, 0, stream>>>(dst, ws, n_nodes, E);
    prep_w_kernel<<<257, 256, 0, stream>>>(Wl, Wr, W1, ln2_g, ln2_b, b1, ws, n_nodes, E);
    if (use_pre)
        ln_y_kernel<<<(E + 63) / 64, 256, 0, stream>>>(y, ln_g, ln_b, ws, n_nodes, E, ynb);
    gates_kernel<<<eb, 512, 0, stream>>>(y, dst, ln_g, ln_b, bl, br, ws, n_nodes, E, ynb);
    node_mlp_kernel<<<(N_MAX + 127) / 128, 512, 0, stream>>>(ln2_g, ws, n_nodes, E);
    edge_out_kernel<<<2048, 256, 0, stream>>>(src, dst, W2, b2, ws, n_nodes, out, E);
}

// Round 11
// 539.347 us; speedup vs baseline: 1.5452x; 1.0383x over previous
//
#include <hip/hip_runtime.h>
#include <hip/hip_bf16.h>

#define LN_EPS 1e-5f

typedef __attribute__((ext_vector_type(8))) short bf16x8;
typedef __attribute__((ext_vector_type(4))) float f32x4;

__device__ __forceinline__ float sigmoid_fast(float x) {
    return __builtin_amdgcn_rcpf(1.0f + __expf(-x));
}
__device__ __forceinline__ ushort f2bf(float x) {
    __hip_bfloat16 h = __float2bfloat16(x);   // RNE
    return __builtin_bit_cast(ushort, h);
}
// m204 bijective XCD-chunked swizzle (8 XCDs)
__device__ __forceinline__ int xcd_swz(int bid, int nwg) {
    const int q = nwg >> 3, r = nwg & 7;
    const int xcd = bid & 7, idx = bid >> 3;
    return (xcd < r ? xcd * (q + 1) : r * (q + 1) + (xcd - r) * q) + idx;
}
// block-local edge permutation: swap bits[3:2] <-> bits[5:4] (involution).
__device__ __forceinline__ int gperm(int l) {
    return (l & ~63) | (((l >> 2) & 3) << 4) | (((l >> 4) & 3) << 2) | (l & 3);
}
__device__ __forceinline__ void gload_lds16(const void* g, void* l) {
    __builtin_amdgcn_global_load_lds((const __attribute__((address_space(1))) void*)g,
                                     (__attribute__((address_space(3))) void*)l, 16, 0, 0);
}

// ws layout (N read on device):
//   float aggL[N*128]; float aggR[N*128]; float rd[N];
//   int ideg[N]; int ioff[N+1]; int icur[N]; int elist[E]; int epos[E];
//   ushort WgF[16*4*64*8]; ushort W1F[8*8*64*8];
//   float gwb[384]; float nstL[2N]; float nstR[2N]
//   ... tail of ws: ushort ynb[(E+128)*128]
struct WsPtrs {
    float *aggL, *aggR, *rd;
    int *ideg, *ioff, *icur, *elist, *epos;
    ushort *WgF, *W1F;
    float *gwb, *nstL, *nstR;
    int N;
};
__device__ __forceinline__ WsPtrs ws_ptrs(float* ws, const int* n_nodes_p, int E) {
    WsPtrs p;
    p.N    = *n_nodes_p;
    p.aggL = ws;
    p.aggR = ws + (size_t)p.N * 128;
    p.rd   = ws + (size_t)p.N * 256;
    p.ideg = (int*)(ws + (size_t)p.N * 257);
    p.ioff = p.ideg + p.N;
    p.icur = p.ioff + p.N + 1;
    p.elist = p.icur + p.N;
    p.epos  = p.elist + E;
    p.WgF = (ushort*)(((uintptr_t)(p.epos + E) + 15) & ~(uintptr_t)15);
    p.W1F = p.WgF + 32768;
    p.gwb = (float*)(p.W1F + 32768);
    p.nstL = p.gwb + 384;
    p.nstR = p.nstL + 2 * p.N;
    return p;
}

// ---------------- zero agg + deg ----------------
__global__ void init_kernel(float* __restrict__ ws, const int* __restrict__ n_nodes_p, int E) {
    WsPtrs p = ws_ptrs(ws, n_nodes_p, E);
    const long long stride = (long long)gridDim.x * blockDim.x;
    const long long tid = (long long)blockIdx.x * blockDim.x + threadIdx.x;
    const long long nf = (long long)p.N * 256;
    for (long long i = tid; i < nf; i += stride) ws[i] = 0.0f;
    for (long long i = tid; i < p.N; i += stride) p.ideg[i] = 0;
}

// ---------------- histogram of dst ----------------
__global__ void hist_kernel(const int* __restrict__ dst, float* __restrict__ ws,
                            const int* __restrict__ n_nodes_p, int E) {
    WsPtrs p = ws_ptrs(ws, n_nodes_p, E);
    const int i = blockIdx.x * blockDim.x + threadIdx.x;
    if (i < E) atomicAdd(&p.ideg[dst[i]], 1);
}

// ---------------- exclusive scan (single block) + rd = 1/max(deg,1) ----------------
__global__ __launch_bounds__(256) void scan_kernel(float* __restrict__ ws,
                                                   const int* __restrict__ n_nodes_p, int E) {
    WsPtrs p = ws_ptrs(ws, n_nodes_p, E);
    __shared__ int wsum[4];
    __shared__ int carry_s;
    const int t = threadIdx.x;
    const int lane = t & 63, wid = t >> 6;
    if (t == 0) carry_s = 0;
    __syncthreads();
    for (int base = 0; base < p.N; base += 1024) {
        const int i0 = base + t * 4;
        const int v0 = (i0 + 0 < p.N) ? p.ideg[i0 + 0] : 0;
        const int v1 = (i0 + 1 < p.N) ? p.ideg[i0 + 1] : 0;
        const int v2 = (i0 + 2 < p.N) ? p.ideg[i0 + 2] : 0;
        const int v3 = (i0 + 3 < p.N) ? p.ideg[i0 + 3] : 0;
        const int s = v0 + v1 + v2 + v3;
        int sc = s;
        #pragma unroll
        for (int off = 1; off < 64; off <<= 1) {
            const int n = __shfl_up(sc, off);
            if (lane >= off) sc += n;
        }
        if (lane == 63) wsum[wid] = sc;
        __syncthreads();
        int woff = 0;
        #pragma unroll
        for (int w = 0; w < 4; ++w) if (w < wid) woff += wsum[w];
        const int carry = carry_s;
        __syncthreads();
        const int excl = carry + woff + (sc - s);
        if (i0 + 0 < p.N) { p.ioff[i0+0] = excl;          p.icur[i0+0] = excl;          p.rd[i0+0] = 1.0f / fmaxf((float)v0, 1.0f); }
        if (i0 + 1 < p.N) { p.ioff[i0+1] = excl+v0;       p.icur[i0+1] = excl+v0;       p.rd[i0+1] = 1.0f / fmaxf((float)v1, 1.0f); }
        if (i0 + 2 < p.N) { p.ioff[i0+2] = excl+v0+v1;    p.icur[i0+2] = excl+v0+v1;    p.rd[i0+2] = 1.0f / fmaxf((float)v2, 1.0f); }
        if (i0 + 3 < p.N) { p.ioff[i0+3] = excl+v0+v1+v2; p.icur[i0+3] = excl+v0+v1+v2; p.rd[i0+3] = 1.0f / fmaxf((float)v3, 1.0f); }
        if (t == 255) carry_s = carry + woff + sc;
        __syncthreads();
    }
    if (t == 0) p.ioff[p.N] = carry_s;
}

// ---------------- scatter edge ids into buckets + position map ----------------
__global__ void scatter_kernel(const int* __restrict__ dst, float* __restrict__ ws,
                               const int* __restrict__ n_nodes_p, int E) {
    WsPtrs p = ws_ptrs(ws, n_nodes_p, E);
    const int i = blockIdx.x * blockDim.x + threadIdx.x;
    if (i < E) {
        const int pos = atomicAdd(&p.icur[dst[i]], 1);
        p.elist[pos] = i;
        p.epos[i] = (pos & ~63) | gperm(pos & 63);
    }
}

// ---------------- build fragment-major bf16 B tables + split gW1 halves + bW1 ----------------
__global__ void prep_w_kernel(const float* __restrict__ Wl, const float* __restrict__ Wr,
                              const float* __restrict__ W1,
                              const float* __restrict__ ln2_g, const float* __restrict__ ln2_b,
                              const float* __restrict__ b1,
                              float* __restrict__ ws, const int* __restrict__ n_nodes_p, int E) {
    WsPtrs p = ws_ptrs(ws, n_nodes_p, E);
    const int i = blockIdx.x * blockDim.x + threadIdx.x;
    if (i < 32768) {
        const int i8 = i & 7, lane = (i >> 3) & 63, kf = (i >> 9) & 3, nblk = i >> 11;
        const int k = kf * 32 + (lane >> 4) * 8 + i8;
        const int n = nblk * 16 + (lane & 15);
        const float val = (n < 128) ? Wl[k * 128 + n] : Wr[k * 128 + (n - 128)];
        p.WgF[i] = f2bf(val);
    } else if (i < 65536) {
        const int j = i - 32768;
        const int i8 = j & 7, lane = (j >> 3) & 63, kf = (j >> 9) & 7, nblk = j >> 12;
        const int k = kf * 32 + (lane >> 4) * 8 + i8;
        const int n = nblk * 16 + (lane & 15);
        p.W1F[j] = f2bf(W1[k * 128 + n]);
    } else if (i < 65664) {
        const int j = i - 65536;   // 0..127
        float gsL = 0.f, gsR = 0.f, bs = 0.f;
        for (int k = 0; k < 128; ++k) {
            const float wt = W1[k * 128 + j];
            const float wb = W1[(k + 128) * 128 + j];
            gsL += ln2_g[k] * wt;
            gsR += ln2_g[k + 128] * wb;
            bs  += ln2_b[k] * wt + ln2_b[k + 128] * wb;
        }
        p.gwb[j]       = gsL;
        p.gwb[128 + j] = gsR;
        p.gwb[256 + j] = bs + b1[j];
    }
}

// ---------------- streaming LN(y) -> bf16, scatter-write to permuted-sorted order ----------------
__global__ __launch_bounds__(256) void ln_y_kernel(
    const float* __restrict__ y,
    const float* __restrict__ ln_g, const float* __restrict__ ln_b,
    float* __restrict__ ws, const int* __restrict__ n_nodes_p, int E,
    ushort* __restrict__ ynb)
{
    WsPtrs p = ws_ptrs(ws, n_nodes_p, E);
    const int t = threadIdx.x;
    const int e = blockIdx.x * 64 + (t >> 2);
    const int sub = t & 3;
    if (e >= E) return;

    const float* yr = y + (size_t)e * 128;
    float v[32];
    float s = 0.f, sq = 0.f;
    #pragma unroll
    for (int i = 0; i < 8; ++i) {
        const float4 q = *reinterpret_cast<const float4*>(yr + sub * 32 + i * 4);
        v[i*4+0] = q.x; v[i*4+1] = q.y; v[i*4+2] = q.z; v[i*4+3] = q.w;
        s  += q.x + q.y + q.z + q.w;
        sq += q.x*q.x + q.y*q.y + q.z*q.z + q.w*q.w;
    }
    s  += __shfl_xor(s, 1);  s  += __shfl_xor(s, 2);
    sq += __shfl_xor(sq, 1); sq += __shfl_xor(sq, 2);
    const float mu = s * (1.f / 128.f);
    const float rstd = rsqrtf(sq * (1.f / 128.f) - mu * mu + LN_EPS);

    ushort* dstrow = ynb + (size_t)p.epos[e] * 128 + sub * 32;
    #pragma unroll
    for (int i = 0; i < 4; ++i) {
        uint w32[4];
        #pragma unroll
        for (int h2 = 0; h2 < 4; ++h2) {
            const int c = sub * 32 + i * 8 + h2 * 2;
            const float x0 = (v[i*8 + h2*2 + 0] - mu) * rstd * ln_g[c + 0] + ln_b[c + 0];
            const float x1 = (v[i*8 + h2*2 + 1] - mu) * rstd * ln_g[c + 1] + ln_b[c + 1];
            w32[h2] = (uint)f2bf(x0) | ((uint)f2bf(x1) << 16);
        }
        *reinterpret_cast<uint4*>(dstrow + i * 8) = make_uint4(w32[0], w32[1], w32[2], w32[3]);
    }
}

// ---------------- gates: 64-edge tile, 8 waves, acc[4][2] (<=64 VGPR target) ----------------
// Wave w8 owns output cols [w8*32, w8*32+32) of the 256-wide [Wl|Wr] output.
// sA: [64 rows][128 cols] bf16 (16 KB), byte = r*256 + col*2, XOR-swizzle ((byte>>8)&7)<<4.
// Thread owns 16 CONSECUTIVE sorted edges (gperm) x 2 cols -> run-compressed atomics.
__global__ __launch_bounds__(512, 8) void gates_kernel(
    const float* __restrict__ y, const int* __restrict__ dst,
    const float* __restrict__ ln_g, const float* __restrict__ ln_b,
    const float* __restrict__ bl, const float* __restrict__ br,
    float* __restrict__ ws, const int* __restrict__ n_nodes_p, int E,
    const ushort* __restrict__ ynb)
{
    __shared__ ushort sA[64 * 128];   // 16 KB
    __shared__ int sNode[64];

    WsPtrs p = ws_ptrs(ws, n_nodes_p, E);
    char* sAb = reinterpret_cast<char*>(sA);
    const int t = threadIdx.x;
    const int bid = xcd_swz(blockIdx.x, gridDim.x);
    const int s0 = bid * 64;
    const int lane = t & 63;
    const int w8 = t >> 6;

    if (t < 64) {
        const int j = s0 + t;
        const int eid = (j < E) ? p.elist[j] : -1;
        sNode[t] = (eid >= 0) ? dst[eid] : -1;
    }

    if (ynb) {
        // 16 chunks of 1KB; each wave stages 2. Swizzle folded into source offset.
        const char* ybase = (const char*)ynb + (size_t)s0 * 256;
        #pragma unroll
        for (int i = 0; i < 2; ++i) {
            const int chunk = w8 * 2 + i;
            const int L = chunk * 1024 + lane * 16;
            const int b = L ^ (((L >> 8) & 7) << 4);
            gload_lds16(ybase + b, sAb + chunk * 1024);
        }
    } else {
        // fallback: in-kernel LN, 8 threads/row; row r holds edge elist[s0+gperm(r)]
        const int r = t >> 3, sub8 = t & 7;
        const int je = s0 + gperm(r);
        const int eid = (je < E) ? p.elist[je] : 0;
        const float* yr = y + (size_t)eid * 128;
        float v[16];
        float s = 0.f, sq = 0.f;
        #pragma unroll
        for (int i = 0; i < 4; ++i) {
            const float4 q = *reinterpret_cast<const float4*>(yr + sub8 * 16 + i * 4);
            v[i*4+0] = q.x; v[i*4+1] = q.y; v[i*4+2] = q.z; v[i*4+3] = q.w;
            s  += q.x + q.y + q.z + q.w;
            sq += q.x*q.x + q.y*q.y + q.z*q.z + q.w*q.w;
        }
        s  += __shfl_xor(s, 1);  s  += __shfl_xor(s, 2);  s  += __shfl_xor(s, 4);
        sq += __shfl_xor(sq, 1); sq += __shfl_xor(sq, 2); sq += __shfl_xor(sq, 4);
        const float mu = s * (1.f / 128.f);
        const float rstd = rsqrtf(sq * (1.f / 128.f) - mu * mu + LN_EPS);
        #pragma unroll
        for (int i = 0; i < 2; ++i) {
            uint w32[4];
            #pragma unroll
            for (int h2 = 0; h2 < 4; ++h2) {
                const int c = sub8 * 16 + i * 8 + h2 * 2;
                const float x0 = (v[i*8 + h2*2 + 0] - mu) * rstd * ln_g[c + 0] + ln_b[c + 0];
                const float x1 = (v[i*8 + h2*2 + 1] - mu) * rstd * ln_g[c + 1] + ln_b[c + 1];
                w32[h2] = (uint)f2bf(x0) | ((uint)f2bf(x1) << 16);
            }
            int byte = r * 256 + sub8 * 32 + i * 16;
            byte ^= ((byte >> 8) & 7) << 4;
            *reinterpret_cast<uint4*>(sAb + byte) = make_uint4(w32[0], w32[1], w32[2], w32[3]);
        }
    }
    __syncthreads();

    const int lhi = lane >> 4, llo = lane & 15;

    f32x4 acc[4][2];
    #pragma unroll
    for (int m = 0; m < 4; ++m)
        #pragma unroll
        for (int n = 0; n < 2; ++n) acc[m][n] = (f32x4){0.f, 0.f, 0.f, 0.f};

    #pragma unroll
    for (int kf = 0; kf < 4; ++kf) {
        bf16x8 b[2];
        #pragma unroll
        for (int nf = 0; nf < 2; ++nf) {
            const int nblk = w8 * 2 + nf;
            b[nf] = *reinterpret_cast<const bf16x8*>(p.WgF + ((size_t)(nblk * 4 + kf) * 64 + lane) * 8);
        }
        #pragma unroll
        for (int m = 0; m < 4; ++m) {
            const int row = m * 16 + llo;
            int byte = row * 256 + kf * 64 + lhi * 16;
            byte ^= ((byte >> 8) & 7) << 4;
            const bf16x8 a = *reinterpret_cast<const bf16x8*>(sAb + byte);
            acc[m][0] = __builtin_amdgcn_mfma_f32_16x16x32_bf16(a, b[0], acc[m][0], 0, 0, 0);
            acc[m][1] = __builtin_amdgcn_mfma_f32_16x16x32_bf16(a, b[1], acc[m][1], 0, 0, 0);
        }
    }

    // epilogue: thread owns 16 consecutive edges (el = lhi*16 + m*4 + j) x 2 cols.
    const int g = w8 >> 2;
    float* ag = g ? p.aggR : p.aggL;
    const float* bp = g ? br : bl;
    const int lcol0 = (w8 & 3) * 32 + llo;   // col within gate (mod 128)
    const float bias0 = bp[lcol0];
    const float bias1 = bp[lcol0 + 16];

    float run0 = 0.f, run1 = 0.f;
    int rnode = -1;
    #pragma unroll
    for (int m = 0; m < 4; ++m) {
        #pragma unroll
        for (int j = 0; j < 4; ++j) {
            const int el = lhi * 16 + m * 4 + j;
            const int node = sNode[el];
            const float v0 = sigmoid_fast(acc[m][0][j] + bias0);
            const float v1 = sigmoid_fast(acc[m][1][j] + bias1);
            if (node != rnode) {
                if (rnode >= 0) {
                    float* dest = ag + (size_t)rnode * 128 + lcol0;
                    atomicAdd(dest +  0, run0);
                    atomicAdd(dest + 16, run1);
                }
                rnode = node;
                run0 = v0; run1 = v1;
            } else {
                run0 += v0; run1 += v1;
            }
        }
    }
    if (rnode >= 0) {
        float* dest = ag + (size_t)rnode * 128 + lcol0;
        atomicAdd(dest +  0, run0);
        atomicAdd(dest + 16, run1);
    }
}

// ---------------- node_mlp: u = ((z - mu_node) ⊙ g2) @ W1half -> bf16 IN PLACE; stats ----------------
__global__ __launch_bounds__(512) void node_mlp_kernel(
    const float* __restrict__ ln2_g,
    float* __restrict__ ws, const int* __restrict__ n_nodes_p, int E)
{
    __shared__ ushort sA[128 * 256];   // 64 KB

    WsPtrs p = ws_ptrs(ws, n_nodes_p, E);
    char* sAb = reinterpret_cast<char*>(sA);
    const int t = threadIdx.x;
    const int n0 = blockIdx.x * 128;

    {
        const int r = t >> 2, sub = t & 3;
        const int n = n0 + r;
        const bool vld = n < p.N;
        const int nn = vld ? n : (p.N - 1);
        const float* base = ((sub < 2) ? p.aggL : p.aggR) + (size_t)nn * 128 + (sub & 1) * 64;
        const float scale = vld ? p.rd[nn] : 0.f;
        const int cb = ((sub >> 1) << 7) + ((sub & 1) << 6);   // concat col base

        float s = 0.f, sq = 0.f;
        #pragma unroll
        for (int ii = 0; ii < 8; ++ii) {
            const float4 qa = *reinterpret_cast<const float4*>(base + ii * 8);
            const float4 qb = *reinterpret_cast<const float4*>(base + ii * 8 + 4);
            s  += qa.x + qa.y + qa.z + qa.w + qb.x + qb.y + qb.z + qb.w;
            sq += qa.x*qa.x + qa.y*qa.y + qa.z*qa.z + qa.w*qa.w
                + qb.x*qb.x + qb.y*qb.y + qb.z*qb.z + qb.w*qb.w;
        }
        s *= scale; sq *= scale * scale;
        s  += __shfl_xor(s, 1);
        sq += __shfl_xor(sq, 1);
        if (vld && sub == 0) { p.nstL[2*n] = s; p.nstL[2*n+1] = sq; }
        if (vld && sub == 2) { p.nstR[2*n] = s; p.nstR[2*n+1] = sq; }
        const float mu_n = s * (1.f / 128.f);

        #pragma unroll
        for (int ii = 0; ii < 8; ++ii) {
            const float4 qa = *reinterpret_cast<const float4*>(base + ii * 8);
            const float4 qb = *reinterpret_cast<const float4*>(base + ii * 8 + 4);
            const float xs[8] = { qa.x*scale - mu_n, qa.y*scale - mu_n, qa.z*scale - mu_n, qa.w*scale - mu_n,
                                  qb.x*scale - mu_n, qb.y*scale - mu_n, qb.z*scale - mu_n, qb.w*scale - mu_n };
            uint w32[4];
            #pragma unroll
            for (int h2 = 0; h2 < 4; ++h2) {
                const int c = cb + ii * 8 + h2 * 2;
                w32[h2] = (uint)f2bf(xs[h2*2+0] * ln2_g[c+0]) |
                          ((uint)f2bf(xs[h2*2+1] * ln2_g[c+1]) << 16);
            }
            int byte = r * 512 + cb * 2 + ii * 16;
            byte ^= ((byte >> 9) & 7) << 4;
            *reinterpret_cast<uint4*>(sAb + byte) = make_uint4(w32[0], w32[1], w32[2], w32[3]);
        }
    }
    __syncthreads();

    const int lane = t & 63;
    const int w8 = t >> 6;
    const int rowh = w8 >> 2, colw = w8 & 3;
    const int half = colw >> 1;                  // 0 -> uL, 1 -> uR
    const int lhi = lane >> 4, llo = lane & 15;

    f32x4 acc[4][4];
    #pragma unroll
    for (int m = 0; m < 4; ++m)
        #pragma unroll
        for (int n = 0; n < 4; ++n) acc[m][n] = (f32x4){0.f, 0.f, 0.f, 0.f};

    #pragma unroll
    for (int kfl = 0; kfl < 4; ++kfl) {
        bf16x8 a[4], b[4];
        #pragma unroll
        for (int m = 0; m < 4; ++m) {
            const int row = rowh * 64 + m * 16 + llo;
            int byte = row * 512 + half * 256 + kfl * 64 + lhi * 16;
            byte ^= ((byte >> 9) & 7) << 4;
            a[m] = *reinterpret_cast<const bf16x8*>(sAb + byte);
        }
        #pragma unroll
        for (int nf = 0; nf < 4; ++nf) {
            const int nblk = (colw & 1) * 4 + nf;
            const int kf = half * 4 + kfl;
            b[nf] = *reinterpret_cast<const bf16x8*>(p.W1F + ((size_t)(nblk * 8 + kf) * 64 + lane) * 8);
        }
        #pragma unroll
        for (int m = 0; m < 4; ++m)
            #pragma unroll
            for (int nf = 0; nf < 4; ++nf)
                acc[m][nf] = __builtin_amdgcn_mfma_f32_16x16x32_bf16(a[m], b[nf], acc[m][nf], 0, 0, 0);
    }

    ushort* u16 = (ushort*)(half ? p.aggR : p.aggL);
    #pragma unroll
    for (int m = 0; m < 4; ++m) {
        #pragma unroll
        for (int j = 0; j < 4; ++j) {
            const int n = n0 + rowh * 64 + m * 16 + lhi * 4 + j;
            if (n < p.N) {
                const int col = (colw & 1) * 64 + llo;
                #pragma unroll
                for (int nf = 0; nf < 4; ++nf)
                    u16[(size_t)n * 256 + col + nf * 16] = f2bf(acc[m][nf][j]);
            }
        }
    }
}

// ---------------- edge_out: dst-run cached; 2-way unrolled uL gathers ----------------
__global__ __launch_bounds__(256) void edge_out_kernel(
    const int* __restrict__ src, const int* __restrict__ dst,
    const float* __restrict__ W2, const float* __restrict__ b2,
    float* __restrict__ ws, const int* __restrict__ n_nodes_p,
    float* __restrict__ out, int E)
{
    WsPtrs p = ws_ptrs(ws, n_nodes_p, E);
    const ushort* uLb = (const ushort*)p.aggL;   // bf16 rows, stride 256 ushorts
    const ushort* uRb = (const ushort*)p.aggR;
    const int t = threadIdx.x;
    const int lane = t & 63;
    const int wv = blockIdx.x * 4 + (t >> 6);
    const int nw = gridDim.x * 4;
    const int span = (E + nw - 1) / nw;
    const int j0 = wv * span;
    const int j1 = min(E, j0 + span);

    const float2 gwl = *reinterpret_cast<const float2*>(p.gwb + lane * 2);
    const float2 gwr = *reinterpret_cast<const float2*>(p.gwb + 128 + lane * 2);
    const float2 bw  = *reinterpret_cast<const float2*>(p.gwb + 256 + lane * 2);
    const float2 w2  = *reinterpret_cast<const float2*>(W2 + lane * 2);
    const float b2v = b2[0];

    // dst-run cache (elist is dst-bucketed: d repeats ~deg times)
    int dc = -1;
    float urx = 0.f, ury = 0.f;
    float2 nsr = make_float2(0.f, 0.f);

    auto load_d = [&](int d) {
        if (d != dc) {
            const uint urp = *reinterpret_cast<const uint*>(uRb + (size_t)d * 256 + lane * 2);
            urx = __builtin_bit_cast(float, urp << 16);
            ury = __builtin_bit_cast(float, urp & 0xffff0000u);
            nsr = *reinterpret_cast<const float2*>(p.nstR + 2 * d);
            dc = d;
        }
    };
    auto finish = [&](int s, float& accv) {
        const uint ulp = *reinterpret_cast<const uint*>(uLb + (size_t)s * 256 + lane * 2);
        const float ulx = __builtin_bit_cast(float, ulp << 16);
        const float uly = __builtin_bit_cast(float, ulp & 0xffff0000u);
        const float2 nsl = *reinterpret_cast<const float2*>(p.nstL + 2 * s);
        const float mu = (nsl.x + nsr.x) * (1.f / 256.f);
        const float var = (nsl.y + nsr.y) * (1.f / 256.f) - mu * mu;
        const float rstd = rsqrtf(var + LN_EPS);
        const float dL = nsl.x * (1.f / 128.f) - mu;
        const float dR = nsr.x * (1.f / 128.f) - mu;
        float x0 = rstd * (ulx + urx + dL * gwl.x + dR * gwr.x) + bw.x;
        float x1 = rstd * (uly + ury + dL * gwl.y + dR * gwr.y) + bw.y;
        x0 = x0 > 0.f ? x0 : __expf(x0) - 1.f;
        x1 = x1 > 0.f ? x1 : __expf(x1) - 1.f;
        accv = x0 * w2.x + x1 * w2.y;
    };

    int j = j0;
    for (; j + 1 < j1; j += 2) {
        const int e0 = p.elist[j], e1 = p.elist[j + 1];
        const int s0_ = src[e0], s1_ = src[e1];
        const int d0_ = dst[e0], d1_ = dst[e1];
        float a0, a1;
        load_d(d0_);
        finish(s0_, a0);
        load_d(d1_);
        finish(s1_, a1);
        #pragma unroll
        for (int m = 32; m >= 1; m >>= 1) {
            a0 += __shfl_xor(a0, m);
            a1 += __shfl_xor(a1, m);
        }
        if (lane == 0) { out[e0] = a0 + b2v; out[e1] = a1 + b2v; }
    }
    if (j < j1) {
        const int e0 = p.elist[j];
        float a0;
        load_d(dst[e0]);
        finish(src[e0], a0);
        #pragma unroll
        for (int m = 32; m >= 1; m >>= 1) a0 += __shfl_xor(a0, m);
        if (lane == 0) out[e0] = a0 + b2v;
    }
}

extern "C" void kernel_launch(void* const* d_in, const int* in_sizes, int n_in,
                              void* d_out, int out_size, void* d_ws, size_t ws_size,
                              hipStream_t stream) {
    const float* y       = (const float*)d_in[0];
    const int*   src     = (const int*)d_in[1];
    const int*   dst     = (const int*)d_in[2];
    const int*   n_nodes = (const int*)d_in[3];
    const float* ln_g    = (const float*)d_in[4];
    const float* ln_b    = (const float*)d_in[5];
    const float* Wl      = (const float*)d_in[6];
    const float* bl      = (const float*)d_in[7];
    const float* Wr      = (const float*)d_in[8];
    const float* br      = (const float*)d_in[9];
    const float* ln2_g   = (const float*)d_in[10];
    const float* ln2_b   = (const float*)d_in[11];
    const float* W1      = (const float*)d_in[12];
    const float* b1      = (const float*)d_in[13];
    const float* W2      = (const float*)d_in[14];
    const float* b2      = (const float*)d_in[15];
    float* out = (float*)d_out;
    float* ws  = (float*)d_ws;

    const int E = in_sizes[0] / 128;
    const int eb64 = (E + 63) / 64;
    const int N_MAX = 40000;   // grid sizing only; device code reads *n_nodes

    const size_t need = (size_t)(E + 128) * 256;
    const bool use_pre = ws_size >= need + (96ull << 20);
    ushort* ynb = use_pre
        ? (ushort*)(((uintptr_t)ws + ws_size - need) & ~(uintptr_t)255)
        : nullptr;

    init_kernel<<<2048, 256, 0, stream>>>(ws, n_nodes, E);
    hist_kernel<<<(E + 255) / 256, 256, 0, stream>>>(dst, ws, n_nodes, E);
    scan_kernel<<<1, 256, 0, stream>>>(ws, n_nodes, E);
    scatter_kernel<<<(E + 255) / 256, 256, 0, stream>>>(dst, ws, n_nodes, E);
    prep_w_kernel<<<257, 256, 0, stream>>>(Wl, Wr, W1, ln2_g, ln2_b, b1, ws, n_nodes, E);
    if (use_pre)
        ln_y_kernel<<<(E + 63) / 64, 256, 0, stream>>>(y, ln_g, ln_b, ws, n_nodes, E, ynb);
    gates_kernel<<<eb64, 512, 0, stream>>>(y, dst, ln_g, ln_b, bl, br, ws, n_nodes, E, ynb);
    node_mlp_kernel<<<(N_MAX + 127) / 128, 512, 0, stream>>>(ln2_g, ws, n_nodes, E);
    edge_out_kernel<<<2048, 256, 0, stream>>>(src, dst, W2, b2, ws, n_nodes, out, E);
}

// Round 12
// 504.421 us; speedup vs baseline: 1.6522x; 1.0692x over previous
//
#include <hip/hip_runtime.h>
#include <hip/hip_bf16.h>

#define LN_EPS 1e-5f

typedef __attribute__((ext_vector_type(8))) short bf16x8;
typedef __attribute__((ext_vector_type(4))) float f32x4;

__device__ __forceinline__ float sigmoid_fast(float x) {
    return __builtin_amdgcn_rcpf(1.0f + __expf(-x));
}
__device__ __forceinline__ ushort f2bf(float x) {
    __hip_bfloat16 h = __float2bfloat16(x);   // RNE
    return __builtin_bit_cast(ushort, h);
}
// m204 bijective XCD-chunked swizzle (8 XCDs)
__device__ __forceinline__ int xcd_swz(int bid, int nwg) {
    const int q = nwg >> 3, r = nwg & 7;
    const int xcd = bid & 7, idx = bid >> 3;
    return (xcd < r ? xcd * (q + 1) : r * (q + 1) + (xcd - r) * q) + idx;
}
// block-local edge permutation: swap bits[3:2] <-> bits[5:4] (involution).
__device__ __forceinline__ int gperm(int l) {
    return (l & ~63) | (((l >> 2) & 3) << 4) | (((l >> 4) & 3) << 2) | (l & 3);
}
__device__ __forceinline__ void gload_lds16(const void* g, void* l) {
    __builtin_amdgcn_global_load_lds((const __attribute__((address_space(1))) void*)g,
                                     (__attribute__((address_space(3))) void*)l, 16, 0, 0);
}

// ws layout (N read on device):
//   float aggL[N*128]; float aggR[N*128]; float rd[N];
//   int ideg[N]; int ioff[N+1]; int icur[N]; int elist[E]; int epos[E];
//   ushort WgF[16*4*64*8]; ushort W1F[8*8*64*8];
//   float gwb[384]; float nstL[2N]; float nstR[2N]
//   ... tail of ws: ushort ynb[(E+128)*128]
struct WsPtrs {
    float *aggL, *aggR, *rd;
    int *ideg, *ioff, *icur, *elist, *epos;
    ushort *WgF, *W1F;
    float *gwb, *nstL, *nstR;
    int N;
};
__device__ __forceinline__ WsPtrs ws_ptrs(float* ws, const int* n_nodes_p, int E) {
    WsPtrs p;
    p.N    = *n_nodes_p;
    p.aggL = ws;
    p.aggR = ws + (size_t)p.N * 128;
    p.rd   = ws + (size_t)p.N * 256;
    p.ideg = (int*)(ws + (size_t)p.N * 257);
    p.ioff = p.ideg + p.N;
    p.icur = p.ioff + p.N + 1;
    p.elist = p.icur + p.N;
    p.epos  = p.elist + E;
    p.WgF = (ushort*)(((uintptr_t)(p.epos + E) + 15) & ~(uintptr_t)15);
    p.W1F = p.WgF + 32768;
    p.gwb = (float*)(p.W1F + 32768);
    p.nstL = p.gwb + 384;
    p.nstR = p.nstL + 2 * p.N;
    return p;
}

// ---------------- zero agg + deg ----------------
__global__ void init_kernel(float* __restrict__ ws, const int* __restrict__ n_nodes_p, int E) {
    WsPtrs p = ws_ptrs(ws, n_nodes_p, E);
    const long long stride = (long long)gridDim.x * blockDim.x;
    const long long tid = (long long)blockIdx.x * blockDim.x + threadIdx.x;
    const long long nf = (long long)p.N * 256;
    for (long long i = tid; i < nf; i += stride) ws[i] = 0.0f;
    for (long long i = tid; i < p.N; i += stride) p.ideg[i] = 0;
}

// ---------------- histogram of dst ----------------
__global__ void hist_kernel(const int* __restrict__ dst, float* __restrict__ ws,
                            const int* __restrict__ n_nodes_p, int E) {
    WsPtrs p = ws_ptrs(ws, n_nodes_p, E);
    const int i = blockIdx.x * blockDim.x + threadIdx.x;
    if (i < E) atomicAdd(&p.ideg[dst[i]], 1);
}

// ---------------- exclusive scan (single block, 1024 thr) + rd = 1/max(deg,1) ----------------
__global__ __launch_bounds__(1024) void scan_kernel(float* __restrict__ ws,
                                                    const int* __restrict__ n_nodes_p, int E) {
    WsPtrs p = ws_ptrs(ws, n_nodes_p, E);
    __shared__ int wsum[16];
    __shared__ int carry_s;
    const int t = threadIdx.x;
    const int lane = t & 63, wid = t >> 6;
    if (t == 0) carry_s = 0;
    __syncthreads();
    for (int base = 0; base < p.N; base += 4096) {
        const int i0 = base + t * 4;
        const int v0 = (i0 + 0 < p.N) ? p.ideg[i0 + 0] : 0;
        const int v1 = (i0 + 1 < p.N) ? p.ideg[i0 + 1] : 0;
        const int v2 = (i0 + 2 < p.N) ? p.ideg[i0 + 2] : 0;
        const int v3 = (i0 + 3 < p.N) ? p.ideg[i0 + 3] : 0;
        const int s = v0 + v1 + v2 + v3;
        int sc = s;
        #pragma unroll
        for (int off = 1; off < 64; off <<= 1) {
            const int n = __shfl_up(sc, off);
            if (lane >= off) sc += n;
        }
        if (lane == 63) wsum[wid] = sc;
        __syncthreads();
        int woff = 0;
        #pragma unroll
        for (int w = 0; w < 16; ++w) if (w < wid) woff += wsum[w];
        const int carry = carry_s;
        __syncthreads();
        const int excl = carry + woff + (sc - s);
        if (i0 + 0 < p.N) { p.ioff[i0+0] = excl;          p.icur[i0+0] = excl;          p.rd[i0+0] = 1.0f / fmaxf((float)v0, 1.0f); }
        if (i0 + 1 < p.N) { p.ioff[i0+1] = excl+v0;       p.icur[i0+1] = excl+v0;       p.rd[i0+1] = 1.0f / fmaxf((float)v1, 1.0f); }
        if (i0 + 2 < p.N) { p.ioff[i0+2] = excl+v0+v1;    p.icur[i0+2] = excl+v0+v1;    p.rd[i0+2] = 1.0f / fmaxf((float)v2, 1.0f); }
        if (i0 + 3 < p.N) { p.ioff[i0+3] = excl+v0+v1+v2; p.icur[i0+3] = excl+v0+v1+v2; p.rd[i0+3] = 1.0f / fmaxf((float)v3, 1.0f); }
        if (t == 1023) carry_s = carry + woff + sc;
        __syncthreads();
    }
    if (t == 0) p.ioff[p.N] = carry_s;
}

// ---------------- scatter edge ids into buckets + position map ----------------
__global__ void scatter_kernel(const int* __restrict__ dst, float* __restrict__ ws,
                               const int* __restrict__ n_nodes_p, int E) {
    WsPtrs p = ws_ptrs(ws, n_nodes_p, E);
    const int i = blockIdx.x * blockDim.x + threadIdx.x;
    if (i < E) {
        const int pos = atomicAdd(&p.icur[dst[i]], 1);
        p.elist[pos] = i;
        p.epos[i] = (pos & ~63) | gperm(pos & 63);
    }
}

// ---------------- build fragment-major bf16 B tables + split gW1 halves + bW1 ----------------
__global__ void prep_w_kernel(const float* __restrict__ Wl, const float* __restrict__ Wr,
                              const float* __restrict__ W1,
                              const float* __restrict__ ln2_g, const float* __restrict__ ln2_b,
                              const float* __restrict__ b1,
                              float* __restrict__ ws, const int* __restrict__ n_nodes_p, int E) {
    WsPtrs p = ws_ptrs(ws, n_nodes_p, E);
    const int i = blockIdx.x * blockDim.x + threadIdx.x;
    if (i < 32768) {
        const int i8 = i & 7, lane = (i >> 3) & 63, kf = (i >> 9) & 3, nblk = i >> 11;
        const int k = kf * 32 + (lane >> 4) * 8 + i8;
        const int n = nblk * 16 + (lane & 15);
        const float val = (n < 128) ? Wl[k * 128 + n] : Wr[k * 128 + (n - 128)];
        p.WgF[i] = f2bf(val);
    } else if (i < 65536) {
        const int j = i - 32768;
        const int i8 = j & 7, lane = (j >> 3) & 63, kf = (j >> 9) & 7, nblk = j >> 12;
        const int k = kf * 32 + (lane >> 4) * 8 + i8;
        const int n = nblk * 16 + (lane & 15);
        p.W1F[j] = f2bf(W1[k * 128 + n]);
    } else if (i < 65664) {
        const int j = i - 65536;   // 0..127
        float gsL = 0.f, gsR = 0.f, bs = 0.f;
        for (int k = 0; k < 128; ++k) {
            const float wt = W1[k * 128 + j];
            const float wb = W1[(k + 128) * 128 + j];
            gsL += ln2_g[k] * wt;
            gsR += ln2_g[k + 128] * wb;
            bs  += ln2_b[k] * wt + ln2_b[k + 128] * wb;
        }
        p.gwb[j]       = gsL;
        p.gwb[128 + j] = gsR;
        p.gwb[256 + j] = bs + b1[j];
    }
}

// ---------------- streaming LN(y) -> bf16, scatter-write to permuted-sorted order ----------------
__global__ __launch_bounds__(256) void ln_y_kernel(
    const float* __restrict__ y,
    const float* __restrict__ ln_g, const float* __restrict__ ln_b,
    float* __restrict__ ws, const int* __restrict__ n_nodes_p, int E,
    ushort* __restrict__ ynb)
{
    WsPtrs p = ws_ptrs(ws, n_nodes_p, E);
    const int t = threadIdx.x;
    const int e = blockIdx.x * 64 + (t >> 2);
    const int sub = t & 3;
    if (e >= E) return;

    const float* yr = y + (size_t)e * 128;
    float v[32];
    float s = 0.f, sq = 0.f;
    #pragma unroll
    for (int i = 0; i < 8; ++i) {
        const float4 q = *reinterpret_cast<const float4*>(yr + sub * 32 + i * 4);
        v[i*4+0] = q.x; v[i*4+1] = q.y; v[i*4+2] = q.z; v[i*4+3] = q.w;
        s  += q.x + q.y + q.z + q.w;
        sq += q.x*q.x + q.y*q.y + q.z*q.z + q.w*q.w;
    }
    s  += __shfl_xor(s, 1);  s  += __shfl_xor(s, 2);
    sq += __shfl_xor(sq, 1); sq += __shfl_xor(sq, 2);
    const float mu = s * (1.f / 128.f);
    const float rstd = rsqrtf(sq * (1.f / 128.f) - mu * mu + LN_EPS);

    ushort* dstrow = ynb + (size_t)p.epos[e] * 128 + sub * 32;
    #pragma unroll
    for (int i = 0; i < 4; ++i) {
        uint w32[4];
        #pragma unroll
        for (int h2 = 0; h2 < 4; ++h2) {
            const int c = sub * 32 + i * 8 + h2 * 2;
            const float x0 = (v[i*8 + h2*2 + 0] - mu) * rstd * ln_g[c + 0] + ln_b[c + 0];
            const float x1 = (v[i*8 + h2*2 + 1] - mu) * rstd * ln_g[c + 1] + ln_b[c + 1];
            w32[h2] = (uint)f2bf(x0) | ((uint)f2bf(x1) << 16);
        }
        *reinterpret_cast<uint4*>(dstrow + i * 8) = make_uint4(w32[0], w32[1], w32[2], w32[3]);
    }
}

// ---------------- gates: 64-edge tile, 8 waves, acc[4][2] (<=64 VGPR target) ----------------
__global__ __launch_bounds__(512, 8) void gates_kernel(
    const float* __restrict__ y, const int* __restrict__ dst,
    const float* __restrict__ ln_g, const float* __restrict__ ln_b,
    const float* __restrict__ bl, const float* __restrict__ br,
    float* __restrict__ ws, const int* __restrict__ n_nodes_p, int E,
    const ushort* __restrict__ ynb)
{
    __shared__ ushort sA[64 * 128];   // 16 KB
    __shared__ int sNode[64];

    WsPtrs p = ws_ptrs(ws, n_nodes_p, E);
    char* sAb = reinterpret_cast<char*>(sA);
    const int t = threadIdx.x;
    const int bid = xcd_swz(blockIdx.x, gridDim.x);
    const int s0 = bid * 64;
    const int lane = t & 63;
    const int w8 = t >> 6;

    if (t < 64) {
        const int j = s0 + t;
        const int eid = (j < E) ? p.elist[j] : -1;
        sNode[t] = (eid >= 0) ? dst[eid] : -1;
    }

    if (ynb) {
        const char* ybase = (const char*)ynb + (size_t)s0 * 256;
        #pragma unroll
        for (int i = 0; i < 2; ++i) {
            const int chunk = w8 * 2 + i;
            const int L = chunk * 1024 + lane * 16;
            const int b = L ^ (((L >> 8) & 7) << 4);
            gload_lds16(ybase + b, sAb + chunk * 1024);
        }
    } else {
        const int r = t >> 3, sub8 = t & 7;
        const int je = s0 + gperm(r);
        const int eid = (je < E) ? p.elist[je] : 0;
        const float* yr = y + (size_t)eid * 128;
        float v[16];
        float s = 0.f, sq = 0.f;
        #pragma unroll
        for (int i = 0; i < 4; ++i) {
            const float4 q = *reinterpret_cast<const float4*>(yr + sub8 * 16 + i * 4);
            v[i*4+0] = q.x; v[i*4+1] = q.y; v[i*4+2] = q.z; v[i*4+3] = q.w;
            s  += q.x + q.y + q.z + q.w;
            sq += q.x*q.x + q.y*q.y + q.z*q.z + q.w*q.w;
        }
        s  += __shfl_xor(s, 1);  s  += __shfl_xor(s, 2);  s  += __shfl_xor(s, 4);
        sq += __shfl_xor(sq, 1); sq += __shfl_xor(sq, 2); sq += __shfl_xor(sq, 4);
        const float mu = s * (1.f / 128.f);
        const float rstd = rsqrtf(sq * (1.f / 128.f) - mu * mu + LN_EPS);
        #pragma unroll
        for (int i = 0; i < 2; ++i) {
            uint w32[4];
            #pragma unroll
            for (int h2 = 0; h2 < 4; ++h2) {
                const int c = sub8 * 16 + i * 8 + h2 * 2;
                const float x0 = (v[i*8 + h2*2 + 0] - mu) * rstd * ln_g[c + 0] + ln_b[c + 0];
                const float x1 = (v[i*8 + h2*2 + 1] - mu) * rstd * ln_g[c + 1] + ln_b[c + 1];
                w32[h2] = (uint)f2bf(x0) | ((uint)f2bf(x1) << 16);
            }
            int byte = r * 256 + sub8 * 32 + i * 16;
            byte ^= ((byte >> 8) & 7) << 4;
            *reinterpret_cast<uint4*>(sAb + byte) = make_uint4(w32[0], w32[1], w32[2], w32[3]);
        }
    }
    __syncthreads();

    const int lhi = lane >> 4, llo = lane & 15;

    f32x4 acc[4][2];
    #pragma unroll
    for (int m = 0; m < 4; ++m)
        #pragma unroll
        for (int n = 0; n < 2; ++n) acc[m][n] = (f32x4){0.f, 0.f, 0.f, 0.f};

    #pragma unroll
    for (int kf = 0; kf < 4; ++kf) {
        bf16x8 b[2];
        #pragma unroll
        for (int nf = 0; nf < 2; ++nf) {
            const int nblk = w8 * 2 + nf;
            b[nf] = *reinterpret_cast<const bf16x8*>(p.WgF + ((size_t)(nblk * 4 + kf) * 64 + lane) * 8);
        }
        #pragma unroll
        for (int m = 0; m < 4; ++m) {
            const int row = m * 16 + llo;
            int byte = row * 256 + kf * 64 + lhi * 16;
            byte ^= ((byte >> 8) & 7) << 4;
            const bf16x8 a = *reinterpret_cast<const bf16x8*>(sAb + byte);
            acc[m][0] = __builtin_amdgcn_mfma_f32_16x16x32_bf16(a, b[0], acc[m][0], 0, 0, 0);
            acc[m][1] = __builtin_amdgcn_mfma_f32_16x16x32_bf16(a, b[1], acc[m][1], 0, 0, 0);
        }
    }

    const int g = w8 >> 2;
    float* ag = g ? p.aggR : p.aggL;
    const float* bp = g ? br : bl;
    const int lcol0 = (w8 & 3) * 32 + llo;   // col within gate (mod 128)
    const float bias0 = bp[lcol0];
    const float bias1 = bp[lcol0 + 16];

    float run0 = 0.f, run1 = 0.f;
    int rnode = -1;
    #pragma unroll
    for (int m = 0; m < 4; ++m) {
        #pragma unroll
        for (int j = 0; j < 4; ++j) {
            const int el = lhi * 16 + m * 4 + j;
            const int node = sNode[el];
            const float v0 = sigmoid_fast(acc[m][0][j] + bias0);
            const float v1 = sigmoid_fast(acc[m][1][j] + bias1);
            if (node != rnode) {
                if (rnode >= 0) {
                    float* dest = ag + (size_t)rnode * 128 + lcol0;
                    atomicAdd(dest +  0, run0);
                    atomicAdd(dest + 16, run1);
                }
                rnode = node;
                run0 = v0; run1 = v1;
            } else {
                run0 += v0; run1 += v1;
            }
        }
    }
    if (rnode >= 0) {
        float* dest = ag + (size_t)rnode * 128 + lcol0;
        atomicAdd(dest +  0, run0);
        atomicAdd(dest + 16, run1);
    }
}

// ---------------- node_mlp: u = ((z - mu_node) ⊙ g2) @ W1half -> bf16 IN PLACE; stats ----------------
__global__ __launch_bounds__(512) void node_mlp_kernel(
    const float* __restrict__ ln2_g,
    float* __restrict__ ws, const int* __restrict__ n_nodes_p, int E)
{
    __shared__ ushort sA[128 * 256];   // 64 KB

    WsPtrs p = ws_ptrs(ws, n_nodes_p, E);
    char* sAb = reinterpret_cast<char*>(sA);
    const int t = threadIdx.x;
    const int n0 = blockIdx.x * 128;

    {
        const int r = t >> 2, sub = t & 3;
        const int n = n0 + r;
        const bool vld = n < p.N;
        const int nn = vld ? n : (p.N - 1);
        const float* base = ((sub < 2) ? p.aggL : p.aggR) + (size_t)nn * 128 + (sub & 1) * 64;
        const float scale = vld ? p.rd[nn] : 0.f;
        const int cb = ((sub >> 1) << 7) + ((sub & 1) << 6);   // concat col base

        float s = 0.f, sq = 0.f;
        #pragma unroll
        for (int ii = 0; ii < 8; ++ii) {
            const float4 qa = *reinterpret_cast<const float4*>(base + ii * 8);
            const float4 qb = *reinterpret_cast<const float4*>(base + ii * 8 + 4);
            s  += qa.x + qa.y + qa.z + qa.w + qb.x + qb.y + qb.z + qb.w;
            sq += qa.x*qa.x + qa.y*qa.y + qa.z*qa.z + qa.w*qa.w
                + qb.x*qb.x + qb.y*qb.y + qb.z*qb.z + qb.w*qb.w;
        }
        s *= scale; sq *= scale * scale;
        s  += __shfl_xor(s, 1);
        sq += __shfl_xor(sq, 1);
        if (vld && sub == 0) { p.nstL[2*n] = s; p.nstL[2*n+1] = sq; }
        if (vld && sub == 2) { p.nstR[2*n] = s; p.nstR[2*n+1] = sq; }
        const float mu_n = s * (1.f / 128.f);

        #pragma unroll
        for (int ii = 0; ii < 8; ++ii) {
            const float4 qa = *reinterpret_cast<const float4*>(base + ii * 8);
            const float4 qb = *reinterpret_cast<const float4*>(base + ii * 8 + 4);
            const float xs[8] = { qa.x*scale - mu_n, qa.y*scale - mu_n, qa.z*scale - mu_n, qa.w*scale - mu_n,
                                  qb.x*scale - mu_n, qb.y*scale - mu_n, qb.z*scale - mu_n, qb.w*scale - mu_n };
            uint w32[4];
            #pragma unroll
            for (int h2 = 0; h2 < 4; ++h2) {
                const int c = cb + ii * 8 + h2 * 2;
                w32[h2] = (uint)f2bf(xs[h2*2+0] * ln2_g[c+0]) |
                          ((uint)f2bf(xs[h2*2+1] * ln2_g[c+1]) << 16);
            }
            int byte = r * 512 + cb * 2 + ii * 16;
            byte ^= ((byte >> 9) & 7) << 4;
            *reinterpret_cast<uint4*>(sAb + byte) = make_uint4(w32[0], w32[1], w32[2], w32[3]);
        }
    }
    __syncthreads();

    const int lane = t & 63;
    const int w8 = t >> 6;
    const int rowh = w8 >> 2, colw = w8 & 3;
    const int half = colw >> 1;                  // 0 -> uL, 1 -> uR
    const int lhi = lane >> 4, llo = lane & 15;

    f32x4 acc[4][4];
    #pragma unroll
    for (int m = 0; m < 4; ++m)
        #pragma unroll
        for (int n = 0; n < 4; ++n) acc[m][n] = (f32x4){0.f, 0.f, 0.f, 0.f};

    #pragma unroll
    for (int kfl = 0; kfl < 4; ++kfl) {
        bf16x8 a[4], b[4];
        #pragma unroll
        for (int m = 0; m < 4; ++m) {
            const int row = rowh * 64 + m * 16 + llo;
            int byte = row * 512 + half * 256 + kfl * 64 + lhi * 16;
            byte ^= ((byte >> 9) & 7) << 4;
            a[m] = *reinterpret_cast<const bf16x8*>(sAb + byte);
        }
        #pragma unroll
        for (int nf = 0; nf < 4; ++nf) {
            const int nblk = (colw & 1) * 4 + nf;
            const int kf = half * 4 + kfl;
            b[nf] = *reinterpret_cast<const bf16x8*>(p.W1F + ((size_t)(nblk * 8 + kf) * 64 + lane) * 8);
        }
        #pragma unroll
        for (int m = 0; m < 4; ++m)
            #pragma unroll
            for (int nf = 0; nf < 4; ++nf)
                acc[m][nf] = __builtin_amdgcn_mfma_f32_16x16x32_bf16(a[m], b[nf], acc[m][nf], 0, 0, 0);
    }

    ushort* u16 = (ushort*)(half ? p.aggR : p.aggL);
    #pragma unroll
    for (int m = 0; m < 4; ++m) {
        #pragma unroll
        for (int j = 0; j < 4; ++j) {
            const int n = n0 + rowh * 64 + m * 16 + lhi * 4 + j;
            if (n < p.N) {
                const int col = (colw & 1) * 64 + llo;
                #pragma unroll
                for (int nf = 0; nf < 4; ++nf)
                    u16[(size_t)n * 256 + col + nf * 16] = f2bf(acc[m][nf][j]);
            }
        }
    }
}

// ---------------- edge_out: 32-lane sub-wave per edge (2 edges/wave in flight) ----------------
// Each lane owns 4 cols (uint2 bf16 u-loads, float4 constants); 5-deep shfl reduce.
// dst-run cache per sub-wave (elist dst-bucketed; stride-2 walk keeps runs).
__global__ __launch_bounds__(256) void edge_out_kernel(
    const int* __restrict__ src, const int* __restrict__ dst,
    const float* __restrict__ W2, const float* __restrict__ b2,
    float* __restrict__ ws, const int* __restrict__ n_nodes_p,
    float* __restrict__ out, int E)
{
    WsPtrs p = ws_ptrs(ws, n_nodes_p, E);
    const ushort* uLb = (const ushort*)p.aggL;   // bf16 rows, stride 256 ushorts
    const ushort* uRb = (const ushort*)p.aggR;
    const int t = threadIdx.x;
    const int lane = t & 63;
    const int g = lane >> 5;        // sub-wave 0/1
    const int sl = lane & 31;       // lane within sub-wave; owns cols sl*4..sl*4+3
    const int wv = blockIdx.x * 4 + (t >> 6);
    const int nw = gridDim.x * 4;
    const int span = (E + nw - 1) / nw;
    const int j0 = wv * span;
    const int j1 = min(E, j0 + span);

    const float4 gwl = *reinterpret_cast<const float4*>(p.gwb + sl * 4);
    const float4 gwr = *reinterpret_cast<const float4*>(p.gwb + 128 + sl * 4);
    const float4 bw  = *reinterpret_cast<const float4*>(p.gwb + 256 + sl * 4);
    const float4 w2  = *reinterpret_cast<const float4*>(W2 + sl * 4);
    const float b2v = b2[0];

    // dst-run cache (per sub-wave)
    int dc = -1;
    float ur0 = 0.f, ur1 = 0.f, ur2 = 0.f, ur3 = 0.f;
    float2 nsr = make_float2(0.f, 0.f);

    for (int j = j0 + g; j < j1; j += 2) {
        const int eid = p.elist[j];
        const int s = src[eid], d = dst[eid];
        if (d != dc) {
            const uint2 urp = *reinterpret_cast<const uint2*>(uRb + (size_t)d * 256 + sl * 4);
            ur0 = __builtin_bit_cast(float, urp.x << 16);
            ur1 = __builtin_bit_cast(float, urp.x & 0xffff0000u);
            ur2 = __builtin_bit_cast(float, urp.y << 16);
            ur3 = __builtin_bit_cast(float, urp.y & 0xffff0000u);
            nsr = *reinterpret_cast<const float2*>(p.nstR + 2 * d);
            dc = d;
        }
        const uint2 ulp = *reinterpret_cast<const uint2*>(uLb + (size_t)s * 256 + sl * 4);
        const float ul0 = __builtin_bit_cast(float, ulp.x << 16);
        const float ul1 = __builtin_bit_cast(float, ulp.x & 0xffff0000u);
        const float ul2 = __builtin_bit_cast(float, ulp.y << 16);
        const float ul3 = __builtin_bit_cast(float, ulp.y & 0xffff0000u);
        const float2 nsl = *reinterpret_cast<const float2*>(p.nstL + 2 * s);
        const float mu = (nsl.x + nsr.x) * (1.f / 256.f);
        const float var = (nsl.y + nsr.y) * (1.f / 256.f) - mu * mu;
        const float rstd = rsqrtf(var + LN_EPS);
        const float dL = nsl.x * (1.f / 128.f) - mu;
        const float dR = nsr.x * (1.f / 128.f) - mu;
        float x0 = rstd * (ul0 + ur0 + dL * gwl.x + dR * gwr.x) + bw.x;
        float x1 = rstd * (ul1 + ur1 + dL * gwl.y + dR * gwr.y) + bw.y;
        float x2 = rstd * (ul2 + ur2 + dL * gwl.z + dR * gwr.z) + bw.z;
        float x3 = rstd * (ul3 + ur3 + dL * gwl.w + dR * gwr.w) + bw.w;
        x0 = x0 > 0.f ? x0 : __expf(x0) - 1.f;
        x1 = x1 > 0.f ? x1 : __expf(x1) - 1.f;
        x2 = x2 > 0.f ? x2 : __expf(x2) - 1.f;
        x3 = x3 > 0.f ? x3 : __expf(x3) - 1.f;
        float a = x0 * w2.x + x1 * w2.y + x2 * w2.z + x3 * w2.w;
        #pragma unroll
        for (int m = 16; m >= 1; m >>= 1) a += __shfl_xor(a, m);
        if (sl == 0) out[eid] = a + b2v;
    }
}

extern "C" void kernel_launch(void* const* d_in, const int* in_sizes, int n_in,
                              void* d_out, int out_size, void* d_ws, size_t ws_size,
                              hipStream_t stream) {
    const float* y       = (const float*)d_in[0];
    const int*   src     = (const int*)d_in[1];
    const int*   dst     = (const int*)d_in[2];
    const int*   n_nodes = (const int*)d_in[3];
    const float* ln_g    = (const float*)d_in[4];
    const float* ln_b    = (const float*)d_in[5];
    const float* Wl      = (const float*)d_in[6];
    const float* bl      = (const float*)d_in[7];
    const float* Wr      = (const float*)d_in[8];
    const float* br      = (const float*)d_in[9];
    const float* ln2_g   = (const float*)d_in[10];
    const float* ln2_b   = (const float*)d_in[11];
    const float* W1      = (const float*)d_in[12];
    const float* b1      = (const float*)d_in[13];
    const float* W2      = (const float*)d_in[14];
    const float* b2      = (const float*)d_in[15];
    float* out = (float*)d_out;
    float* ws  = (float*)d_ws;

    const int E = in_sizes[0] / 128;
    const int eb64 = (E + 63) / 64;
    const int N_MAX = 40000;   // grid sizing only; device code reads *n_nodes

    const size_t need = (size_t)(E + 128) * 256;
    const bool use_pre = ws_size >= need + (96ull << 20);
    ushort* ynb = use_pre
        ? (ushort*)(((uintptr_t)ws + ws_size - need) & ~(uintptr_t)255)
        : nullptr;

    init_kernel<<<2048, 256, 0, stream>>>(ws, n_nodes, E);
    hist_kernel<<<(E + 255) / 256, 256, 0, stream>>>(dst, ws, n_nodes, E);
    scan_kernel<<<1, 1024, 0, stream>>>(ws, n_nodes, E);
    scatter_kernel<<<(E + 255) / 256, 256, 0, stream>>>(dst, ws, n_nodes, E);
    prep_w_kernel<<<257, 256, 0, stream>>>(Wl, Wr, W1, ln2_g, ln2_b, b1, ws, n_nodes, E);
    if (use_pre)
        ln_y_kernel<<<(E + 63) / 64, 256, 0, stream>>>(y, ln_g, ln_b, ws, n_nodes, E, ynb);
    gates_kernel<<<eb64, 512, 0, stream>>>(y, dst, ln_g, ln_b, bl, br, ws, n_nodes, E, ynb);
    node_mlp_kernel<<<(N_MAX + 127) / 128, 512, 0, stream>>>(ln2_g, ws, n_nodes, E);
    edge_out_kernel<<<2048, 256, 0, stream>>>(src, dst, W2, b2, ws, n_nodes, out, E);
}

// Round 13
// 497.620 us; speedup vs baseline: 1.6748x; 1.0137x over previous
//
#include <hip/hip_runtime.h>
#include <hip/hip_bf16.h>

#define LN_EPS 1e-5f

typedef __attribute__((ext_vector_type(8))) short bf16x8;
typedef __attribute__((ext_vector_type(4))) float f32x4;

__device__ __forceinline__ float sigmoid_fast(float x) {
    return __builtin_amdgcn_rcpf(1.0f + __expf(-x));
}
__device__ __forceinline__ ushort f2bf(float x) {
    __hip_bfloat16 h = __float2bfloat16(x);   // RNE
    return __builtin_bit_cast(ushort, h);
}
// m204 bijective XCD-chunked swizzle (8 XCDs)
__device__ __forceinline__ int xcd_swz(int bid, int nwg) {
    const int q = nwg >> 3, r = nwg & 7;
    const int xcd = bid & 7, idx = bid >> 3;
    return (xcd < r ? xcd * (q + 1) : r * (q + 1) + (xcd - r) * q) + idx;
}
// block-local edge permutation: swap bits[3:2] <-> bits[5:4] (involution).
__device__ __forceinline__ int gperm(int l) {
    return (l & ~63) | (((l >> 2) & 3) << 4) | (((l >> 4) & 3) << 2) | (l & 3);
}
__device__ __forceinline__ void gload_lds16(const void* g, void* l) {
    __builtin_amdgcn_global_load_lds((const __attribute__((address_space(1))) void*)g,
                                     (__attribute__((address_space(3))) void*)l, 16, 0, 0);
}

// ws layout (N read on device):
//   float aggL[N*128]; float aggR[N*128]; float rd[N];
//   int ideg[N]; int ioff[N+1]; int icur[N]; int elist[E]; int epos[E];
//   ushort WgF[16*4*64*8]; ushort W1F[8*8*64*8];
//   float gwb[384]; float nstL[2N]; float nstR[2N]
//   ... tail of ws: ushort ynb[(E+128)*128]
struct WsPtrs {
    float *aggL, *aggR, *rd;
    int *ideg, *ioff, *icur, *elist, *epos;
    ushort *WgF, *W1F;
    float *gwb, *nstL, *nstR;
    int N;
};
__device__ __forceinline__ WsPtrs ws_ptrs(float* ws, const int* n_nodes_p, int E) {
    WsPtrs p;
    p.N    = *n_nodes_p;
    p.aggL = ws;
    p.aggR = ws + (size_t)p.N * 128;
    p.rd   = ws + (size_t)p.N * 256;
    p.ideg = (int*)(ws + (size_t)p.N * 257);
    p.ioff = p.ideg + p.N;
    p.icur = p.ioff + p.N + 1;
    p.elist = p.icur + p.N;
    p.epos  = p.elist + E;
    p.WgF = (ushort*)(((uintptr_t)(p.epos + E) + 15) & ~(uintptr_t)15);
    p.W1F = p.WgF + 32768;
    p.gwb = (float*)(p.W1F + 32768);
    p.nstL = p.gwb + 384;
    p.nstR = p.nstL + 2 * p.N;
    return p;
}

// ---------------- zero agg + deg ----------------
__global__ void init_kernel(float* __restrict__ ws, const int* __restrict__ n_nodes_p, int E) {
    WsPtrs p = ws_ptrs(ws, n_nodes_p, E);
    const long long stride = (long long)gridDim.x * blockDim.x;
    const long long tid = (long long)blockIdx.x * blockDim.x + threadIdx.x;
    const long long nf = (long long)p.N * 256;
    for (long long i = tid; i < nf; i += stride) ws[i] = 0.0f;
    for (long long i = tid; i < p.N; i += stride) p.ideg[i] = 0;
}

// ---------------- histogram of dst + (merged) fragment-major B tables + gW1/bW1 ----------------
// Blocks [0, histBlocks): histogram. Blocks [histBlocks, histBlocks+257): prep_w work.
__global__ void hist_prep_kernel(const int* __restrict__ dst,
                                 const float* __restrict__ Wl, const float* __restrict__ Wr,
                                 const float* __restrict__ W1,
                                 const float* __restrict__ ln2_g, const float* __restrict__ ln2_b,
                                 const float* __restrict__ b1,
                                 float* __restrict__ ws, const int* __restrict__ n_nodes_p,
                                 int E, int histBlocks) {
    WsPtrs p = ws_ptrs(ws, n_nodes_p, E);
    const int t = threadIdx.x;
    if ((int)blockIdx.x < histBlocks) {
        const int i = blockIdx.x * 256 + t;
        if (i < E) atomicAdd(&p.ideg[dst[i]], 1);
        return;
    }
    const int i = (blockIdx.x - histBlocks) * 256 + t;
    if (i < 32768) {
        const int i8 = i & 7, lane = (i >> 3) & 63, kf = (i >> 9) & 3, nblk = i >> 11;
        const int k = kf * 32 + (lane >> 4) * 8 + i8;
        const int n = nblk * 16 + (lane & 15);
        const float val = (n < 128) ? Wl[k * 128 + n] : Wr[k * 128 + (n - 128)];
        p.WgF[i] = f2bf(val);
    } else if (i < 65536) {
        const int j = i - 32768;
        const int i8 = j & 7, lane = (j >> 3) & 63, kf = (j >> 9) & 7, nblk = j >> 12;
        const int k = kf * 32 + (lane >> 4) * 8 + i8;
        const int n = nblk * 16 + (lane & 15);
        p.W1F[j] = f2bf(W1[k * 128 + n]);
    } else if (i < 65664) {
        const int j = i - 65536;   // 0..127
        float gsL = 0.f, gsR = 0.f, bs = 0.f;
        for (int k = 0; k < 128; ++k) {
            const float wt = W1[k * 128 + j];
            const float wb = W1[(k + 128) * 128 + j];
            gsL += ln2_g[k] * wt;
            gsR += ln2_g[k + 128] * wb;
            bs  += ln2_b[k] * wt + ln2_b[k + 128] * wb;
        }
        p.gwb[j]       = gsL;
        p.gwb[128 + j] = gsR;
        p.gwb[256 + j] = bs + b1[j];
    }
}

// ---------------- exclusive scan (single block, 1024 thr) + rd = 1/max(deg,1) ----------------
__global__ __launch_bounds__(1024) void scan_kernel(float* __restrict__ ws,
                                                    const int* __restrict__ n_nodes_p, int E) {
    WsPtrs p = ws_ptrs(ws, n_nodes_p, E);
    __shared__ int wsum[16];
    __shared__ int carry_s;
    const int t = threadIdx.x;
    const int lane = t & 63, wid = t >> 6;
    if (t == 0) carry_s = 0;
    __syncthreads();
    for (int base = 0; base < p.N; base += 4096) {
        const int i0 = base + t * 4;
        const int v0 = (i0 + 0 < p.N) ? p.ideg[i0 + 0] : 0;
        const int v1 = (i0 + 1 < p.N) ? p.ideg[i0 + 1] : 0;
        const int v2 = (i0 + 2 < p.N) ? p.ideg[i0 + 2] : 0;
        const int v3 = (i0 + 3 < p.N) ? p.ideg[i0 + 3] : 0;
        const int s = v0 + v1 + v2 + v3;
        int sc = s;
        #pragma unroll
        for (int off = 1; off < 64; off <<= 1) {
            const int n = __shfl_up(sc, off);
            if (lane >= off) sc += n;
        }
        if (lane == 63) wsum[wid] = sc;
        __syncthreads();
        int woff = 0;
        #pragma unroll
        for (int w = 0; w < 16; ++w) if (w < wid) woff += wsum[w];
        const int carry = carry_s;
        __syncthreads();
        const int excl = carry + woff + (sc - s);
        if (i0 + 0 < p.N) { p.ioff[i0+0] = excl;          p.icur[i0+0] = excl;          p.rd[i0+0] = 1.0f / fmaxf((float)v0, 1.0f); }
        if (i0 + 1 < p.N) { p.ioff[i0+1] = excl+v0;       p.icur[i0+1] = excl+v0;       p.rd[i0+1] = 1.0f / fmaxf((float)v1, 1.0f); }
        if (i0 + 2 < p.N) { p.ioff[i0+2] = excl+v0+v1;    p.icur[i0+2] = excl+v0+v1;    p.rd[i0+2] = 1.0f / fmaxf((float)v2, 1.0f); }
        if (i0 + 3 < p.N) { p.ioff[i0+3] = excl+v0+v1+v2; p.icur[i0+3] = excl+v0+v1+v2; p.rd[i0+3] = 1.0f / fmaxf((float)v3, 1.0f); }
        if (t == 1023) carry_s = carry + woff + sc;
        __syncthreads();
    }
    if (t == 0) p.ioff[p.N] = carry_s;
}

// ---------------- scatter edge ids into buckets + position map ----------------
__global__ void scatter_kernel(const int* __restrict__ dst, float* __restrict__ ws,
                               const int* __restrict__ n_nodes_p, int E) {
    WsPtrs p = ws_ptrs(ws, n_nodes_p, E);
    const int i = blockIdx.x * blockDim.x + threadIdx.x;
    if (i < E) {
        const int pos = atomicAdd(&p.icur[dst[i]], 1);
        p.elist[pos] = i;
        p.epos[i] = (pos & ~63) | gperm(pos & 63);
    }
}

// ---------------- streaming LN(y) -> bf16, scatter-write to permuted-sorted order ----------------
__global__ __launch_bounds__(256) void ln_y_kernel(
    const float* __restrict__ y,
    const float* __restrict__ ln_g, const float* __restrict__ ln_b,
    float* __restrict__ ws, const int* __restrict__ n_nodes_p, int E,
    ushort* __restrict__ ynb)
{
    WsPtrs p = ws_ptrs(ws, n_nodes_p, E);
    const int t = threadIdx.x;
    const int e = blockIdx.x * 64 + (t >> 2);
    const int sub = t & 3;
    if (e >= E) return;

    const float* yr = y + (size_t)e * 128;
    float v[32];
    float s = 0.f, sq = 0.f;
    #pragma unroll
    for (int i = 0; i < 8; ++i) {
        const float4 q = *reinterpret_cast<const float4*>(yr + sub * 32 + i * 4);
        v[i*4+0] = q.x; v[i*4+1] = q.y; v[i*4+2] = q.z; v[i*4+3] = q.w;
        s  += q.x + q.y + q.z + q.w;
        sq += q.x*q.x + q.y*q.y + q.z*q.z + q.w*q.w;
    }
    s  += __shfl_xor(s, 1);  s  += __shfl_xor(s, 2);
    sq += __shfl_xor(sq, 1); sq += __shfl_xor(sq, 2);
    const float mu = s * (1.f / 128.f);
    const float rstd = rsqrtf(sq * (1.f / 128.f) - mu * mu + LN_EPS);

    ushort* dstrow = ynb + (size_t)p.epos[e] * 128 + sub * 32;
    #pragma unroll
    for (int i = 0; i < 4; ++i) {
        uint w32[4];
        #pragma unroll
        for (int h2 = 0; h2 < 4; ++h2) {
            const int c = sub * 32 + i * 8 + h2 * 2;
            const float x0 = (v[i*8 + h2*2 + 0] - mu) * rstd * ln_g[c + 0] + ln_b[c + 0];
            const float x1 = (v[i*8 + h2*2 + 1] - mu) * rstd * ln_g[c + 1] + ln_b[c + 1];
            w32[h2] = (uint)f2bf(x0) | ((uint)f2bf(x1) << 16);
        }
        *reinterpret_cast<uint4*>(dstrow + i * 8) = make_uint4(w32[0], w32[1], w32[2], w32[3]);
    }
}

// ---------------- gates: 64-edge tile, 8 waves, acc[4][2] (<=64 VGPR target) ----------------
__global__ __launch_bounds__(512, 8) void gates_kernel(
    const float* __restrict__ y, const int* __restrict__ dst,
    const float* __restrict__ ln_g, const float* __restrict__ ln_b,
    const float* __restrict__ bl, const float* __restrict__ br,
    float* __restrict__ ws, const int* __restrict__ n_nodes_p, int E,
    const ushort* __restrict__ ynb)
{
    __shared__ ushort sA[64 * 128];   // 16 KB
    __shared__ int sNode[64];

    WsPtrs p = ws_ptrs(ws, n_nodes_p, E);
    char* sAb = reinterpret_cast<char*>(sA);
    const int t = threadIdx.x;
    const int bid = xcd_swz(blockIdx.x, gridDim.x);
    const int s0 = bid * 64;
    const int lane = t & 63;
    const int w8 = t >> 6;

    if (t < 64) {
        const int j = s0 + t;
        const int eid = (j < E) ? p.elist[j] : -1;
        sNode[t] = (eid >= 0) ? dst[eid] : -1;
    }

    if (ynb) {
        const char* ybase = (const char*)ynb + (size_t)s0 * 256;
        #pragma unroll
        for (int i = 0; i < 2; ++i) {
            const int chunk = w8 * 2 + i;
            const int L = chunk * 1024 + lane * 16;
            const int b = L ^ (((L >> 8) & 7) << 4);
            gload_lds16(ybase + b, sAb + chunk * 1024);
        }
    } else {
        const int r = t >> 3, sub8 = t & 7;
        const int je = s0 + gperm(r);
        const int eid = (je < E) ? p.elist[je] : 0;
        const float* yr = y + (size_t)eid * 128;
        float v[16];
        float s = 0.f, sq = 0.f;
        #pragma unroll
        for (int i = 0; i < 4; ++i) {
            const float4 q = *reinterpret_cast<const float4*>(yr + sub8 * 16 + i * 4);
            v[i*4+0] = q.x; v[i*4+1] = q.y; v[i*4+2] = q.z; v[i*4+3] = q.w;
            s  += q.x + q.y + q.z + q.w;
            sq += q.x*q.x + q.y*q.y + q.z*q.z + q.w*q.w;
        }
        s  += __shfl_xor(s, 1);  s  += __shfl_xor(s, 2);  s  += __shfl_xor(s, 4);
        sq += __shfl_xor(sq, 1); sq += __shfl_xor(sq, 2); sq += __shfl_xor(sq, 4);
        const float mu = s * (1.f / 128.f);
        const float rstd = rsqrtf(sq * (1.f / 128.f) - mu * mu + LN_EPS);
        #pragma unroll
        for (int i = 0; i < 2; ++i) {
            uint w32[4];
            #pragma unroll
            for (int h2 = 0; h2 < 4; ++h2) {
                const int c = sub8 * 16 + i * 8 + h2 * 2;
                const float x0 = (v[i*8 + h2*2 + 0] - mu) * rstd * ln_g[c + 0] + ln_b[c + 0];
                const float x1 = (v[i*8 + h2*2 + 1] - mu) * rstd * ln_g[c + 1] + ln_b[c + 1];
                w32[h2] = (uint)f2bf(x0) | ((uint)f2bf(x1) << 16);
            }
            int byte = r * 256 + sub8 * 32 + i * 16;
            byte ^= ((byte >> 8) & 7) << 4;
            *reinterpret_cast<uint4*>(sAb + byte) = make_uint4(w32[0], w32[1], w32[2], w32[3]);
        }
    }
    __syncthreads();

    const int lhi = lane >> 4, llo = lane & 15;

    f32x4 acc[4][2];
    #pragma unroll
    for (int m = 0; m < 4; ++m)
        #pragma unroll
        for (int n = 0; n < 2; ++n) acc[m][n] = (f32x4){0.f, 0.f, 0.f, 0.f};

    #pragma unroll
    for (int kf = 0; kf < 4; ++kf) {
        bf16x8 b[2];
        #pragma unroll
        for (int nf = 0; nf < 2; ++nf) {
            const int nblk = w8 * 2 + nf;
            b[nf] = *reinterpret_cast<const bf16x8*>(p.WgF + ((size_t)(nblk * 4 + kf) * 64 + lane) * 8);
        }
        #pragma unroll
        for (int m = 0; m < 4; ++m) {
            const int row = m * 16 + llo;
            int byte = row * 256 + kf * 64 + lhi * 16;
            byte ^= ((byte >> 8) & 7) << 4;
            const bf16x8 a = *reinterpret_cast<const bf16x8*>(sAb + byte);
            acc[m][0] = __builtin_amdgcn_mfma_f32_16x16x32_bf16(a, b[0], acc[m][0], 0, 0, 0);
            acc[m][1] = __builtin_amdgcn_mfma_f32_16x16x32_bf16(a, b[1], acc[m][1], 0, 0, 0);
        }
    }

    const int g = w8 >> 2;
    float* ag = g ? p.aggR : p.aggL;
    const float* bp = g ? br : bl;
    const int lcol0 = (w8 & 3) * 32 + llo;   // col within gate (mod 128)
    const float bias0 = bp[lcol0];
    const float bias1 = bp[lcol0 + 16];

    float run0 = 0.f, run1 = 0.f;
    int rnode = -1;
    #pragma unroll
    for (int m = 0; m < 4; ++m) {
        #pragma unroll
        for (int j = 0; j < 4; ++j) {
            const int el = lhi * 16 + m * 4 + j;
            const int node = sNode[el];
            const float v0 = sigmoid_fast(acc[m][0][j] + bias0);
            const float v1 = sigmoid_fast(acc[m][1][j] + bias1);
            if (node != rnode) {
                if (rnode >= 0) {
                    float* dest = ag + (size_t)rnode * 128 + lcol0;
                    atomicAdd(dest +  0, run0);
                    atomicAdd(dest + 16, run1);
                }
                rnode = node;
                run0 = v0; run1 = v1;
            } else {
                run0 += v0; run1 += v1;
            }
        }
    }
    if (rnode >= 0) {
        float* dest = ag + (size_t)rnode * 128 + lcol0;
        atomicAdd(dest +  0, run0);
        atomicAdd(dest + 16, run1);
    }
}

// ---------------- node_mlp: u = ((z - mu_node) ⊙ g2) @ W1half -> bf16 IN PLACE; stats ----------------
__global__ __launch_bounds__(512) void node_mlp_kernel(
    const float* __restrict__ ln2_g,
    float* __restrict__ ws, const int* __restrict__ n_nodes_p, int E)
{
    __shared__ ushort sA[128 * 256];   // 64 KB

    WsPtrs p = ws_ptrs(ws, n_nodes_p, E);
    char* sAb = reinterpret_cast<char*>(sA);
    const int t = threadIdx.x;
    const int n0 = blockIdx.x * 128;

    {
        const int r = t >> 2, sub = t & 3;
        const int n = n0 + r;
        const bool vld = n < p.N;
        const int nn = vld ? n : (p.N - 1);
        const float* base = ((sub < 2) ? p.aggL : p.aggR) + (size_t)nn * 128 + (sub & 1) * 64;
        const float scale = vld ? p.rd[nn] : 0.f;
        const int cb = ((sub >> 1) << 7) + ((sub & 1) << 6);   // concat col base

        float s = 0.f, sq = 0.f;
        #pragma unroll
        for (int ii = 0; ii < 8; ++ii) {
            const float4 qa = *reinterpret_cast<const float4*>(base + ii * 8);
            const float4 qb = *reinterpret_cast<const float4*>(base + ii * 8 + 4);
            s  += qa.x + qa.y + qa.z + qa.w + qb.x + qb.y + qb.z + qb.w;
            sq += qa.x*qa.x + qa.y*qa.y + qa.z*qa.z + qa.w*qa.w
                + qb.x*qb.x + qb.y*qb.y + qb.z*qb.z + qb.w*qb.w;
        }
        s *= scale; sq *= scale * scale;
        s  += __shfl_xor(s, 1);
        sq += __shfl_xor(sq, 1);
        if (vld && sub == 0) { p.nstL[2*n] = s; p.nstL[2*n+1] = sq; }
        if (vld && sub == 2) { p.nstR[2*n] = s; p.nstR[2*n+1] = sq; }
        const float mu_n = s * (1.f / 128.f);

        #pragma unroll
        for (int ii = 0; ii < 8; ++ii) {
            const float4 qa = *reinterpret_cast<const float4*>(base + ii * 8);
            const float4 qb = *reinterpret_cast<const float4*>(base + ii * 8 + 4);
            const float xs[8] = { qa.x*scale - mu_n, qa.y*scale - mu_n, qa.z*scale - mu_n, qa.w*scale - mu_n,
                                  qb.x*scale - mu_n, qb.y*scale - mu_n, qb.z*scale - mu_n, qb.w*scale - mu_n };
            uint w32[4];
            #pragma unroll
            for (int h2 = 0; h2 < 4; ++h2) {
                const int c = cb + ii * 8 + h2 * 2;
                w32[h2] = (uint)f2bf(xs[h2*2+0] * ln2_g[c+0]) |
                          ((uint)f2bf(xs[h2*2+1] * ln2_g[c+1]) << 16);
            }
            int byte = r * 512 + cb * 2 + ii * 16;
            byte ^= ((byte >> 9) & 7) << 4;
            *reinterpret_cast<uint4*>(sAb + byte) = make_uint4(w32[0], w32[1], w32[2], w32[3]);
        }
    }
    __syncthreads();

    const int lane = t & 63;
    const int w8 = t >> 6;
    const int rowh = w8 >> 2, colw = w8 & 3;
    const int half = colw >> 1;                  // 0 -> uL, 1 -> uR
    const int lhi = lane >> 4, llo = lane & 15;

    f32x4 acc[4][4];
    #pragma unroll
    for (int m = 0; m < 4; ++m)
        #pragma unroll
        for (int n = 0; n < 4; ++n) acc[m][n] = (f32x4){0.f, 0.f, 0.f, 0.f};

    #pragma unroll
    for (int kfl = 0; kfl < 4; ++kfl) {
        bf16x8 a[4], b[4];
        #pragma unroll
        for (int m = 0; m < 4; ++m) {
            const int row = rowh * 64 + m * 16 + llo;
            int byte = row * 512 + half * 256 + kfl * 64 + lhi * 16;
            byte ^= ((byte >> 9) & 7) << 4;
            a[m] = *reinterpret_cast<const bf16x8*>(sAb + byte);
        }
        #pragma unroll
        for (int nf = 0; nf < 4; ++nf) {
            const int nblk = (colw & 1) * 4 + nf;
            const int kf = half * 4 + kfl;
            b[nf] = *reinterpret_cast<const bf16x8*>(p.W1F + ((size_t)(nblk * 8 + kf) * 64 + lane) * 8);
        }
        #pragma unroll
        for (int m = 0; m < 4; ++m)
            #pragma unroll
            for (int nf = 0; nf < 4; ++nf)
                acc[m][nf] = __builtin_amdgcn_mfma_f32_16x16x32_bf16(a[m], b[nf], acc[m][nf], 0, 0, 0);
    }

    ushort* u16 = (ushort*)(half ? p.aggR : p.aggL);
    #pragma unroll
    for (int m = 0; m < 4; ++m) {
        #pragma unroll
        for (int j = 0; j < 4; ++j) {
            const int n = n0 + rowh * 64 + m * 16 + lhi * 4 + j;
            if (n < p.N) {
                const int col = (colw & 1) * 64 + llo;
                #pragma unroll
                for (int nf = 0; nf < 4; ++nf)
                    u16[(size_t)n * 256 + col + nf * 16] = f2bf(acc[m][nf][j]);
            }
        }
    }
}

// ---------------- edge_out: 16-lane sub-wave per edge (4 edges/wave), contiguous spans ----------------
// Lane sl owns cols sl*8..sl*8+7 (uint4 bf16 u-loads); 4-step shfl reduce within 16 lanes.
// Each sub-wave walks a contiguous range of dst-sorted positions -> dst-run cache sees full runs.
__global__ __launch_bounds__(256) void edge_out_kernel(
    const int* __restrict__ src, const int* __restrict__ dst,
    const float* __restrict__ W2, const float* __restrict__ b2,
    float* __restrict__ ws, const int* __restrict__ n_nodes_p,
    float* __restrict__ out, int E)
{
    WsPtrs p = ws_ptrs(ws, n_nodes_p, E);
    const ushort* uLb = (const ushort*)p.aggL;   // bf16 rows, stride 256 ushorts
    const ushort* uRb = (const ushort*)p.aggR;
    const int t = threadIdx.x;
    const int sl = t & 15;                 // lane within 16-lane sub-wave
    const int swid = blockIdx.x * 16 + (t >> 4);
    const int nsw = gridDim.x * 16;
    const int span = (E + nsw - 1) / nsw;
    const int j0 = swid * span;
    const int j1 = min(E, j0 + span);

    const float4 gwl0 = *reinterpret_cast<const float4*>(p.gwb + sl * 8);
    const float4 gwl1 = *reinterpret_cast<const float4*>(p.gwb + sl * 8 + 4);
    const float4 gwr0 = *reinterpret_cast<const float4*>(p.gwb + 128 + sl * 8);
    const float4 gwr1 = *reinterpret_cast<const float4*>(p.gwb + 128 + sl * 8 + 4);
    const float4 bw0  = *reinterpret_cast<const float4*>(p.gwb + 256 + sl * 8);
    const float4 bw1  = *reinterpret_cast<const float4*>(p.gwb + 256 + sl * 8 + 4);
    const float4 w20  = *reinterpret_cast<const float4*>(W2 + sl * 8);
    const float4 w21  = *reinterpret_cast<const float4*>(W2 + sl * 8 + 4);
    const float b2v = b2[0];

    // dst-run cache (per sub-wave; elist is dst-bucketed, contiguous span keeps runs intact)
    int dc = -1;
    float ur[8];
    #pragma unroll
    for (int i = 0; i < 8; ++i) ur[i] = 0.f;
    float2 nsr = make_float2(0.f, 0.f);

    for (int j = j0; j < j1; ++j) {
        const int eid = p.elist[j];
        const int s = src[eid], d = dst[eid];
        if (d != dc) {
            const uint4 urp = *reinterpret_cast<const uint4*>(uRb + (size_t)d * 256 + sl * 8);
            ur[0] = __builtin_bit_cast(float, urp.x << 16);
            ur[1] = __builtin_bit_cast(float, urp.x & 0xffff0000u);
            ur[2] = __builtin_bit_cast(float, urp.y << 16);
            ur[3] = __builtin_bit_cast(float, urp.y & 0xffff0000u);
            ur[4] = __builtin_bit_cast(float, urp.z << 16);
            ur[5] = __builtin_bit_cast(float, urp.z & 0xffff0000u);
            ur[6] = __builtin_bit_cast(float, urp.w << 16);
            ur[7] = __builtin_bit_cast(float, urp.w & 0xffff0000u);
            nsr = *reinterpret_cast<const float2*>(p.nstR + 2 * d);
            dc = d;
        }
        const uint4 ulp = *reinterpret_cast<const uint4*>(uLb + (size_t)s * 256 + sl * 8);
        float ul[8];
        ul[0] = __builtin_bit_cast(float, ulp.x << 16);
        ul[1] = __builtin_bit_cast(float, ulp.x & 0xffff0000u);
        ul[2] = __builtin_bit_cast(float, ulp.y << 16);
        ul[3] = __builtin_bit_cast(float, ulp.y & 0xffff0000u);
        ul[4] = __builtin_bit_cast(float, ulp.z << 16);
        ul[5] = __builtin_bit_cast(float, ulp.z & 0xffff0000u);
        ul[6] = __builtin_bit_cast(float, ulp.w << 16);
        ul[7] = __builtin_bit_cast(float, ulp.w & 0xffff0000u);
        const float2 nsl = *reinterpret_cast<const float2*>(p.nstL + 2 * s);
        const float mu = (nsl.x + nsr.x) * (1.f / 256.f);
        const float var = (nsl.y + nsr.y) * (1.f / 256.f) - mu * mu;
        const float rstd = rsqrtf(var + LN_EPS);
        const float dL = nsl.x * (1.f / 128.f) - mu;
        const float dR = nsr.x * (1.f / 128.f) - mu;

        const float gl[8] = {gwl0.x, gwl0.y, gwl0.z, gwl0.w, gwl1.x, gwl1.y, gwl1.z, gwl1.w};
        const float gr[8] = {gwr0.x, gwr0.y, gwr0.z, gwr0.w, gwr1.x, gwr1.y, gwr1.z, gwr1.w};
        const float bb[8] = {bw0.x, bw0.y, bw0.z, bw0.w, bw1.x, bw1.y, bw1.z, bw1.w};
        const float ww[8] = {w20.x, w20.y, w20.z, w20.w, w21.x, w21.y, w21.z, w21.w};
        float a = 0.f;
        #pragma unroll
        for (int i = 0; i < 8; ++i) {
            float x = rstd * (ul[i] + ur[i] + dL * gl[i] + dR * gr[i]) + bb[i];
            x = x > 0.f ? x : __expf(x) - 1.f;
            a += x * ww[i];
        }
        a += __shfl_xor(a, 8);
        a += __shfl_xor(a, 4);
        a += __shfl_xor(a, 2);
        a += __shfl_xor(a, 1);
        if (sl == 0) out[eid] = a + b2v;
    }
}

extern "C" void kernel_launch(void* const* d_in, const int* in_sizes, int n_in,
                              void* d_out, int out_size, void* d_ws, size_t ws_size,
                              hipStream_t stream) {
    const float* y       = (const float*)d_in[0];
    const int*   src     = (const int*)d_in[1];
    const int*   dst     = (const int*)d_in[2];
    const int*   n_nodes = (const int*)d_in[3];
    const float* ln_g    = (const float*)d_in[4];
    const float* ln_b    = (const float*)d_in[5];
    const float* Wl      = (const float*)d_in[6];
    const float* bl      = (const float*)d_in[7];
    const float* Wr      = (const float*)d_in[8];
    const float* br      = (const float*)d_in[9];
    const float* ln2_g   = (const float*)d_in[10];
    const float* ln2_b   = (const float*)d_in[11];
    const float* W1      = (const float*)d_in[12];
    const float* b1      = (const float*)d_in[13];
    const float* W2      = (const float*)d_in[14];
    const float* b2      = (const float*)d_in[15];
    float* out = (float*)d_out;
    float* ws  = (float*)d_ws;

    const int E = in_sizes[0] / 128;
    const int eb64 = (E + 63) / 64;
    const int hb = (E + 255) / 256;
    const int N_MAX = 40000;   // grid sizing only; device code reads *n_nodes

    const size_t need = (size_t)(E + 128) * 256;
    const bool use_pre = ws_size >= need + (96ull << 20);
    ushort* ynb = use_pre
        ? (ushort*)(((uintptr_t)ws + ws_size - need) & ~(uintptr_t)255)
        : nullptr;

    init_kernel<<<2048, 256, 0, stream>>>(ws, n_nodes, E);
    hist_prep_kernel<<<hb + 257, 256, 0, stream>>>(dst, Wl, Wr, W1, ln2_g, ln2_b, b1,
                                                   ws, n_nodes, E, hb);
    scan_kernel<<<1, 1024, 0, stream>>>(ws, n_nodes, E);
    scatter_kernel<<<hb, 256, 0, stream>>>(dst, ws, n_nodes, E);
    if (use_pre)
        ln_y_kernel<<<(E + 63) / 64, 256, 0, stream>>>(y, ln_g, ln_b, ws, n_nodes, E, ynb);
    gates_kernel<<<eb64, 512, 0, stream>>>(y, dst, ln_g, ln_b, bl, br, ws, n_nodes, E, ynb);
    node_mlp_kernel<<<(N_MAX + 127) / 128, 512, 0, stream>>>(ln2_g, ws, n_nodes, E);
    edge_out_kernel<<<2048, 256, 0, stream>>>(src, dst, W2, b2, ws, n_nodes, out, E);
}

// Round 14
// 477.115 us; speedup vs baseline: 1.7467x; 1.0430x over previous
//
#include <hip/hip_runtime.h>
#include <hip/hip_bf16.h>

#define LN_EPS 1e-5f

typedef __attribute__((ext_vector_type(8))) short bf16x8;
typedef __attribute__((ext_vector_type(4))) float f32x4;

__device__ __forceinline__ float sigmoid_fast(float x) {
    return __builtin_amdgcn_rcpf(1.0f + __expf(-x));
}
__device__ __forceinline__ ushort f2bf(float x) {
    __hip_bfloat16 h = __float2bfloat16(x);   // RNE
    return __builtin_bit_cast(ushort, h);
}
// m204 bijective XCD-chunked swizzle (8 XCDs)
__device__ __forceinline__ int xcd_swz(int bid, int nwg) {
    const int q = nwg >> 3, r = nwg & 7;
    const int xcd = bid & 7, idx = bid >> 3;
    return (xcd < r ? xcd * (q + 1) : r * (q + 1) + (xcd - r) * q) + idx;
}
// block-local edge permutation: swap bits[3:2] <-> bits[5:4] (involution).
__device__ __forceinline__ int gperm(int l) {
    return (l & ~63) | (((l >> 2) & 3) << 4) | (((l >> 4) & 3) << 2) | (l & 3);
}
__device__ __forceinline__ void gload_lds16(const void* g, void* l) {
    __builtin_amdgcn_global_load_lds((const __attribute__((address_space(1))) void*)g,
                                     (__attribute__((address_space(3))) void*)l, 16, 0, 0);
}

// ws layout (N read on device):
//   float aggL[N*128]; float aggR[N*128]; float rd[N];
//   int ideg[N]; int ioff[N+1]; int icur[N]; int elist[E]; int epos[E];
//   ushort WgF[16*4*64*8]; ushort W1F[8*8*64*8];
//   float gwb[384]; float nstL[2N]; float nstR[2N]
//   ... tail of ws: ushort ynb[(E+128)*128]
struct WsPtrs {
    float *aggL, *aggR, *rd;
    int *ideg, *ioff, *icur, *elist, *epos;
    ushort *WgF, *W1F;
    float *gwb, *nstL, *nstR;
    int N;
};
__device__ __forceinline__ WsPtrs ws_ptrs(float* ws, const int* n_nodes_p, int E) {
    WsPtrs p;
    p.N    = *n_nodes_p;
    p.aggL = ws;
    p.aggR = ws + (size_t)p.N * 128;
    p.rd   = ws + (size_t)p.N * 256;
    p.ideg = (int*)(ws + (size_t)p.N * 257);
    p.ioff = p.ideg + p.N;
    p.icur = p.ioff + p.N + 1;
    p.elist = p.icur + p.N;
    p.epos  = p.elist + E;
    p.WgF = (ushort*)(((uintptr_t)(p.epos + E) + 15) & ~(uintptr_t)15);
    p.W1F = p.WgF + 32768;
    p.gwb = (float*)(p.W1F + 32768);
    p.nstL = p.gwb + 384;
    p.nstR = p.nstL + 2 * p.N;
    return p;
}

// ---------------- zero agg + deg ----------------
__global__ void init_kernel(float* __restrict__ ws, const int* __restrict__ n_nodes_p, int E) {
    WsPtrs p = ws_ptrs(ws, n_nodes_p, E);
    const long long stride = (long long)gridDim.x * blockDim.x;
    const long long tid = (long long)blockIdx.x * blockDim.x + threadIdx.x;
    const long long nf = (long long)p.N * 256;
    for (long long i = tid; i < nf; i += stride) ws[i] = 0.0f;
    for (long long i = tid; i < p.N; i += stride) p.ideg[i] = 0;
}

// ---------------- histogram of dst + (merged) fragment-major B tables + gW1/bW1 ----------------
__global__ void hist_prep_kernel(const int* __restrict__ dst,
                                 const float* __restrict__ Wl, const float* __restrict__ Wr,
                                 const float* __restrict__ W1,
                                 const float* __restrict__ ln2_g, const float* __restrict__ ln2_b,
                                 const float* __restrict__ b1,
                                 float* __restrict__ ws, const int* __restrict__ n_nodes_p,
                                 int E, int histBlocks) {
    WsPtrs p = ws_ptrs(ws, n_nodes_p, E);
    const int t = threadIdx.x;
    if ((int)blockIdx.x < histBlocks) {
        const int i = blockIdx.x * 256 + t;
        if (i < E) atomicAdd(&p.ideg[dst[i]], 1);
        return;
    }
    const int i = (blockIdx.x - histBlocks) * 256 + t;
    if (i < 32768) {
        const int i8 = i & 7, lane = (i >> 3) & 63, kf = (i >> 9) & 3, nblk = i >> 11;
        const int k = kf * 32 + (lane >> 4) * 8 + i8;
        const int n = nblk * 16 + (lane & 15);
        const float val = (n < 128) ? Wl[k * 128 + n] : Wr[k * 128 + (n - 128)];
        p.WgF[i] = f2bf(val);
    } else if (i < 65536) {
        const int j = i - 32768;
        const int i8 = j & 7, lane = (j >> 3) & 63, kf = (j >> 9) & 7, nblk = j >> 12;
        const int k = kf * 32 + (lane >> 4) * 8 + i8;
        const int n = nblk * 16 + (lane & 15);
        p.W1F[j] = f2bf(W1[k * 128 + n]);
    } else if (i < 65664) {
        const int j = i - 65536;   // 0..127
        float gsL = 0.f, gsR = 0.f, bs = 0.f;
        for (int k = 0; k < 128; ++k) {
            const float wt = W1[k * 128 + j];
            const float wb = W1[(k + 128) * 128 + j];
            gsL += ln2_g[k] * wt;
            gsR += ln2_g[k + 128] * wb;
            bs  += ln2_b[k] * wt + ln2_b[k + 128] * wb;
        }
        p.gwb[j]       = gsL;
        p.gwb[128 + j] = gsR;
        p.gwb[256 + j] = bs + b1[j];
    }
}

// ---------------- exclusive scan (single block, 1024 thr) + rd = 1/max(deg,1) ----------------
__global__ __launch_bounds__(1024) void scan_kernel(float* __restrict__ ws,
                                                    const int* __restrict__ n_nodes_p, int E) {
    WsPtrs p = ws_ptrs(ws, n_nodes_p, E);
    __shared__ int wsum[16];
    __shared__ int carry_s;
    const int t = threadIdx.x;
    const int lane = t & 63, wid = t >> 6;
    if (t == 0) carry_s = 0;
    __syncthreads();
    for (int base = 0; base < p.N; base += 4096) {
        const int i0 = base + t * 4;
        const int v0 = (i0 + 0 < p.N) ? p.ideg[i0 + 0] : 0;
        const int v1 = (i0 + 1 < p.N) ? p.ideg[i0 + 1] : 0;
        const int v2 = (i0 + 2 < p.N) ? p.ideg[i0 + 2] : 0;
        const int v3 = (i0 + 3 < p.N) ? p.ideg[i0 + 3] : 0;
        const int s = v0 + v1 + v2 + v3;
        int sc = s;
        #pragma unroll
        for (int off = 1; off < 64; off <<= 1) {
            const int n = __shfl_up(sc, off);
            if (lane >= off) sc += n;
        }
        if (lane == 63) wsum[wid] = sc;
        __syncthreads();
        int woff = 0;
        #pragma unroll
        for (int w = 0; w < 16; ++w) if (w < wid) woff += wsum[w];
        const int carry = carry_s;
        __syncthreads();
        const int excl = carry + woff + (sc - s);
        if (i0 + 0 < p.N) { p.ioff[i0+0] = excl;          p.icur[i0+0] = excl;          p.rd[i0+0] = 1.0f / fmaxf((float)v0, 1.0f); }
        if (i0 + 1 < p.N) { p.ioff[i0+1] = excl+v0;       p.icur[i0+1] = excl+v0;       p.rd[i0+1] = 1.0f / fmaxf((float)v1, 1.0f); }
        if (i0 + 2 < p.N) { p.ioff[i0+2] = excl+v0+v1;    p.icur[i0+2] = excl+v0+v1;    p.rd[i0+2] = 1.0f / fmaxf((float)v2, 1.0f); }
        if (i0 + 3 < p.N) { p.ioff[i0+3] = excl+v0+v1+v2; p.icur[i0+3] = excl+v0+v1+v2; p.rd[i0+3] = 1.0f / fmaxf((float)v3, 1.0f); }
        if (t == 1023) carry_s = carry + woff + sc;
        __syncthreads();
    }
    if (t == 0) p.ioff[p.N] = carry_s;
}

// ---------------- (fallback only) scatter edge ids into buckets ----------------
__global__ void scatter_kernel(const int* __restrict__ dst, float* __restrict__ ws,
                               const int* __restrict__ n_nodes_p, int E) {
    WsPtrs p = ws_ptrs(ws, n_nodes_p, E);
    const int i = blockIdx.x * blockDim.x + threadIdx.x;
    if (i < E) {
        const int pos = atomicAdd(&p.icur[dst[i]], 1);
        p.elist[pos] = i;
    }
}

// ---------------- fused scatter + streaming LN(y) -> bf16 permuted-sorted write ----------------
// Phase 1 (64 lanes): bucket-scatter this block's 64 edges, epos kept in LDS.
// Phase 2 (256 lanes, 4/row): LN + quantize + write ynb row at epos.
__global__ __launch_bounds__(256) void lnscatter_kernel(
    const float* __restrict__ y, const int* __restrict__ dst,
    const float* __restrict__ ln_g, const float* __restrict__ ln_b,
    float* __restrict__ ws, const int* __restrict__ n_nodes_p, int E,
    ushort* __restrict__ ynb)
{
    __shared__ int sEpos[64];
    WsPtrs p = ws_ptrs(ws, n_nodes_p, E);
    const int t = threadIdx.x;
    const int s0 = blockIdx.x * 64;

    if (t < 64) {
        const int e = s0 + t;
        if (e < E) {
            const int pos = atomicAdd(&p.icur[dst[e]], 1);
            p.elist[pos] = e;
            sEpos[t] = (pos & ~63) | gperm(pos & 63);
        }
    }
    __syncthreads();

    const int e = s0 + (t >> 2);
    const int sub = t & 3;
    if (e >= E) return;

    const float* yr = y + (size_t)e * 128;
    float v[32];
    float s = 0.f, sq = 0.f;
    #pragma unroll
    for (int i = 0; i < 8; ++i) {
        const float4 q = *reinterpret_cast<const float4*>(yr + sub * 32 + i * 4);
        v[i*4+0] = q.x; v[i*4+1] = q.y; v[i*4+2] = q.z; v[i*4+3] = q.w;
        s  += q.x + q.y + q.z + q.w;
        sq += q.x*q.x + q.y*q.y + q.z*q.z + q.w*q.w;
    }
    s  += __shfl_xor(s, 1);  s  += __shfl_xor(s, 2);
    sq += __shfl_xor(sq, 1); sq += __shfl_xor(sq, 2);
    const float mu = s * (1.f / 128.f);
    const float rstd = rsqrtf(sq * (1.f / 128.f) - mu * mu + LN_EPS);

    ushort* dstrow = ynb + (size_t)sEpos[t >> 2] * 128 + sub * 32;
    #pragma unroll
    for (int i = 0; i < 4; ++i) {
        uint w32[4];
        #pragma unroll
        for (int h2 = 0; h2 < 4; ++h2) {
            const int c = sub * 32 + i * 8 + h2 * 2;
            const float x0 = (v[i*8 + h2*2 + 0] - mu) * rstd * ln_g[c + 0] + ln_b[c + 0];
            const float x1 = (v[i*8 + h2*2 + 1] - mu) * rstd * ln_g[c + 1] + ln_b[c + 1];
            w32[h2] = (uint)f2bf(x0) | ((uint)f2bf(x1) << 16);
        }
        *reinterpret_cast<uint4*>(dstrow + i * 8) = make_uint4(w32[0], w32[1], w32[2], w32[3]);
    }
}

// ---------------- gates: 64-edge tile, 8 waves, acc[4][2] (<=64 VGPR target) ----------------
__global__ __launch_bounds__(512, 8) void gates_kernel(
    const float* __restrict__ y, const int* __restrict__ dst,
    const float* __restrict__ ln_g, const float* __restrict__ ln_b,
    const float* __restrict__ bl, const float* __restrict__ br,
    float* __restrict__ ws, const int* __restrict__ n_nodes_p, int E,
    const ushort* __restrict__ ynb)
{
    __shared__ ushort sA[64 * 128];   // 16 KB
    __shared__ int sNode[64];

    WsPtrs p = ws_ptrs(ws, n_nodes_p, E);
    char* sAb = reinterpret_cast<char*>(sA);
    const int t = threadIdx.x;
    const int bid = xcd_swz(blockIdx.x, gridDim.x);
    const int s0 = bid * 64;
    const int lane = t & 63;
    const int w8 = t >> 6;

    if (t < 64) {
        const int j = s0 + t;
        const int eid = (j < E) ? p.elist[j] : -1;
        sNode[t] = (eid >= 0) ? dst[eid] : -1;
    }

    if (ynb) {
        const char* ybase = (const char*)ynb + (size_t)s0 * 256;
        #pragma unroll
        for (int i = 0; i < 2; ++i) {
            const int chunk = w8 * 2 + i;
            const int L = chunk * 1024 + lane * 16;
            const int b = L ^ (((L >> 8) & 7) << 4);
            gload_lds16(ybase + b, sAb + chunk * 1024);
        }
    } else {
        const int r = t >> 3, sub8 = t & 7;
        const int je = s0 + gperm(r);
        const int eid = (je < E) ? p.elist[je] : 0;
        const float* yr = y + (size_t)eid * 128;
        float v[16];
        float s = 0.f, sq = 0.f;
        #pragma unroll
        for (int i = 0; i < 4; ++i) {
            const float4 q = *reinterpret_cast<const float4*>(yr + sub8 * 16 + i * 4);
            v[i*4+0] = q.x; v[i*4+1] = q.y; v[i*4+2] = q.z; v[i*4+3] = q.w;
            s  += q.x + q.y + q.z + q.w;
            sq += q.x*q.x + q.y*q.y + q.z*q.z + q.w*q.w;
        }
        s  += __shfl_xor(s, 1);  s  += __shfl_xor(s, 2);  s  += __shfl_xor(s, 4);
        sq += __shfl_xor(sq, 1); sq += __shfl_xor(sq, 2); sq += __shfl_xor(sq, 4);
        const float mu = s * (1.f / 128.f);
        const float rstd = rsqrtf(sq * (1.f / 128.f) - mu * mu + LN_EPS);
        #pragma unroll
        for (int i = 0; i < 2; ++i) {
            uint w32[4];
            #pragma unroll
            for (int h2 = 0; h2 < 4; ++h2) {
                const int c = sub8 * 16 + i * 8 + h2 * 2;
                const float x0 = (v[i*8 + h2*2 + 0] - mu) * rstd * ln_g[c + 0] + ln_b[c + 0];
                const float x1 = (v[i*8 + h2*2 + 1] - mu) * rstd * ln_g[c + 1] + ln_b[c + 1];
                w32[h2] = (uint)f2bf(x0) | ((uint)f2bf(x1) << 16);
            }
            int byte = r * 256 + sub8 * 32 + i * 16;
            byte ^= ((byte >> 8) & 7) << 4;
            *reinterpret_cast<uint4*>(sAb + byte) = make_uint4(w32[0], w32[1], w32[2], w32[3]);
        }
    }
    __syncthreads();

    const int lhi = lane >> 4, llo = lane & 15;

    f32x4 acc[4][2];
    #pragma unroll
    for (int m = 0; m < 4; ++m)
        #pragma unroll
        for (int n = 0; n < 2; ++n) acc[m][n] = (f32x4){0.f, 0.f, 0.f, 0.f};

    #pragma unroll
    for (int kf = 0; kf < 4; ++kf) {
        bf16x8 b[2];
        #pragma unroll
        for (int nf = 0; nf < 2; ++nf) {
            const int nblk = w8 * 2 + nf;
            b[nf] = *reinterpret_cast<const bf16x8*>(p.WgF + ((size_t)(nblk * 4 + kf) * 64 + lane) * 8);
        }
        #pragma unroll
        for (int m = 0; m < 4; ++m) {
            const int row = m * 16 + llo;
            int byte = row * 256 + kf * 64 + lhi * 16;
            byte ^= ((byte >> 8) & 7) << 4;
            const bf16x8 a = *reinterpret_cast<const bf16x8*>(sAb + byte);
            acc[m][0] = __builtin_amdgcn_mfma_f32_16x16x32_bf16(a, b[0], acc[m][0], 0, 0, 0);
            acc[m][1] = __builtin_amdgcn_mfma_f32_16x16x32_bf16(a, b[1], acc[m][1], 0, 0, 0);
        }
    }

    const int g = w8 >> 2;
    float* ag = g ? p.aggR : p.aggL;
    const float* bp = g ? br : bl;
    const int lcol0 = (w8 & 3) * 32 + llo;   // col within gate (mod 128)
    const float bias0 = bp[lcol0];
    const float bias1 = bp[lcol0 + 16];

    float run0 = 0.f, run1 = 0.f;
    int rnode = -1;
    #pragma unroll
    for (int m = 0; m < 4; ++m) {
        #pragma unroll
        for (int j = 0; j < 4; ++j) {
            const int el = lhi * 16 + m * 4 + j;
            const int node = sNode[el];
            const float v0 = sigmoid_fast(acc[m][0][j] + bias0);
            const float v1 = sigmoid_fast(acc[m][1][j] + bias1);
            if (node != rnode) {
                if (rnode >= 0) {
                    float* dest = ag + (size_t)rnode * 128 + lcol0;
                    atomicAdd(dest +  0, run0);
                    atomicAdd(dest + 16, run1);
                }
                rnode = node;
                run0 = v0; run1 = v1;
            } else {
                run0 += v0; run1 += v1;
            }
        }
    }
    if (rnode >= 0) {
        float* dest = ag + (size_t)rnode * 128 + lcol0;
        atomicAdd(dest +  0, run0);
        atomicAdd(dest + 16, run1);
    }
}

// ---------------- node_mlp: u = ((z - mu_node) ⊙ g2) @ W1half -> bf16 IN PLACE; stats ----------------
__global__ __launch_bounds__(512) void node_mlp_kernel(
    const float* __restrict__ ln2_g,
    float* __restrict__ ws, const int* __restrict__ n_nodes_p, int E)
{
    __shared__ ushort sA[128 * 256];   // 64 KB

    WsPtrs p = ws_ptrs(ws, n_nodes_p, E);
    char* sAb = reinterpret_cast<char*>(sA);
    const int t = threadIdx.x;
    const int n0 = blockIdx.x * 128;

    {
        const int r = t >> 2, sub = t & 3;
        const int n = n0 + r;
        const bool vld = n < p.N;
        const int nn = vld ? n : (p.N - 1);
        const float* base = ((sub < 2) ? p.aggL : p.aggR) + (size_t)nn * 128 + (sub & 1) * 64;
        const float scale = vld ? p.rd[nn] : 0.f;
        const int cb = ((sub >> 1) << 7) + ((sub & 1) << 6);   // concat col base

        float s = 0.f, sq = 0.f;
        #pragma unroll
        for (int ii = 0; ii < 8; ++ii) {
            const float4 qa = *reinterpret_cast<const float4*>(base + ii * 8);
            const float4 qb = *reinterpret_cast<const float4*>(base + ii * 8 + 4);
            s  += qa.x + qa.y + qa.z + qa.w + qb.x + qb.y + qb.z + qb.w;
            sq += qa.x*qa.x + qa.y*qa.y + qa.z*qa.z + qa.w*qa.w
                + qb.x*qb.x + qb.y*qb.y + qb.z*qb.z + qb.w*qb.w;
        }
        s *= scale; sq *= scale * scale;
        s  += __shfl_xor(s, 1);
        sq += __shfl_xor(sq, 1);
        if (vld && sub == 0) { p.nstL[2*n] = s; p.nstL[2*n+1] = sq; }
        if (vld && sub == 2) { p.nstR[2*n] = s; p.nstR[2*n+1] = sq; }
        const float mu_n = s * (1.f / 128.f);

        #pragma unroll
        for (int ii = 0; ii < 8; ++ii) {
            const float4 qa = *reinterpret_cast<const float4*>(base + ii * 8);
            const float4 qb = *reinterpret_cast<const float4*>(base + ii * 8 + 4);
            const float xs[8] = { qa.x*scale - mu_n, qa.y*scale - mu_n, qa.z*scale - mu_n, qa.w*scale - mu_n,
                                  qb.x*scale - mu_n, qb.y*scale - mu_n, qb.z*scale - mu_n, qb.w*scale - mu_n };
            uint w32[4];
            #pragma unroll
            for (int h2 = 0; h2 < 4; ++h2) {
                const int c = cb + ii * 8 + h2 * 2;
                w32[h2] = (uint)f2bf(xs[h2*2+0] * ln2_g[c+0]) |
                          ((uint)f2bf(xs[h2*2+1] * ln2_g[c+1]) << 16);
            }
            int byte = r * 512 + cb * 2 + ii * 16;
            byte ^= ((byte >> 9) & 7) << 4;
            *reinterpret_cast<uint4*>(sAb + byte) = make_uint4(w32[0], w32[1], w32[2], w32[3]);
        }
    }
    __syncthreads();

    const int lane = t & 63;
    const int w8 = t >> 6;
    const int rowh = w8 >> 2, colw = w8 & 3;
    const int half = colw >> 1;                  // 0 -> uL, 1 -> uR
    const int lhi = lane >> 4, llo = lane & 15;

    f32x4 acc[4][4];
    #pragma unroll
    for (int m = 0; m < 4; ++m)
        #pragma unroll
        for (int n = 0; n < 4; ++n) acc[m][n] = (f32x4){0.f, 0.f, 0.f, 0.f};

    #pragma unroll
    for (int kfl = 0; kfl < 4; ++kfl) {
        bf16x8 a[4], b[4];
        #pragma unroll
        for (int m = 0; m < 4; ++m) {
            const int row = rowh * 64 + m * 16 + llo;
            int byte = row * 512 + half * 256 + kfl * 64 + lhi * 16;
            byte ^= ((byte >> 9) & 7) << 4;
            a[m] = *reinterpret_cast<const bf16x8*>(sAb + byte);
        }
        #pragma unroll
        for (int nf = 0; nf < 4; ++nf) {
            const int nblk = (colw & 1) * 4 + nf;
            const int kf = half * 4 + kfl;
            b[nf] = *reinterpret_cast<const bf16x8*>(p.W1F + ((size_t)(nblk * 8 + kf) * 64 + lane) * 8);
        }
        #pragma unroll
        for (int m = 0; m < 4; ++m)
            #pragma unroll
            for (int nf = 0; nf < 4; ++nf)
                acc[m][nf] = __builtin_amdgcn_mfma_f32_16x16x32_bf16(a[m], b[nf], acc[m][nf], 0, 0, 0);
    }

    ushort* u16 = (ushort*)(half ? p.aggR : p.aggL);
    #pragma unroll
    for (int m = 0; m < 4; ++m) {
        #pragma unroll
        for (int j = 0; j < 4; ++j) {
            const int n = n0 + rowh * 64 + m * 16 + lhi * 4 + j;
            if (n < p.N) {
                const int col = (colw & 1) * 64 + llo;
                #pragma unroll
                for (int nf = 0; nf < 4; ++nf)
                    u16[(size_t)n * 256 + col + nf * 16] = f2bf(acc[m][nf][j]);
            }
        }
    }
}

// ---------------- edge_out: 16-lane sub-wave per edge, contiguous spans, XCD-chunked ----------------
__global__ __launch_bounds__(256) void edge_out_kernel(
    const int* __restrict__ src, const int* __restrict__ dst,
    const float* __restrict__ W2, const float* __restrict__ b2,
    float* __restrict__ ws, const int* __restrict__ n_nodes_p,
    float* __restrict__ out, int E)
{
    WsPtrs p = ws_ptrs(ws, n_nodes_p, E);
    const ushort* uLb = (const ushort*)p.aggL;   // bf16 rows, stride 256 ushorts
    const ushort* uRb = (const ushort*)p.aggR;
    const int t = threadIdx.x;
    const int sl = t & 15;                 // lane within 16-lane sub-wave
    const int bid = xcd_swz(blockIdx.x, gridDim.x);
    const int swid = bid * 16 + (t >> 4);
    const int nsw = gridDim.x * 16;
    const int span = (E + nsw - 1) / nsw;
    const int j0 = swid * span;
    const int j1 = min(E, j0 + span);

    const float4 gwl0 = *reinterpret_cast<const float4*>(p.gwb + sl * 8);
    const float4 gwl1 = *reinterpret_cast<const float4*>(p.gwb + sl * 8 + 4);
    const float4 gwr0 = *reinterpret_cast<const float4*>(p.gwb + 128 + sl * 8);
    const float4 gwr1 = *reinterpret_cast<const float4*>(p.gwb + 128 + sl * 8 + 4);
    const float4 bw0  = *reinterpret_cast<const float4*>(p.gwb + 256 + sl * 8);
    const float4 bw1  = *reinterpret_cast<const float4*>(p.gwb + 256 + sl * 8 + 4);
    const float4 w20  = *reinterpret_cast<const float4*>(W2 + sl * 8);
    const float4 w21  = *reinterpret_cast<const float4*>(W2 + sl * 8 + 4);
    const float b2v = b2[0];

    int dc = -1;
    float ur[8];
    #pragma unroll
    for (int i = 0; i < 8; ++i) ur[i] = 0.f;
    float2 nsr = make_float2(0.f, 0.f);

    for (int j = j0; j < j1; ++j) {
        const int eid = p.elist[j];
        const int s = src[eid], d = dst[eid];
        if (d != dc) {
            const uint4 urp = *reinterpret_cast<const uint4*>(uRb + (size_t)d * 256 + sl * 8);
            ur[0] = __builtin_bit_cast(float, urp.x << 16);
            ur[1] = __builtin_bit_cast(float, urp.x & 0xffff0000u);
            ur[2] = __builtin_bit_cast(float, urp.y << 16);
            ur[3] = __builtin_bit_cast(float, urp.y & 0xffff0000u);
            ur[4] = __builtin_bit_cast(float, urp.z << 16);
            ur[5] = __builtin_bit_cast(float, urp.z & 0xffff0000u);
            ur[6] = __builtin_bit_cast(float, urp.w << 16);
            ur[7] = __builtin_bit_cast(float, urp.w & 0xffff0000u);
            nsr = *reinterpret_cast<const float2*>(p.nstR + 2 * d);
            dc = d;
        }
        const uint4 ulp = *reinterpret_cast<const uint4*>(uLb + (size_t)s * 256 + sl * 8);
        float ul[8];
        ul[0] = __builtin_bit_cast(float, ulp.x << 16);
        ul[1] = __builtin_bit_cast(float, ulp.x & 0xffff0000u);
        ul[2] = __builtin_bit_cast(float, ulp.y << 16);
        ul[3] = __builtin_bit_cast(float, ulp.y & 0xffff0000u);
        ul[4] = __builtin_bit_cast(float, ulp.z << 16);
        ul[5] = __builtin_bit_cast(float, ulp.z & 0xffff0000u);
        ul[6] = __builtin_bit_cast(float, ulp.w << 16);
        ul[7] = __builtin_bit_cast(float, ulp.w & 0xffff0000u);
        const float2 nsl = *reinterpret_cast<const float2*>(p.nstL + 2 * s);
        const float mu = (nsl.x + nsr.x) * (1.f / 256.f);
        const float var = (nsl.y + nsr.y) * (1.f / 256.f) - mu * mu;
        const float rstd = rsqrtf(var + LN_EPS);
        const float dL = nsl.x * (1.f / 128.f) - mu;
        const float dR = nsr.x * (1.f / 128.f) - mu;

        const float gl[8] = {gwl0.x, gwl0.y, gwl0.z, gwl0.w, gwl1.x, gwl1.y, gwl1.z, gwl1.w};
        const float gr[8] = {gwr0.x, gwr0.y, gwr0.z, gwr0.w, gwr1.x, gwr1.y, gwr1.z, gwr1.w};
        const float bb[8] = {bw0.x, bw0.y, bw0.z, bw0.w, bw1.x, bw1.y, bw1.z, bw1.w};
        const float ww[8] = {w20.x, w20.y, w20.z, w20.w, w21.x, w21.y, w21.z, w21.w};
        float a = 0.f;
        #pragma unroll
        for (int i = 0; i < 8; ++i) {
            float x = rstd * (ul[i] + ur[i] + dL * gl[i] + dR * gr[i]) + bb[i];
            x = x > 0.f ? x : __expf(x) - 1.f;
            a += x * ww[i];
        }
        a += __shfl_xor(a, 8);
        a += __shfl_xor(a, 4);
        a += __shfl_xor(a, 2);
        a += __shfl_xor(a, 1);
        if (sl == 0) out[eid] = a + b2v;
    }
}

extern "C" void kernel_launch(void* const* d_in, const int* in_sizes, int n_in,
                              void* d_out, int out_size, void* d_ws, size_t ws_size,
                              hipStream_t stream) {
    const float* y       = (const float*)d_in[0];
    const int*   src     = (const int*)d_in[1];
    const int*   dst     = (const int*)d_in[2];
    const int*   n_nodes = (const int*)d_in[3];
    const float* ln_g    = (const float*)d_in[4];
    const float* ln_b    = (const float*)d_in[5];
    const float* Wl      = (const float*)d_in[6];
    const float* bl      = (const float*)d_in[7];
    const float* Wr      = (const float*)d_in[8];
    const float* br      = (const float*)d_in[9];
    const float* ln2_g   = (const float*)d_in[10];
    const float* ln2_b   = (const float*)d_in[11];
    const float* W1      = (const float*)d_in[12];
    const float* b1      = (const float*)d_in[13];
    const float* W2      = (const float*)d_in[14];
    const float* b2      = (const float*)d_in[15];
    float* out = (float*)d_out;
    float* ws  = (float*)d_ws;

    const int E = in_sizes[0] / 128;
    const int eb64 = (E + 63) / 64;
    const int hb = (E + 255) / 256;
    const int N_MAX = 40000;   // grid sizing only; device code reads *n_nodes

    const size_t need = (size_t)(E + 128) * 256;
    const bool use_pre = ws_size >= need + (96ull << 20);
    ushort* ynb = use_pre
        ? (ushort*)(((uintptr_t)ws + ws_size - need) & ~(uintptr_t)255)
        : nullptr;

    init_kernel<<<2048, 256, 0, stream>>>(ws, n_nodes, E);
    hist_prep_kernel<<<hb + 257, 256, 0, stream>>>(dst, Wl, Wr, W1, ln2_g, ln2_b, b1,
                                                   ws, n_nodes, E, hb);
    scan_kernel<<<1, 1024, 0, stream>>>(ws, n_nodes, E);
    if (use_pre) {
        lnscatter_kernel<<<eb64, 256, 0, stream>>>(y, dst, ln_g, ln_b, ws, n_nodes, E, ynb);
    } else {
        scatter_kernel<<<hb, 256, 0, stream>>>(dst, ws, n_nodes, E);
    }
    gates_kernel<<<eb64, 512, 0, stream>>>(y, dst, ln_g, ln_b, bl, br, ws, n_nodes, E, ynb);
    node_mlp_kernel<<<(N_MAX + 127) / 128, 512, 0, stream>>>(ln2_g, ws, n_nodes, E);
    edge_out_kernel<<<2048, 256, 0, stream>>>(src, dst, W2, b2, ws, n_nodes, out, E);
}